// Round 2
// baseline (933.386 us; speedup 1.0000x reference)
//
#include <hip/hip_runtime.h>
#include <math.h>

// Problem constants (fixed shapes)
#define BB  2
#define NN  5000
#define EE  40000
#define TT  12
#define FF  16
#define DD  128
#define HH  4
#define HORZ 12

__device__ __forceinline__ float sigf(float x) { return 1.f / (1.f + expf(-x)); }

// ---------------------------------------------------------------------------
// K0a: tiny prep — s_h[h] = sum_c W_edge[h*32+c]*att_edge[h*32+c]; bias_sum
// ---------------------------------------------------------------------------
__global__ __launch_bounds__(512) void prep_small(
    const float* __restrict__ W_edge, const float* __restrict__ att_edge,
    const float* __restrict__ b_ih, const float* __restrict__ b_hh,
    float* __restrict__ s_h, float* __restrict__ bias_sum)
{
    int tid = threadIdx.x;
    if (tid < 128) {
        float v = W_edge[tid] * att_edge[tid];
        for (int off = 16; off; off >>= 1) v += __shfl_xor(v, off, 32);
        if ((tid & 31) == 0) s_h[tid >> 5] = v;
    }
    bias_sum[tid] = b_ih[tid] + b_hh[tid];
}

// ---------------------------------------------------------------------------
// K0b: transpose W_ih (512x128) and W_hh -> [k][j] layout (128x512)
// ---------------------------------------------------------------------------
__global__ __launch_bounds__(256) void transpose_w(
    const float* __restrict__ W_ih, const float* __restrict__ W_hh,
    float* __restrict__ W_ihT, float* __restrict__ W_hhT)
{
    int idx = blockIdx.x * 256 + threadIdx.x;   // 65536 total
    if (idx < 512 * 128) {
        int j = idx >> 7, k = idx & 127;
        W_ihT[k * 512 + j] = W_ih[idx];
        W_hhT[k * 512 + j] = W_hh[idx];
    }
}

// ---------------------------------------------------------------------------
// K1: hx = x @ W_lin  (row per block), plus a_src/a_dst per-head reductions
// ---------------------------------------------------------------------------
__global__ __launch_bounds__(128) void hx_kernel(
    const float* __restrict__ x, const float* __restrict__ W_lin,
    const float* __restrict__ att_src, const float* __restrict__ att_dst,
    float* __restrict__ hx, float* __restrict__ a_srcT, float* __restrict__ a_dstT)
{
    const int rt = blockIdx.x;                 // (b*N+n)*T+t, 0..119999
    const int d  = threadIdx.x;                // 0..127, h = d>>5, c = d&31
    const float* xr = x + (size_t)rt * FF;
    float acc = 0.f;
    #pragma unroll
    for (int f = 0; f < FF; ++f) acc += xr[f] * W_lin[f * DD + d];
    hx[(size_t)rt * DD + d] = acc;
    float vs = acc * att_src[d];               // att_src is (H,C) flat = [d]
    float vd = acc * att_dst[d];
    for (int off = 16; off; off >>= 1) {
        vs += __shfl_xor(vs, off, 32);
        vd += __shfl_xor(vd, off, 32);
    }
    if ((d & 31) == 0) {
        int h = d >> 5;
        a_srcT[(size_t)rt * HH + h] = vs;
        a_dstT[(size_t)rt * HH + h] = vd;
    }
}

// ---------------------------------------------------------------------------
// K2: CSR build (count -> scan -> fill)
// ---------------------------------------------------------------------------
__global__ __launch_bounds__(256) void count_kernel(const int* __restrict__ dst,
                                                    int* __restrict__ counts)
{
    int e = blockIdx.x * 256 + threadIdx.x;
    if (e < EE) atomicAdd(&counts[dst[e]], 1);
}

__global__ __launch_bounds__(1024) void scan_kernel(const int* __restrict__ counts,
                                                    int* __restrict__ offs,
                                                    int* __restrict__ cur)
{
    __shared__ int part[1024];
    const int tid = threadIdx.x;
    const int CH = 5;                          // ceil(5000/1024)
    int base = tid * CH;
    int pre[CH];
    int run = 0;
    #pragma unroll
    for (int i = 0; i < CH; ++i) {
        int idx = base + i;
        int v = (idx < NN) ? counts[idx] : 0;
        pre[i] = run;
        run += v;
    }
    part[tid] = run;
    __syncthreads();
    for (int off = 1; off < 1024; off <<= 1) {
        int v = (tid >= off) ? part[tid - off] : 0;
        __syncthreads();
        part[tid] += v;
        __syncthreads();
    }
    int prefix = (tid == 0) ? 0 : part[tid - 1];
    #pragma unroll
    for (int i = 0; i < CH; ++i) {
        int idx = base + i;
        if (idx < NN) {
            int o = prefix + pre[i];
            offs[idx] = o;
            cur[idx]  = o;
        }
    }
    if (tid == 1023) offs[NN] = part[1023];
}

__global__ __launch_bounds__(256) void fill_kernel(const int* __restrict__ dst,
                                                   int* __restrict__ cur,
                                                   int* __restrict__ elist)
{
    int e = blockIdx.x * 256 + threadIdx.x;
    if (e < EE) {
        int p = atomicAdd(&cur[dst[e]], 1);
        elist[p] = e;
    }
}

// ---------------------------------------------------------------------------
// K3: GAT scatter-softmax + aggregate + bias + ELU
// One block per (n, b); 128 threads (d); edges OUTER, t INNER (acc/den in regs)
// -> per edge, the 12 hx rows are 6KB contiguous; elist/src read once per edge.
// softmax without max-subtract: shift-invariant, |alpha| < ~1 by construction
// ---------------------------------------------------------------------------
__global__ __launch_bounds__(128) void gat_kernel(
    const float* __restrict__ hx, const float* __restrict__ a_srcT,
    const float* __restrict__ a_dstT, const int* __restrict__ src_arr,
    const float* __restrict__ ew, const float* __restrict__ s_h,
    const int* __restrict__ offs, const int* __restrict__ elist,
    const float* __restrict__ gat_bias, float* __restrict__ gnn)
{
    const int blk = blockIdx.x;                // n*B + b
    const int n = blk >> 1;
    const int b = blk & 1;
    const int d = threadIdx.x;
    const int h = d >> 5;
    const int e0 = offs[n], e1 = offs[n + 1];
    const float sh = s_h[h];
    const float bias = gat_bias[d];

    const size_t base_dst = (size_t)(b * NN + n) * TT;   // row block for dst
    float ad[TT];
    #pragma unroll
    for (int t = 0; t < TT; ++t) ad[t] = a_dstT[(base_dst + t) * HH + h];

    float den[TT], acc[TT];
    #pragma unroll
    for (int t = 0; t < TT; ++t) { den[t] = 0.f; acc[t] = 0.f; }

    for (int ii = e0; ii < e1; ++ii) {
        int e = elist[ii];
        int s = src_arr[e];
        float aew = ew[e] * sh;
        const size_t base_src = (size_t)(b * NN + s) * TT;
        #pragma unroll
        for (int t = 0; t < TT; ++t) {
            float al = a_srcT[(base_src + t) * HH + h] + ad[t] + aew;
            al = (al >= 0.f) ? al : 0.2f * al;           // leaky_relu
            float exv = expf(al);
            den[t] += exv;
            acc[t] += exv * hx[(base_src + t) * DD + d];
        }
    }
    #pragma unroll
    for (int t = 0; t < TT; ++t) {
        float g = acc[t] / (den[t] + 1e-16f) + bias;
        gnn[(base_dst + t) * DD + d] = (g > 0.f) ? g : expm1f(g);   // ELU
    }
}

// ---------------------------------------------------------------------------
// K5: fused LSTM (12 steps) + LayerNorm + Linear/ReLU + Linear head.
// Row-local recurrence => no inter-block sync needed.
// Block: 512 threads, 16 rows. Thread (ti,tj) computes 4 rows x 4 gate-cols.
// ---------------------------------------------------------------------------
#define LSTM_R 16
__global__ __launch_bounds__(512) void lstm_head_kernel(
    const float* __restrict__ gnn,    // [B*N][T][128]
    const float* __restrict__ W_ihT,  // [128][512]
    const float* __restrict__ W_hhT,  // [128][512]
    const float* __restrict__ bias_s, // [512]
    const float* __restrict__ ln_g, const float* __restrict__ ln_b,
    const float* __restrict__ W1, const float* __restrict__ b1,
    const float* __restrict__ W2, const float* __restrict__ b2,
    float* __restrict__ out)          // [B*N][HORZ]
{
    __shared__ float xbT[128][20];    // [k][row], pad 20 keeps float4 align
    __shared__ float hbT[128][20];
    __shared__ float gb[LSTM_R][512]; // gate buffer; reused by head

    const int tid = threadIdx.x;
    const int r0  = blockIdx.x * LSTM_R;
    const int ti  = tid >> 7;          // row group 0..3  (rows ti*4..ti*4+3)
    const int tj  = tid & 127;         // col group       (cols tj*4..tj*4+3)

    for (int idx = tid; idx < 128 * 20; idx += 512) (&hbT[0][0])[idx] = 0.f;
    float c4[4] = {0.f, 0.f, 0.f, 0.f};
    __syncthreads();

    float4 bv = *(const float4*)&bias_s[tj * 4];
    const float* Wip = W_ihT + tj * 4;
    const float* Whp = W_hhT + tj * 4;

    for (int t = 0; t < TT; ++t) {
        // stage x tile transposed: xbT[k][row]
        for (int idx = tid; idx < LSTM_R * 128; idx += 512) {
            int row = idx >> 7, k = idx & 127;
            xbT[k][row] = gnn[((size_t)(r0 + row) * TT + t) * DD + k];
        }
        __syncthreads();

        float acc[4][4];
        #pragma unroll
        for (int i = 0; i < 4; ++i) {
            acc[i][0] = bv.x; acc[i][1] = bv.y; acc[i][2] = bv.z; acc[i][3] = bv.w;
        }
        #pragma unroll 8
        for (int k = 0; k < 128; ++k) {
            float4 w  = *(const float4*)(Wip + k * 512);
            float4 xv = *(const float4*)&xbT[k][ti * 4];
            float xr_[4] = {xv.x, xv.y, xv.z, xv.w};
            float wr_[4] = {w.x, w.y, w.z, w.w};
            #pragma unroll
            for (int i = 0; i < 4; ++i)
                #pragma unroll
                for (int q = 0; q < 4; ++q) acc[i][q] += xr_[i] * wr_[q];
        }
        #pragma unroll 8
        for (int k = 0; k < 128; ++k) {
            float4 w  = *(const float4*)(Whp + k * 512);
            float4 hv = *(const float4*)&hbT[k][ti * 4];
            float hr_[4] = {hv.x, hv.y, hv.z, hv.w};
            float wr_[4] = {w.x, w.y, w.z, w.w};
            #pragma unroll
            for (int i = 0; i < 4; ++i)
                #pragma unroll
                for (int q = 0; q < 4; ++q) acc[i][q] += hr_[i] * wr_[q];
        }
        #pragma unroll
        for (int i = 0; i < 4; ++i) {
            float4 gv;
            gv.x = acc[i][0]; gv.y = acc[i][1]; gv.z = acc[i][2]; gv.w = acc[i][3];
            *(float4*)&gb[ti * 4 + i][tj * 4] = gv;
        }
        __syncthreads();

        // gate nonlinearity + state update; thread owns 4 (row,d) pairs
        #pragma unroll
        for (int s = 0; s < 4; ++s) {
            int linear = tid + s * 512;
            int row = linear >> 7, d = linear & 127;
            float ig = gb[row][d];
            float fg = gb[row][128 + d];
            float gg = gb[row][256 + d];
            float og = gb[row][384 + d];
            float c = sigf(fg) * c4[s] + sigf(ig) * tanhf(gg);
            float hny = sigf(og) * tanhf(c);
            c4[s] = c;
            hbT[d][row] = hny;
        }
        __syncthreads();
    }

    // ---- head: LayerNorm -> Linear(128,128)+ReLU -> Linear(128,12) ----
    float* lnbuf = &gb[0][0];          // 16*128
    float* zbuf  = lnbuf + LSTM_R * 128;

    {
        const int row  = tid >> 5;     // 0..15
        const int lane = tid & 31;
        float v[4];
        #pragma unroll
        for (int s = 0; s < 4; ++s) v[s] = hbT[lane + s * 32][row];
        float sum = v[0] + v[1] + v[2] + v[3];
        for (int off = 16; off; off >>= 1) sum += __shfl_xor(sum, off, 32);
        float mu = sum * (1.f / 128.f);
        float var = 0.f;
        #pragma unroll
        for (int s = 0; s < 4; ++s) { float dv = v[s] - mu; var += dv * dv; }
        for (int off = 16; off; off >>= 1) var += __shfl_xor(var, off, 32);
        float rstd = rsqrtf(var * (1.f / 128.f) + 1e-5f);
        #pragma unroll
        for (int s = 0; s < 4; ++s) {
            int d = lane + s * 32;
            lnbuf[row * 128 + d] = (v[s] - mu) * rstd * ln_g[d] + ln_b[d];
        }
    }
    __syncthreads();

    {
        float zv[4];
        #pragma unroll
        for (int s = 0; s < 4; ++s) {
            int linear = tid + s * 512;
            int r2 = linear >> 7, j = linear & 127;
            float a = b1[j];
            #pragma unroll 4
            for (int k = 0; k < 128; ++k) a += lnbuf[r2 * 128 + k] * W1[k * 128 + j];
            zv[s] = fmaxf(a, 0.f);
        }
        #pragma unroll
        for (int s = 0; s < 4; ++s) zbuf[tid + s * 512] = zv[s];
    }
    __syncthreads();

    if (tid < LSTM_R * HORZ) {
        int r2 = tid / HORZ, o = tid % HORZ;
        float a = b2[o];
        #pragma unroll 4
        for (int k = 0; k < 128; ++k) a += zbuf[r2 * 128 + k] * W2[k * HORZ + o];
        out[(size_t)(r0 + r2) * HORZ + o] = a;
    }
}

// ---------------------------------------------------------------------------
extern "C" void kernel_launch(void* const* d_in, const int* in_sizes, int n_in,
                              void* d_out, int out_size, void* d_ws, size_t ws_size,
                              hipStream_t stream)
{
    const float* x        = (const float*)d_in[0];
    const int*   eidx     = (const int*)d_in[1];
    const float* ew       = (const float*)d_in[2];
    const float* W_lin    = (const float*)d_in[3];
    const float* att_src  = (const float*)d_in[4];
    const float* att_dst  = (const float*)d_in[5];
    const float* W_edge   = (const float*)d_in[6];
    const float* att_edge = (const float*)d_in[7];
    const float* gat_bias = (const float*)d_in[8];
    const float* W_ih     = (const float*)d_in[9];
    const float* W_hh     = (const float*)d_in[10];
    const float* b_ih     = (const float*)d_in[11];
    const float* b_hh     = (const float*)d_in[12];
    const float* ln_g     = (const float*)d_in[13];
    const float* ln_b     = (const float*)d_in[14];
    const float* W1       = (const float*)d_in[15];
    const float* b1       = (const float*)d_in[16];
    const float* W2       = (const float*)d_in[17];
    const float* b2       = (const float*)d_in[18];
    float* out = (float*)d_out;

    float* ws = (float*)d_ws;
    float* hx      = ws;                          // 15,360,000
    float* gnn     = hx + (size_t)15360000;       // 15,360,000
    float* a_srcT  = gnn + (size_t)15360000;      // 480,000
    float* a_dstT  = a_srcT + 480000;             // 480,000
    float* W_ihT   = a_dstT + 480000;             // 65,536
    float* W_hhT   = W_ihT + 65536;               // 65,536
    float* bias_s  = W_hhT + 65536;               // 512
    float* s_h     = bias_s + 512;                // 16 (4 used)
    int*   counts  = (int*)(s_h + 16);            // 5000
    int*   offs    = counts + NN;                 // 5008 (5001 used)
    int*   cur     = offs + (NN + 8);             // 5000
    int*   elist   = cur + NN;                    // 40000

    const int* srcA = eidx;
    const int* dstA = eidx + EE;

    hipMemsetAsync(counts, 0, NN * sizeof(int), stream);
    prep_small<<<1, 512, 0, stream>>>(W_edge, att_edge, b_ih, b_hh, s_h, bias_s);
    transpose_w<<<256, 256, 0, stream>>>(W_ih, W_hh, W_ihT, W_hhT);
    hx_kernel<<<BB * NN * TT, 128, 0, stream>>>(x, W_lin, att_src, att_dst,
                                                hx, a_srcT, a_dstT);
    count_kernel<<<(EE + 255) / 256, 256, 0, stream>>>(dstA, counts);
    scan_kernel<<<1, 1024, 0, stream>>>(counts, offs, cur);
    fill_kernel<<<(EE + 255) / 256, 256, 0, stream>>>(dstA, cur, elist);
    gat_kernel<<<NN * BB, 128, 0, stream>>>(hx, a_srcT, a_dstT, srcA, ew, s_h,
                                            offs, elist, gat_bias, gnn);
    lstm_head_kernel<<<(BB * NN) / LSTM_R, 512, 0, stream>>>(
        gnn, W_ihT, W_hhT, bias_s, ln_g, ln_b, W1, b1, W2, b2, out);
}

// Round 3
// 802.663 us; speedup vs baseline: 1.1629x; 1.1629x over previous
//
#include <hip/hip_runtime.h>
#include <math.h>

// Problem constants (fixed shapes)
#define BB  2
#define NN  5000
#define EE  40000
#define TT  12
#define FF  16
#define DD  128
#define HH  4
#define HORZ 12

typedef short bf16x8 __attribute__((ext_vector_type(8)));
typedef float f32x4  __attribute__((ext_vector_type(4)));

__device__ __forceinline__ float sigf(float x) { return 1.f / (1.f + expf(-x)); }

__device__ __forceinline__ unsigned short f2bf(float f) {
    unsigned int u = __float_as_uint(f);
    unsigned int r = (u + 0x7fffu + ((u >> 16) & 1u)) >> 16;   // RNE
    return (unsigned short)r;
}
__device__ __forceinline__ float bf2f(unsigned short h) {
    return __uint_as_float(((unsigned int)h) << 16);
}

// ---------------------------------------------------------------------------
// K0a: tiny prep — s_h[h] = sum_c W_edge[h*32+c]*att_edge[h*32+c]; bias_sum
// ---------------------------------------------------------------------------
__global__ __launch_bounds__(512) void prep_small(
    const float* __restrict__ W_edge, const float* __restrict__ att_edge,
    const float* __restrict__ b_ih, const float* __restrict__ b_hh,
    float* __restrict__ s_h, float* __restrict__ bias_sum)
{
    int tid = threadIdx.x;
    if (tid < 128) {
        float v = W_edge[tid] * att_edge[tid];
        for (int off = 16; off; off >>= 1) v += __shfl_xor(v, off, 32);
        if ((tid & 31) == 0) s_h[tid >> 5] = v;
    }
    bias_sum[tid] = b_ih[tid] + b_hh[tid];
}

// ---------------------------------------------------------------------------
// K0b: pack W_ih / W_hh into per-lane MFMA fragment order, split bf16 hi/lo.
// B-frag for (ct, ks): lane L holds col = ct*16+(L&15), k = ks*32+(L>>4)*8+j.
// Array: WF[(((ct*4)+ks)*64 + lane)*8 + j]. k-map matches A-side loads, so the
// MFMA k-permutation is consistent on both operands (dot product invariant).
// ---------------------------------------------------------------------------
__global__ __launch_bounds__(256) void wfrag_kernel(
    const float* __restrict__ W_ih, const float* __restrict__ W_hh,
    unsigned short* __restrict__ WxF_hi, unsigned short* __restrict__ WxF_lo,
    unsigned short* __restrict__ WhF_hi, unsigned short* __restrict__ WhF_lo)
{
    int gidx = blockIdx.x * 256 + threadIdx.x;    // 0..8191 : (ct,ks,lane)
    if (gidx >= 32 * 4 * 64) return;
    int lane = gidx & 63;
    int ks   = (gidx >> 6) & 3;
    int ct   = gidx >> 8;
    int col  = ct * 16 + (lane & 15);
    #pragma unroll
    for (int j = 0; j < 8; ++j) {
        int k = ks * 32 + (lane >> 4) * 8 + j;
        int o = gidx * 8 + j;
        float vx = W_ih[col * DD + k];
        unsigned short xh = f2bf(vx);
        WxF_hi[o] = xh;
        WxF_lo[o] = f2bf(vx - bf2f(xh));
        float vh = W_hh[col * DD + k];
        unsigned short hh = f2bf(vh);
        WhF_hi[o] = hh;
        WhF_lo[o] = f2bf(vh - bf2f(hh));
    }
}

// ---------------------------------------------------------------------------
// K1: hx = x @ W_lin  (row per block), plus a_src/a_dst per-head reductions
// ---------------------------------------------------------------------------
__global__ __launch_bounds__(128) void hx_kernel(
    const float* __restrict__ x, const float* __restrict__ W_lin,
    const float* __restrict__ att_src, const float* __restrict__ att_dst,
    float* __restrict__ hx, float* __restrict__ a_srcT, float* __restrict__ a_dstT)
{
    const int rt = blockIdx.x;                 // (b*N+n)*T+t, 0..119999
    const int d  = threadIdx.x;                // 0..127, h = d>>5, c = d&31
    const float* xr = x + (size_t)rt * FF;
    float acc = 0.f;
    #pragma unroll
    for (int f = 0; f < FF; ++f) acc += xr[f] * W_lin[f * DD + d];
    hx[(size_t)rt * DD + d] = acc;
    float vs = acc * att_src[d];
    float vd = acc * att_dst[d];
    for (int off = 16; off; off >>= 1) {
        vs += __shfl_xor(vs, off, 32);
        vd += __shfl_xor(vd, off, 32);
    }
    if ((d & 31) == 0) {
        int h = d >> 5;
        a_srcT[(size_t)rt * HH + h] = vs;
        a_dstT[(size_t)rt * HH + h] = vd;
    }
}

// ---------------------------------------------------------------------------
// K2: CSR build (count -> scan -> fill)
// ---------------------------------------------------------------------------
__global__ __launch_bounds__(256) void count_kernel(const int* __restrict__ dst,
                                                    int* __restrict__ counts)
{
    int e = blockIdx.x * 256 + threadIdx.x;
    if (e < EE) atomicAdd(&counts[dst[e]], 1);
}

__global__ __launch_bounds__(1024) void scan_kernel(const int* __restrict__ counts,
                                                    int* __restrict__ offs,
                                                    int* __restrict__ cur)
{
    __shared__ int part[1024];
    const int tid = threadIdx.x;
    const int CH = 5;
    int base = tid * CH;
    int pre[CH];
    int run = 0;
    #pragma unroll
    for (int i = 0; i < CH; ++i) {
        int idx = base + i;
        int v = (idx < NN) ? counts[idx] : 0;
        pre[i] = run;
        run += v;
    }
    part[tid] = run;
    __syncthreads();
    for (int off = 1; off < 1024; off <<= 1) {
        int v = (tid >= off) ? part[tid - off] : 0;
        __syncthreads();
        part[tid] += v;
        __syncthreads();
    }
    int prefix = (tid == 0) ? 0 : part[tid - 1];
    #pragma unroll
    for (int i = 0; i < CH; ++i) {
        int idx = base + i;
        if (idx < NN) {
            int o = prefix + pre[i];
            offs[idx] = o;
            cur[idx]  = o;
        }
    }
    if (tid == 1023) offs[NN] = part[1023];
}

__global__ __launch_bounds__(256) void fill_kernel(const int* __restrict__ dst,
                                                   int* __restrict__ cur,
                                                   int* __restrict__ elist)
{
    int e = blockIdx.x * 256 + threadIdx.x;
    if (e < EE) {
        int p = atomicAdd(&cur[dst[e]], 1);
        elist[p] = e;
    }
}

// ---------------------------------------------------------------------------
// K3: GAT scatter-softmax + aggregate + bias + ELU (edges outer, t inner)
// ---------------------------------------------------------------------------
__global__ __launch_bounds__(128) void gat_kernel(
    const float* __restrict__ hx, const float* __restrict__ a_srcT,
    const float* __restrict__ a_dstT, const int* __restrict__ src_arr,
    const float* __restrict__ ew, const float* __restrict__ s_h,
    const int* __restrict__ offs, const int* __restrict__ elist,
    const float* __restrict__ gat_bias, float* __restrict__ gnn)
{
    const int blk = blockIdx.x;                // n*B + b
    const int n = blk >> 1;
    const int b = blk & 1;
    const int d = threadIdx.x;
    const int h = d >> 5;
    const int e0 = offs[n], e1 = offs[n + 1];
    const float sh = s_h[h];
    const float bias = gat_bias[d];

    const size_t base_dst = (size_t)(b * NN + n) * TT;
    float ad[TT];
    #pragma unroll
    for (int t = 0; t < TT; ++t) ad[t] = a_dstT[(base_dst + t) * HH + h];

    float den[TT], acc[TT];
    #pragma unroll
    for (int t = 0; t < TT; ++t) { den[t] = 0.f; acc[t] = 0.f; }

    for (int ii = e0; ii < e1; ++ii) {
        int e = elist[ii];
        int s = src_arr[e];
        float aew = ew[e] * sh;
        const size_t base_src = (size_t)(b * NN + s) * TT;
        #pragma unroll
        for (int t = 0; t < TT; ++t) {
            float al = a_srcT[(base_src + t) * HH + h] + ad[t] + aew;
            al = (al >= 0.f) ? al : 0.2f * al;
            float exv = expf(al);
            den[t] += exv;
            acc[t] += exv * hx[(base_src + t) * DD + d];
        }
    }
    #pragma unroll
    for (int t = 0; t < TT; ++t) {
        float g = acc[t] / (den[t] + 1e-16f) + bias;
        gnn[(base_dst + t) * DD + d] = (g > 0.f) ? g : expm1f(g);
    }
}

// ---------------------------------------------------------------------------
// K5: fused LSTM via split-bf16 MFMA + head.
// Block = 512 thr (8 waves), 16 rows. Wave w owns gate col-tiles w*4..w*4+3.
// W_hh fragments resident in VGPRs; W_ih fragments streamed from L2 per step.
// 3-term split: ah*bh + ah*bl + al*bh  (rel err ~2^-16).
// h stored in LDS as bf16 hi/lo, XOR-swizzled (G4) for conflict-free b128.
// ---------------------------------------------------------------------------
#define LR 16
__global__ __launch_bounds__(512, 2) void lstm_mfma_head(
    const float* __restrict__ gnn,           // [10000*12][128]
    const unsigned short* __restrict__ WxF_hi, const unsigned short* __restrict__ WxF_lo,
    const unsigned short* __restrict__ WhF_hi, const unsigned short* __restrict__ WhF_lo,
    const float* __restrict__ bias_s,
    const float* __restrict__ ln_g, const float* __restrict__ ln_b,
    const float* __restrict__ W1, const float* __restrict__ b1,
    const float* __restrict__ W2, const float* __restrict__ b2,
    float* __restrict__ out)
{
    __shared__ float gb[LR][520];            // gates, padded stride vs conflicts
    __shared__ unsigned short h_hi[LR * 128];  // swizzled bf16 hi of h
    __shared__ unsigned short h_lo[LR * 128];  // swizzled bf16 lo of h

    const int tid  = threadIdx.x;
    const int wv   = tid >> 6;               // wave 0..7
    const int lane = tid & 63;
    const int l15  = lane & 15;
    const int g    = lane >> 4;              // 0..3
    const int r0   = blockIdx.x * LR;

    for (int i = tid; i < LR * 128; i += 512) { h_hi[i] = 0; h_lo[i] = 0; }

    // resident W_hh fragments (hi, lo): 4 col-tiles x 4 k-steps
    bf16x8 whh[4][4], whl[4][4];
    #pragma unroll
    for (int ct = 0; ct < 4; ++ct)
        #pragma unroll
        for (int ks = 0; ks < 4; ++ks) {
            int fidx = (((wv * 4 + ct) * 4 + ks) * 64 + lane) * 8;
            whh[ct][ks] = *(const bf16x8*)&WhF_hi[fidx];
            whl[ct][ks] = *(const bf16x8*)&WhF_lo[fidx];
        }
    float bias[4];
    #pragma unroll
    for (int ct = 0; ct < 4; ++ct) bias[ct] = bias_s[(wv * 4 + ct) * 16 + l15];

    float c4[4] = {0.f, 0.f, 0.f, 0.f};
    __syncthreads();

    for (int t = 0; t < TT; ++t) {
        // ---- A-frags for x_t: direct global read + split (row = r0+l15) ----
        const float* xrow = gnn + ((size_t)(r0 + l15) * TT + t) * DD;
        bf16x8 xa_h[4], xa_l[4];
        #pragma unroll
        for (int ks = 0; ks < 4; ++ks) {
            int k0 = ks * 32 + g * 8;
            float4 v0 = *(const float4*)(xrow + k0);
            float4 v1 = *(const float4*)(xrow + k0 + 4);
            float vv[8] = {v0.x, v0.y, v0.z, v0.w, v1.x, v1.y, v1.z, v1.w};
            bf16x8 hh8, ll8;
            #pragma unroll
            for (int e = 0; e < 8; ++e) {
                unsigned short hb = f2bf(vv[e]);
                hh8[e] = (short)hb;
                ll8[e] = (short)f2bf(vv[e] - bf2f(hb));
            }
            xa_h[ks] = hh8;
            xa_l[ks] = ll8;
        }

        // ---- x-part: acc = bias + x @ Wx  (Wx frags streamed from L2) ----
        f32x4 acc[4];
        #pragma unroll
        for (int ct = 0; ct < 4; ++ct) {
            f32x4 a;
            a[0] = bias[ct]; a[1] = bias[ct]; a[2] = bias[ct]; a[3] = bias[ct];
            #pragma unroll
            for (int ks = 0; ks < 4; ++ks) {
                int fidx = (((wv * 4 + ct) * 4 + ks) * 64 + lane) * 8;
                bf16x8 bh = *(const bf16x8*)&WxF_hi[fidx];
                bf16x8 bl = *(const bf16x8*)&WxF_lo[fidx];
                a = __builtin_amdgcn_mfma_f32_16x16x32_bf16(xa_h[ks], bh, a, 0, 0, 0);
                a = __builtin_amdgcn_mfma_f32_16x16x32_bf16(xa_h[ks], bl, a, 0, 0, 0);
                a = __builtin_amdgcn_mfma_f32_16x16x32_bf16(xa_l[ks], bh, a, 0, 0, 0);
            }
            acc[ct] = a;
        }

        // ---- h-part: acc += h @ Wh  (resident frags; skip t=0, h==0) ----
        if (t > 0) {
            #pragma unroll
            for (int ks = 0; ks < 4; ++ks) {
                int byte = l15 * 256 + (ks * 32 + g * 8) * 2;
                int sw = byte ^ ((l15 & 7) << 4);
                bf16x8 ah = *(const bf16x8*)((const char*)h_hi + sw);
                bf16x8 al = *(const bf16x8*)((const char*)h_lo + sw);
                #pragma unroll
                for (int ct = 0; ct < 4; ++ct) {
                    acc[ct] = __builtin_amdgcn_mfma_f32_16x16x32_bf16(ah, whh[ct][ks], acc[ct], 0, 0, 0);
                    acc[ct] = __builtin_amdgcn_mfma_f32_16x16x32_bf16(ah, whl[ct][ks], acc[ct], 0, 0, 0);
                    acc[ct] = __builtin_amdgcn_mfma_f32_16x16x32_bf16(al, whh[ct][ks], acc[ct], 0, 0, 0);
                }
            }
        }

        // ---- write gates to LDS (D-layout: col=lane&15, row=g*4+i) ----
        #pragma unroll
        for (int ct = 0; ct < 4; ++ct) {
            int col = (wv * 4 + ct) * 16 + l15;
            #pragma unroll
            for (int i = 0; i < 4; ++i) gb[g * 4 + i][col] = acc[ct][i];
        }
        __syncthreads();

        // ---- gate nonlinearity + state update (thread owns 4 (row,d)) ----
        #pragma unroll
        for (int s = 0; s < 4; ++s) {
            int lin = tid + s * 512;
            int row = lin >> 7, d = lin & 127;
            float ig = gb[row][d];
            float fg = gb[row][128 + d];
            float gg = gb[row][256 + d];
            float og = gb[row][384 + d];
            float c = sigf(fg) * c4[s] + sigf(ig) * tanhf(gg);
            float hv = sigf(og) * tanhf(c);
            c4[s] = c;
            unsigned short hb = f2bf(hv);
            unsigned short lb = f2bf(hv - bf2f(hb));
            int byte = row * 256 + d * 2;
            int sw = byte ^ ((row & 7) << 4);
            *(unsigned short*)((char*)h_hi + sw) = hb;
            *(unsigned short*)((char*)h_lo + sw) = lb;
        }
        __syncthreads();
    }

    // ---- head: LayerNorm -> Linear(128,128)+ReLU -> Linear(128,12) ----
    float* lnbuf = &gb[0][0];
    float* zbuf  = lnbuf + LR * 128;

    {
        const int row    = tid >> 5;
        const int lane32 = tid & 31;
        float v[4];
        #pragma unroll
        for (int s = 0; s < 4; ++s) {
            int d = lane32 + s * 32;
            int byte = row * 256 + d * 2;
            int sw = byte ^ ((row & 7) << 4);
            v[s] = bf2f(*(const unsigned short*)((const char*)h_hi + sw)) +
                   bf2f(*(const unsigned short*)((const char*)h_lo + sw));
        }
        float sum = v[0] + v[1] + v[2] + v[3];
        for (int off = 16; off; off >>= 1) sum += __shfl_xor(sum, off, 32);
        float mu = sum * (1.f / 128.f);
        float var = 0.f;
        #pragma unroll
        for (int s = 0; s < 4; ++s) { float dv = v[s] - mu; var += dv * dv; }
        for (int off = 16; off; off >>= 1) var += __shfl_xor(var, off, 32);
        float rstd = rsqrtf(var * (1.f / 128.f) + 1e-5f);
        #pragma unroll
        for (int s = 0; s < 4; ++s) {
            int d = lane32 + s * 32;
            lnbuf[row * 128 + d] = (v[s] - mu) * rstd * ln_g[d] + ln_b[d];
        }
    }
    __syncthreads();

    {
        float zv[4];
        #pragma unroll
        for (int s = 0; s < 4; ++s) {
            int lin = tid + s * 512;
            int r2 = lin >> 7, j = lin & 127;
            float a = b1[j];
            #pragma unroll 4
            for (int k = 0; k < 128; ++k) a += lnbuf[r2 * 128 + k] * W1[k * 128 + j];
            zv[s] = fmaxf(a, 0.f);
        }
        #pragma unroll
        for (int s = 0; s < 4; ++s) zbuf[tid + s * 512] = zv[s];
    }
    __syncthreads();

    if (tid < LR * HORZ) {
        int r2 = tid / HORZ, o = tid % HORZ;
        float a = b2[o];
        #pragma unroll 4
        for (int k = 0; k < 128; ++k) a += zbuf[r2 * 128 + k] * W2[k * HORZ + o];
        out[(size_t)(r0 + r2) * HORZ + o] = a;
    }
}

// ---------------------------------------------------------------------------
extern "C" void kernel_launch(void* const* d_in, const int* in_sizes, int n_in,
                              void* d_out, int out_size, void* d_ws, size_t ws_size,
                              hipStream_t stream)
{
    const float* x        = (const float*)d_in[0];
    const int*   eidx     = (const int*)d_in[1];
    const float* ew       = (const float*)d_in[2];
    const float* W_lin    = (const float*)d_in[3];
    const float* att_src  = (const float*)d_in[4];
    const float* att_dst  = (const float*)d_in[5];
    const float* W_edge   = (const float*)d_in[6];
    const float* att_edge = (const float*)d_in[7];
    const float* gat_bias = (const float*)d_in[8];
    const float* W_ih     = (const float*)d_in[9];
    const float* W_hh     = (const float*)d_in[10];
    const float* b_ih     = (const float*)d_in[11];
    const float* b_hh     = (const float*)d_in[12];
    const float* ln_g     = (const float*)d_in[13];
    const float* ln_b     = (const float*)d_in[14];
    const float* W1       = (const float*)d_in[15];
    const float* b1       = (const float*)d_in[16];
    const float* W2       = (const float*)d_in[17];
    const float* b2       = (const float*)d_in[18];
    float* out = (float*)d_out;

    float* ws = (float*)d_ws;
    float* hx      = ws;                          // 15,360,000 f32
    float* gnn     = hx + (size_t)15360000;       // 15,360,000 f32
    float* a_srcT  = gnn + (size_t)15360000;      // 480,000
    float* a_dstT  = a_srcT + 480000;             // 480,000
    float* bias_s  = a_dstT + 480000;             // 512
    float* s_h     = bias_s + 512;                // 16 (4 used)
    unsigned short* WxF_hi = (unsigned short*)(s_h + 16);   // 65536 u16
    unsigned short* WxF_lo = WxF_hi + 65536;
    unsigned short* WhF_hi = WxF_lo + 65536;
    unsigned short* WhF_lo = WhF_hi + 65536;
    int*   counts  = (int*)(WhF_lo + 65536);      // 5000
    int*   offs    = counts + NN;                 // 5001 (+pad)
    int*   cur     = offs + (NN + 8);             // 5000
    int*   elist   = cur + NN;                    // 40000

    const int* srcA = eidx;
    const int* dstA = eidx + EE;

    hipMemsetAsync(counts, 0, NN * sizeof(int), stream);
    prep_small<<<1, 512, 0, stream>>>(W_edge, att_edge, b_ih, b_hh, s_h, bias_s);
    wfrag_kernel<<<32, 256, 0, stream>>>(W_ih, W_hh, WxF_hi, WxF_lo, WhF_hi, WhF_lo);
    hx_kernel<<<BB * NN * TT, 128, 0, stream>>>(x, W_lin, att_src, att_dst,
                                                hx, a_srcT, a_dstT);
    count_kernel<<<(EE + 255) / 256, 256, 0, stream>>>(dstA, counts);
    scan_kernel<<<1, 1024, 0, stream>>>(counts, offs, cur);
    fill_kernel<<<(EE + 255) / 256, 256, 0, stream>>>(dstA, cur, elist);
    gat_kernel<<<NN * BB, 128, 0, stream>>>(hx, a_srcT, a_dstT, srcA, ew, s_h,
                                            offs, elist, gat_bias, gnn);
    lstm_mfma_head<<<(BB * NN) / LR, 512, 0, stream>>>(
        gnn, WxF_hi, WxF_lo, WhF_hi, WhF_lo, bias_s,
        ln_g, ln_b, W1, b1, W2, b2, out);
}

// Round 4
// 800.084 us; speedup vs baseline: 1.1666x; 1.0032x over previous
//
#include <hip/hip_runtime.h>
#include <math.h>

// Problem constants (fixed shapes)
#define BB  2
#define NN  5000
#define EE  40000
#define TT  12
#define FF  16
#define DD  128
#define HH  4
#define HORZ 12
#define NSEQ (BB * NN)          // 10000
#define MROWS (NSEQ * TT)       // 120000

typedef short bf16x8 __attribute__((ext_vector_type(8)));
typedef float f32x4  __attribute__((ext_vector_type(4)));

__device__ __forceinline__ float sigf(float x) { return 1.f / (1.f + expf(-x)); }

__device__ __forceinline__ unsigned short f2bf(float f) {
    unsigned int u = __float_as_uint(f);
    unsigned int r = (u + 0x7fffu + ((u >> 16) & 1u)) >> 16;   // RNE
    return (unsigned short)r;
}
__device__ __forceinline__ float bf2f(unsigned short h) {
    return __uint_as_float(((unsigned int)h) << 16);
}

// ---------------------------------------------------------------------------
// K0a: tiny prep
// ---------------------------------------------------------------------------
__global__ __launch_bounds__(512) void prep_small(
    const float* __restrict__ W_edge, const float* __restrict__ att_edge,
    const float* __restrict__ b_ih, const float* __restrict__ b_hh,
    float* __restrict__ s_h, float* __restrict__ bias_sum)
{
    int tid = threadIdx.x;
    if (tid < 128) {
        float v = W_edge[tid] * att_edge[tid];
        for (int off = 16; off; off >>= 1) v += __shfl_xor(v, off, 32);
        if ((tid & 31) == 0) s_h[tid >> 5] = v;
    }
    bias_sum[tid] = b_ih[tid] + b_hh[tid];
}

// ---------------------------------------------------------------------------
// K0b: pack W_ih / W_hh into per-lane MFMA fragment order, split bf16 hi/lo.
// frag (ct,ks): lane L holds col=(wv*4+ct)*16+(L&15), k=ks*32+(L>>4)*8+j.
// ---------------------------------------------------------------------------
__global__ __launch_bounds__(256) void wfrag_kernel(
    const float* __restrict__ W_ih, const float* __restrict__ W_hh,
    unsigned short* __restrict__ WxF_hi, unsigned short* __restrict__ WxF_lo,
    unsigned short* __restrict__ WhF_hi, unsigned short* __restrict__ WhF_lo)
{
    int gidx = blockIdx.x * 256 + threadIdx.x;    // 0..8191 : (cg,ks,lane)
    if (gidx >= 32 * 4 * 64) return;
    int lane = gidx & 63;
    int ks   = (gidx >> 6) & 3;
    int cg   = gidx >> 8;                          // global col-tile 0..31
    int col  = cg * 16 + (lane & 15);
    #pragma unroll
    for (int j = 0; j < 8; ++j) {
        int k = ks * 32 + (lane >> 4) * 8 + j;
        int o = gidx * 8 + j;
        float vx = W_ih[col * DD + k];
        unsigned short xh = f2bf(vx);
        WxF_hi[o] = xh;
        WxF_lo[o] = f2bf(vx - bf2f(xh));
        float vh = W_hh[col * DD + k];
        unsigned short hh = f2bf(vh);
        WhF_hi[o] = hh;
        WhF_lo[o] = f2bf(vh - bf2f(hh));
    }
}

// ---------------------------------------------------------------------------
// K1: hx = x @ W_lin (bf16 out) + a_src/a_dst per-head reductions (f32)
// ---------------------------------------------------------------------------
__global__ __launch_bounds__(128) void hx_kernel(
    const float* __restrict__ x, const float* __restrict__ W_lin,
    const float* __restrict__ att_src, const float* __restrict__ att_dst,
    unsigned short* __restrict__ hxb, float* __restrict__ a_srcT,
    float* __restrict__ a_dstT)
{
    const int rt = blockIdx.x;                 // (b*N+n)*T+t
    const int d  = threadIdx.x;
    const float* xr = x + (size_t)rt * FF;
    float acc = 0.f;
    #pragma unroll
    for (int f = 0; f < FF; ++f) acc += xr[f] * W_lin[f * DD + d];
    hxb[(size_t)rt * DD + d] = f2bf(acc);
    float vs = acc * att_src[d];
    float vd = acc * att_dst[d];
    for (int off = 16; off; off >>= 1) {
        vs += __shfl_xor(vs, off, 32);
        vd += __shfl_xor(vd, off, 32);
    }
    if ((d & 31) == 0) {
        int h = d >> 5;
        a_srcT[(size_t)rt * HH + h] = vs;
        a_dstT[(size_t)rt * HH + h] = vd;
    }
}

// ---------------------------------------------------------------------------
// K2: CSR build
// ---------------------------------------------------------------------------
__global__ __launch_bounds__(256) void count_kernel(const int* __restrict__ dst,
                                                    int* __restrict__ counts)
{
    int e = blockIdx.x * 256 + threadIdx.x;
    if (e < EE) atomicAdd(&counts[dst[e]], 1);
}

__global__ __launch_bounds__(1024) void scan_kernel(const int* __restrict__ counts,
                                                    int* __restrict__ offs,
                                                    int* __restrict__ cur)
{
    __shared__ int part[1024];
    const int tid = threadIdx.x;
    const int CH = 5;
    int base = tid * CH;
    int pre[CH];
    int run = 0;
    #pragma unroll
    for (int i = 0; i < CH; ++i) {
        int idx = base + i;
        int v = (idx < NN) ? counts[idx] : 0;
        pre[i] = run;
        run += v;
    }
    part[tid] = run;
    __syncthreads();
    for (int off = 1; off < 1024; off <<= 1) {
        int v = (tid >= off) ? part[tid - off] : 0;
        __syncthreads();
        part[tid] += v;
        __syncthreads();
    }
    int prefix = (tid == 0) ? 0 : part[tid - 1];
    #pragma unroll
    for (int i = 0; i < CH; ++i) {
        int idx = base + i;
        if (idx < NN) {
            int o = prefix + pre[i];
            offs[idx] = o;
            cur[idx]  = o;
        }
    }
    if (tid == 1023) offs[NN] = part[1023];
}

__global__ __launch_bounds__(256) void fill_kernel(const int* __restrict__ dst,
                                                   int* __restrict__ cur,
                                                   int* __restrict__ elist)
{
    int e = blockIdx.x * 256 + threadIdx.x;
    if (e < EE) {
        int p = atomicAdd(&cur[dst[e]], 1);
        elist[p] = e;
    }
}

// ---------------------------------------------------------------------------
// K3: GAT scatter-softmax + aggregate + bias + ELU. hx gather in bf16.
// tmaj=1: gnn written t-major [t][seq][128]; tmaj=0: seq-major [seq*T+t][128]
// ---------------------------------------------------------------------------
__global__ __launch_bounds__(128) void gat_kernel(
    const unsigned short* __restrict__ hxb, const float* __restrict__ a_srcT,
    const float* __restrict__ a_dstT, const int* __restrict__ src_arr,
    const float* __restrict__ ew, const float* __restrict__ s_h,
    const int* __restrict__ offs, const int* __restrict__ elist,
    const float* __restrict__ gat_bias, float* __restrict__ gnn, int tmaj)
{
    const int blk = blockIdx.x;                // n*B + b
    const int n = blk >> 1;
    const int b = blk & 1;
    const int d = threadIdx.x;
    const int h = d >> 5;
    const int e0 = offs[n], e1 = offs[n + 1];
    const float sh = s_h[h];
    const float bias = gat_bias[d];
    const int seq = b * NN + n;

    const size_t base_dst = (size_t)seq * TT;
    float ad[TT];
    #pragma unroll
    for (int t = 0; t < TT; ++t) ad[t] = a_dstT[(base_dst + t) * HH + h];

    float den[TT], acc[TT];
    #pragma unroll
    for (int t = 0; t < TT; ++t) { den[t] = 0.f; acc[t] = 0.f; }

    for (int ii = e0; ii < e1; ++ii) {
        int e = elist[ii];
        int s = src_arr[e];
        float aew = ew[e] * sh;
        const size_t base_src = (size_t)(b * NN + s) * TT;
        #pragma unroll
        for (int t = 0; t < TT; ++t) {
            float al = a_srcT[(base_src + t) * HH + h] + ad[t] + aew;
            al = (al >= 0.f) ? al : 0.2f * al;
            float exv = expf(al);
            den[t] += exv;
            acc[t] += exv * bf2f(hxb[(base_src + t) * DD + d]);
        }
    }
    #pragma unroll
    for (int t = 0; t < TT; ++t) {
        float g = acc[t] / (den[t] + 1e-16f) + bias;
        float o = (g > 0.f) ? g : expm1f(g);
        size_t gidx = tmaj ? ((size_t)t * NSEQ + seq) : (base_dst + t);
        gnn[gidx * DD + d] = o;
    }
}

// ---------------------------------------------------------------------------
// K4a (fast path): gx = bias + gnnT @ W_ihT via split-bf16 MFMA.
// Block: 512 thr, 64 flat rows (4 tiles of 16). Wx frags resident in VGPRs.
// Output in D-fragment order: gx[tile][wv][ct][g][l15][i] (float4/lane).
// ---------------------------------------------------------------------------
__global__ __launch_bounds__(512, 2) void gx_gemm(
    const float* __restrict__ gnnT,            // [120000][128], t-major rows
    const unsigned short* __restrict__ WxF_hi,
    const unsigned short* __restrict__ WxF_lo,
    const float* __restrict__ bias_s,
    float* __restrict__ gx)
{
    __shared__ unsigned short Ahi[64 * 128];   // 16 KB, XOR-swizzled
    __shared__ unsigned short Alo[64 * 128];

    const int tid  = threadIdx.x;
    const int wv   = tid >> 6;
    const int lane = tid & 63;
    const int l15  = lane & 15;
    const int g    = lane >> 4;
    const size_t fr0 = (size_t)blockIdx.x * 64;

    // stage A tile (64 rows x 128 k), split to bf16 hi/lo, swizzled
    #pragma unroll
    for (int c = 0; c < 2; ++c) {
        int linear = tid + c * 512;
        int row = linear >> 4;
        int k0  = (linear & 15) * 8;
        const float* src = gnnT + (fr0 + row) * DD + k0;
        float4 v0 = *(const float4*)src;
        float4 v1 = *(const float4*)(src + 4);
        float vv[8] = {v0.x, v0.y, v0.z, v0.w, v1.x, v1.y, v1.z, v1.w};
        bf16x8 h8, l8;
        #pragma unroll
        for (int e = 0; e < 8; ++e) {
            unsigned short hb = f2bf(vv[e]);
            h8[e] = (short)hb;
            l8[e] = (short)f2bf(vv[e] - bf2f(hb));
        }
        int byte = (row * 256 + k0 * 2) ^ ((row & 7) << 4);
        *(bf16x8*)((char*)Ahi + byte) = h8;
        *(bf16x8*)((char*)Alo + byte) = l8;
    }

    // resident Wx fragments
    bf16x8 wh[16], wl[16];
    #pragma unroll
    for (int ct = 0; ct < 4; ++ct)
        #pragma unroll
        for (int ks = 0; ks < 4; ++ks) {
            int fidx = (((wv * 4 + ct) * 4 + ks) * 64 + lane) * 8;
            wh[ct * 4 + ks] = *(const bf16x8*)&WxF_hi[fidx];
            wl[ct * 4 + ks] = *(const bf16x8*)&WxF_lo[fidx];
        }
    float bias[4];
    #pragma unroll
    for (int ct = 0; ct < 4; ++ct) bias[ct] = bias_s[(wv * 4 + ct) * 16 + l15];

    __syncthreads();

    #pragma unroll
    for (int ar = 0; ar < 4; ++ar) {
        bf16x8 ah[4], al[4];
        int row = ar * 16 + l15;
        #pragma unroll
        for (int ks = 0; ks < 4; ++ks) {
            int byte = (row * 256 + (ks * 32 + g * 8) * 2) ^ ((row & 7) << 4);
            ah[ks] = *(const bf16x8*)((const char*)Ahi + byte);
            al[ks] = *(const bf16x8*)((const char*)Alo + byte);
        }
        size_t tile = (size_t)blockIdx.x * 4 + ar;
        #pragma unroll
        for (int ct = 0; ct < 4; ++ct) {
            f32x4 a;
            a[0] = bias[ct]; a[1] = bias[ct]; a[2] = bias[ct]; a[3] = bias[ct];
            #pragma unroll
            for (int ks = 0; ks < 4; ++ks) {
                a = __builtin_amdgcn_mfma_f32_16x16x32_bf16(ah[ks], wh[ct * 4 + ks], a, 0, 0, 0);
                a = __builtin_amdgcn_mfma_f32_16x16x32_bf16(ah[ks], wl[ct * 4 + ks], a, 0, 0, 0);
                a = __builtin_amdgcn_mfma_f32_16x16x32_bf16(al[ks], wh[ct * 4 + ks], a, 0, 0, 0);
            }
            size_t elem = tile * 8192 + (size_t)((((wv * 4 + ct) * 4 + g) * 16 + l15) * 4);
            *(f32x4*)&gx[elem] = a;
        }
    }
}

// ---------------------------------------------------------------------------
// K4b (fast path): recurrent-only LSTM + head. W_hh resident in VGPRs;
// per step reads its gx fragment (coalesced float4) with 1-step prefetch.
// ---------------------------------------------------------------------------
__global__ __launch_bounds__(512, 2) void lstm_rec(
    const float* __restrict__ gx,
    const unsigned short* __restrict__ WhF_hi,
    const unsigned short* __restrict__ WhF_lo,
    const float* __restrict__ ln_g, const float* __restrict__ ln_b,
    const float* __restrict__ W1, const float* __restrict__ b1,
    const float* __restrict__ W2, const float* __restrict__ b2,
    float* __restrict__ out)
{
    __shared__ float gb[16][520];
    __shared__ unsigned short h_hi[16 * 128];
    __shared__ unsigned short h_lo[16 * 128];

    const int tid  = threadIdx.x;
    const int wv   = tid >> 6;
    const int lane = tid & 63;
    const int l15  = lane & 15;
    const int g    = lane >> 4;
    const int bk   = blockIdx.x;               // 0..624, rows bk*16..
    const int r0   = bk * 16;

    for (int i = tid; i < 16 * 128; i += 512) { h_hi[i] = 0; h_lo[i] = 0; }

    bf16x8 wh[16], wl[16];
    #pragma unroll
    for (int ct = 0; ct < 4; ++ct)
        #pragma unroll
        for (int ks = 0; ks < 4; ++ks) {
            int fidx = (((wv * 4 + ct) * 4 + ks) * 64 + lane) * 8;
            wh[ct * 4 + ks] = *(const bf16x8*)&WhF_hi[fidx];
            wl[ct * 4 + ks] = *(const bf16x8*)&WhF_lo[fidx];
        }

    float c4[4] = {0.f, 0.f, 0.f, 0.f};
    __syncthreads();

    const size_t lelem = (size_t)((((wv * 4) * 4 + g) * 16 + l15) * 4); // ct=0
    f32x4 cur[4], nxt[4];
    #pragma unroll
    for (int ct = 0; ct < 4; ++ct)
        cur[ct] = *(const f32x4*)&gx[(size_t)bk * 8192 + lelem + ct * 256];

    for (int t = 0; t < TT; ++t) {
        // prefetch next step's fragment (clamped; t=11 value unused)
        int tn = (t < TT - 1) ? t + 1 : t;
        size_t nbase = ((size_t)tn * 625 + bk) * 8192 + lelem;
        #pragma unroll
        for (int ct = 0; ct < 4; ++ct)
            nxt[ct] = *(const f32x4*)&gx[nbase + ct * 256];

        f32x4 acc[4];
        #pragma unroll
        for (int ct = 0; ct < 4; ++ct) acc[ct] = cur[ct];

        if (t > 0) {
            #pragma unroll
            for (int ks = 0; ks < 4; ++ks) {
                int byte = (l15 * 256 + (ks * 32 + g * 8) * 2) ^ ((l15 & 7) << 4);
                bf16x8 ah = *(const bf16x8*)((const char*)h_hi + byte);
                bf16x8 al = *(const bf16x8*)((const char*)h_lo + byte);
                #pragma unroll
                for (int ct = 0; ct < 4; ++ct) {
                    acc[ct] = __builtin_amdgcn_mfma_f32_16x16x32_bf16(ah, wh[ct * 4 + ks], acc[ct], 0, 0, 0);
                    acc[ct] = __builtin_amdgcn_mfma_f32_16x16x32_bf16(ah, wl[ct * 4 + ks], acc[ct], 0, 0, 0);
                    acc[ct] = __builtin_amdgcn_mfma_f32_16x16x32_bf16(al, wh[ct * 4 + ks], acc[ct], 0, 0, 0);
                }
            }
        }

        #pragma unroll
        for (int ct = 0; ct < 4; ++ct) {
            int col = (wv * 4 + ct) * 16 + l15;
            #pragma unroll
            for (int i = 0; i < 4; ++i) gb[g * 4 + i][col] = acc[ct][i];
        }
        __syncthreads();

        #pragma unroll
        for (int s = 0; s < 4; ++s) {
            int lin = tid + s * 512;
            int row = lin >> 7, d = lin & 127;
            float ig = gb[row][d];
            float fg = gb[row][128 + d];
            float gg = gb[row][256 + d];
            float og = gb[row][384 + d];
            float c = sigf(fg) * c4[s] + sigf(ig) * tanhf(gg);
            float hv = sigf(og) * tanhf(c);
            c4[s] = c;
            unsigned short hb = f2bf(hv);
            unsigned short lb = f2bf(hv - bf2f(hb));
            int byte = (row * 256 + d * 2) ^ ((row & 7) << 4);
            *(unsigned short*)((char*)h_hi + byte) = hb;
            *(unsigned short*)((char*)h_lo + byte) = lb;
        }
        __syncthreads();

        #pragma unroll
        for (int ct = 0; ct < 4; ++ct) cur[ct] = nxt[ct];
    }

    // ---- head ----
    float* lnbuf = &gb[0][0];
    float* zbuf  = lnbuf + 16 * 128;

    {
        const int row    = tid >> 5;
        const int lane32 = tid & 31;
        float v[4];
        #pragma unroll
        for (int s = 0; s < 4; ++s) {
            int d = lane32 + s * 32;
            int byte = (row * 256 + d * 2) ^ ((row & 7) << 4);
            v[s] = bf2f(*(const unsigned short*)((const char*)h_hi + byte)) +
                   bf2f(*(const unsigned short*)((const char*)h_lo + byte));
        }
        float sum = v[0] + v[1] + v[2] + v[3];
        for (int off = 16; off; off >>= 1) sum += __shfl_xor(sum, off, 32);
        float mu = sum * (1.f / 128.f);
        float var = 0.f;
        #pragma unroll
        for (int s = 0; s < 4; ++s) { float dv = v[s] - mu; var += dv * dv; }
        for (int off = 16; off; off >>= 1) var += __shfl_xor(var, off, 32);
        float rstd = rsqrtf(var * (1.f / 128.f) + 1e-5f);
        #pragma unroll
        for (int s = 0; s < 4; ++s) {
            int d = lane32 + s * 32;
            lnbuf[row * 128 + d] = (v[s] - mu) * rstd * ln_g[d] + ln_b[d];
        }
    }
    __syncthreads();

    {
        float zv[4];
        #pragma unroll
        for (int s = 0; s < 4; ++s) {
            int lin = tid + s * 512;
            int r2 = lin >> 7, j = lin & 127;
            float a = b1[j];
            #pragma unroll 4
            for (int k = 0; k < 128; ++k) a += lnbuf[r2 * 128 + k] * W1[k * 128 + j];
            zv[s] = fmaxf(a, 0.f);
        }
        #pragma unroll
        for (int s = 0; s < 4; ++s) zbuf[tid + s * 512] = zv[s];
    }
    __syncthreads();

    if (tid < 16 * HORZ) {
        int r2 = tid / HORZ, o = tid % HORZ;
        float a = b2[o];
        #pragma unroll 4
        for (int k = 0; k < 128; ++k) a += zbuf[r2 * 128 + k] * W2[k * HORZ + o];
        out[(size_t)(r0 + r2) * HORZ + o] = a;
    }
}

// ---------------------------------------------------------------------------
// Fallback (ws too small): fused LSTM from round 3 (seq-major gnn).
// ---------------------------------------------------------------------------
__global__ __launch_bounds__(512, 2) void lstm_mfma_head(
    const float* __restrict__ gnn,
    const unsigned short* __restrict__ WxF_hi, const unsigned short* __restrict__ WxF_lo,
    const unsigned short* __restrict__ WhF_hi, const unsigned short* __restrict__ WhF_lo,
    const float* __restrict__ bias_s,
    const float* __restrict__ ln_g, const float* __restrict__ ln_b,
    const float* __restrict__ W1, const float* __restrict__ b1,
    const float* __restrict__ W2, const float* __restrict__ b2,
    float* __restrict__ out)
{
    __shared__ float gb[16][520];
    __shared__ unsigned short h_hi[16 * 128];
    __shared__ unsigned short h_lo[16 * 128];

    const int tid  = threadIdx.x;
    const int wv   = tid >> 6;
    const int lane = tid & 63;
    const int l15  = lane & 15;
    const int g    = lane >> 4;
    const int r0   = blockIdx.x * 16;

    for (int i = tid; i < 16 * 128; i += 512) { h_hi[i] = 0; h_lo[i] = 0; }

    bf16x8 whh[4][4], whl[4][4];
    #pragma unroll
    for (int ct = 0; ct < 4; ++ct)
        #pragma unroll
        for (int ks = 0; ks < 4; ++ks) {
            int fidx = (((wv * 4 + ct) * 4 + ks) * 64 + lane) * 8;
            whh[ct][ks] = *(const bf16x8*)&WhF_hi[fidx];
            whl[ct][ks] = *(const bf16x8*)&WhF_lo[fidx];
        }
    float bias[4];
    #pragma unroll
    for (int ct = 0; ct < 4; ++ct) bias[ct] = bias_s[(wv * 4 + ct) * 16 + l15];

    float c4[4] = {0.f, 0.f, 0.f, 0.f};
    __syncthreads();

    for (int t = 0; t < TT; ++t) {
        const float* xrow = gnn + ((size_t)(r0 + l15) * TT + t) * DD;
        bf16x8 xa_h[4], xa_l[4];
        #pragma unroll
        for (int ks = 0; ks < 4; ++ks) {
            int k0 = ks * 32 + g * 8;
            float4 v0 = *(const float4*)(xrow + k0);
            float4 v1 = *(const float4*)(xrow + k0 + 4);
            float vv[8] = {v0.x, v0.y, v0.z, v0.w, v1.x, v1.y, v1.z, v1.w};
            bf16x8 hh8, ll8;
            #pragma unroll
            for (int e = 0; e < 8; ++e) {
                unsigned short hb = f2bf(vv[e]);
                hh8[e] = (short)hb;
                ll8[e] = (short)f2bf(vv[e] - bf2f(hb));
            }
            xa_h[ks] = hh8;
            xa_l[ks] = ll8;
        }

        f32x4 acc[4];
        #pragma unroll
        for (int ct = 0; ct < 4; ++ct) {
            f32x4 a;
            a[0] = bias[ct]; a[1] = bias[ct]; a[2] = bias[ct]; a[3] = bias[ct];
            #pragma unroll
            for (int ks = 0; ks < 4; ++ks) {
                int fidx = (((wv * 4 + ct) * 4 + ks) * 64 + lane) * 8;
                bf16x8 bh = *(const bf16x8*)&WxF_hi[fidx];
                bf16x8 bl = *(const bf16x8*)&WxF_lo[fidx];
                a = __builtin_amdgcn_mfma_f32_16x16x32_bf16(xa_h[ks], bh, a, 0, 0, 0);
                a = __builtin_amdgcn_mfma_f32_16x16x32_bf16(xa_h[ks], bl, a, 0, 0, 0);
                a = __builtin_amdgcn_mfma_f32_16x16x32_bf16(xa_l[ks], bh, a, 0, 0, 0);
            }
            acc[ct] = a;
        }

        if (t > 0) {
            #pragma unroll
            for (int ks = 0; ks < 4; ++ks) {
                int byte = (l15 * 256 + (ks * 32 + g * 8) * 2) ^ ((l15 & 7) << 4);
                bf16x8 ah = *(const bf16x8*)((const char*)h_hi + byte);
                bf16x8 al = *(const bf16x8*)((const char*)h_lo + byte);
                #pragma unroll
                for (int ct = 0; ct < 4; ++ct) {
                    acc[ct] = __builtin_amdgcn_mfma_f32_16x16x32_bf16(ah, whh[ct][ks], acc[ct], 0, 0, 0);
                    acc[ct] = __builtin_amdgcn_mfma_f32_16x16x32_bf16(ah, whl[ct][ks], acc[ct], 0, 0, 0);
                    acc[ct] = __builtin_amdgcn_mfma_f32_16x16x32_bf16(al, whh[ct][ks], acc[ct], 0, 0, 0);
                }
            }
        }

        #pragma unroll
        for (int ct = 0; ct < 4; ++ct) {
            int col = (wv * 4 + ct) * 16 + l15;
            #pragma unroll
            for (int i = 0; i < 4; ++i) gb[g * 4 + i][col] = acc[ct][i];
        }
        __syncthreads();

        #pragma unroll
        for (int s = 0; s < 4; ++s) {
            int lin = tid + s * 512;
            int row = lin >> 7, d = lin & 127;
            float ig = gb[row][d];
            float fg = gb[row][128 + d];
            float gg = gb[row][256 + d];
            float og = gb[row][384 + d];
            float c = sigf(fg) * c4[s] + sigf(ig) * tanhf(gg);
            float hv = sigf(og) * tanhf(c);
            c4[s] = c;
            unsigned short hb = f2bf(hv);
            unsigned short lb = f2bf(hv - bf2f(hb));
            int byte = (row * 256 + d * 2) ^ ((row & 7) << 4);
            *(unsigned short*)((char*)h_hi + byte) = hb;
            *(unsigned short*)((char*)h_lo + byte) = lb;
        }
        __syncthreads();
    }

    float* lnbuf = &gb[0][0];
    float* zbuf  = lnbuf + 16 * 128;

    {
        const int row    = tid >> 5;
        const int lane32 = tid & 31;
        float v[4];
        #pragma unroll
        for (int s = 0; s < 4; ++s) {
            int d = lane32 + s * 32;
            int byte = (row * 256 + d * 2) ^ ((row & 7) << 4);
            v[s] = bf2f(*(const unsigned short*)((const char*)h_hi + byte)) +
                   bf2f(*(const unsigned short*)((const char*)h_lo + byte));
        }
        float sum = v[0] + v[1] + v[2] + v[3];
        for (int off = 16; off; off >>= 1) sum += __shfl_xor(sum, off, 32);
        float mu = sum * (1.f / 128.f);
        float var = 0.f;
        #pragma unroll
        for (int s = 0; s < 4; ++s) { float dv = v[s] - mu; var += dv * dv; }
        for (int off = 16; off; off >>= 1) var += __shfl_xor(var, off, 32);
        float rstd = rsqrtf(var * (1.f / 128.f) + 1e-5f);
        #pragma unroll
        for (int s = 0; s < 4; ++s) {
            int d = lane32 + s * 32;
            lnbuf[row * 128 + d] = (v[s] - mu) * rstd * ln_g[d] + ln_b[d];
        }
    }
    __syncthreads();

    {
        float zv[4];
        #pragma unroll
        for (int s = 0; s < 4; ++s) {
            int lin = tid + s * 512;
            int r2 = lin >> 7, j = lin & 127;
            float a = b1[j];
            #pragma unroll 4
            for (int k = 0; k < 128; ++k) a += lnbuf[r2 * 128 + k] * W1[k * 128 + j];
            zv[s] = fmaxf(a, 0.f);
        }
        #pragma unroll
        for (int s = 0; s < 4; ++s) zbuf[tid + s * 512] = zv[s];
    }
    __syncthreads();

    if (tid < 16 * HORZ) {
        int r2 = tid / HORZ, o = tid % HORZ;
        float a = b2[o];
        #pragma unroll 4
        for (int k = 0; k < 128; ++k) a += zbuf[r2 * 128 + k] * W2[k * HORZ + o];
        out[(size_t)(r0 + r2) * HORZ + o] = a;
    }
}

// ---------------------------------------------------------------------------
extern "C" void kernel_launch(void* const* d_in, const int* in_sizes, int n_in,
                              void* d_out, int out_size, void* d_ws, size_t ws_size,
                              hipStream_t stream)
{
    const float* x        = (const float*)d_in[0];
    const int*   eidx     = (const int*)d_in[1];
    const float* ew       = (const float*)d_in[2];
    const float* W_lin    = (const float*)d_in[3];
    const float* att_src  = (const float*)d_in[4];
    const float* att_dst  = (const float*)d_in[5];
    const float* W_edge   = (const float*)d_in[6];
    const float* att_edge = (const float*)d_in[7];
    const float* gat_bias = (const float*)d_in[8];
    const float* W_ih     = (const float*)d_in[9];
    const float* W_hh     = (const float*)d_in[10];
    const float* b_ih     = (const float*)d_in[11];
    const float* b_hh     = (const float*)d_in[12];
    const float* ln_g     = (const float*)d_in[13];
    const float* ln_b     = (const float*)d_in[14];
    const float* W1       = (const float*)d_in[15];
    const float* b1       = (const float*)d_in[16];
    const float* W2       = (const float*)d_in[17];
    const float* b2       = (const float*)d_in[18];
    float* out = (float*)d_out;

    float* ws = (float*)d_ws;
    float* gnn            = ws;                       // 15,360,000 f32
    unsigned short* hxb   = (unsigned short*)(gnn + 15360000);   // 15,360,000 u16
    float* a_srcT  = (float*)(hxb + 15360000);        // 480,000
    float* a_dstT  = a_srcT + 480000;                 // 480,000
    float* bias_s  = a_dstT + 480000;                 // 512
    float* s_h     = bias_s + 512;                    // 16
    unsigned short* WxF_hi = (unsigned short*)(s_h + 16);        // 65536 u16 x4
    unsigned short* WxF_lo = WxF_hi + 65536;
    unsigned short* WhF_hi = WxF_lo + 65536;
    unsigned short* WhF_lo = WhF_hi + 65536;
    int*   counts  = (int*)(WhF_lo + 65536);          // 5000
    int*   offs    = counts + NN;                     // 5001 (+pad)
    int*   cur     = offs + (NN + 8);                 // 5000
    int*   elist   = cur + NN;                        // 40000
    float* gx      = (float*)(elist + EE + 8);        // 61,440,000 f32 (fast path)

    size_t need_fast = ((char*)(gx + 61440000)) - ((char*)d_ws);
    const int fast = (ws_size >= need_fast) ? 1 : 0;

    const int* srcA = eidx;
    const int* dstA = eidx + EE;

    hipMemsetAsync(counts, 0, NN * sizeof(int), stream);
    prep_small<<<1, 512, 0, stream>>>(W_edge, att_edge, b_ih, b_hh, s_h, bias_s);
    wfrag_kernel<<<32, 256, 0, stream>>>(W_ih, W_hh, WxF_hi, WxF_lo, WhF_hi, WhF_lo);
    hx_kernel<<<BB * NN * TT, 128, 0, stream>>>(x, W_lin, att_src, att_dst,
                                                hxb, a_srcT, a_dstT);
    count_kernel<<<(EE + 255) / 256, 256, 0, stream>>>(dstA, counts);
    scan_kernel<<<1, 1024, 0, stream>>>(counts, offs, cur);
    fill_kernel<<<(EE + 255) / 256, 256, 0, stream>>>(dstA, cur, elist);
    gat_kernel<<<NN * BB, 128, 0, stream>>>(hxb, a_srcT, a_dstT, srcA, ew, s_h,
                                            offs, elist, gat_bias, gnn, fast);
    if (fast) {
        gx_gemm<<<MROWS / 64, 512, 0, stream>>>(gnn, WxF_hi, WxF_lo, bias_s, gx);
        lstm_rec<<<NSEQ / 16, 512, 0, stream>>>(gx, WhF_hi, WhF_lo,
                                                ln_g, ln_b, W1, b1, W2, b2, out);
    } else {
        lstm_mfma_head<<<NSEQ / 16, 512, 0, stream>>>(
            gnn, WxF_hi, WxF_lo, WhF_hi, WhF_lo, bias_s,
            ln_g, ln_b, W1, b1, W2, b2, out);
    }
}

// Round 5
// 615.588 us; speedup vs baseline: 1.5163x; 1.2997x over previous
//
#include <hip/hip_runtime.h>
#include <math.h>

// Problem constants (fixed shapes)
#define BB  2
#define NN  5000
#define EE  40000
#define TT  12
#define FF  16
#define DD  128
#define HH  4
#define HORZ 12
#define NRT (NN * TT)           // 60000 rows per batch
#define NTILE (NRT / 16)        // 3750 16-row tiles per batch

typedef short bf16x8 __attribute__((ext_vector_type(8)));
typedef float f32x4  __attribute__((ext_vector_type(4)));

__device__ __forceinline__ float sigf(float x) { return 1.f / (1.f + expf(-x)); }

__device__ __forceinline__ unsigned short f2bf(float f) {
    unsigned int u = __float_as_uint(f);
    unsigned int r = (u + 0x7fffu + ((u >> 16) & 1u)) >> 16;   // RNE
    return (unsigned short)r;
}
__device__ __forceinline__ float bf2f(unsigned short h) {
    return __uint_as_float(((unsigned int)h) << 16);
}

// ---------------------------------------------------------------------------
// K0a: tiny prep
// ---------------------------------------------------------------------------
__global__ __launch_bounds__(512) void prep_small(
    const float* __restrict__ W_edge, const float* __restrict__ att_edge,
    const float* __restrict__ b_ih, const float* __restrict__ b_hh,
    float* __restrict__ s_h, float* __restrict__ bias_sum)
{
    int tid = threadIdx.x;
    if (tid < 128) {
        float v = W_edge[tid] * att_edge[tid];
        for (int off = 16; off; off >>= 1) v += __shfl_xor(v, off, 32);
        if ((tid & 31) == 0) s_h[tid >> 5] = v;
    }
    bias_sum[tid] = b_ih[tid] + b_hh[tid];
}

// ---------------------------------------------------------------------------
// K0b: pack W_ih / W_hh into per-lane MFMA fragment order, split bf16 hi/lo.
// frag (cg,ks): lane L holds col=cg*16+(L&15), k=ks*32+(L>>4)*8+j.
// ---------------------------------------------------------------------------
__global__ __launch_bounds__(256) void wfrag_kernel(
    const float* __restrict__ W_ih, const float* __restrict__ W_hh,
    unsigned short* __restrict__ WxF_hi, unsigned short* __restrict__ WxF_lo,
    unsigned short* __restrict__ WhF_hi, unsigned short* __restrict__ WhF_lo)
{
    int gidx = blockIdx.x * 256 + threadIdx.x;    // 0..8191 : (cg,ks,lane)
    if (gidx >= 32 * 4 * 64) return;
    int lane = gidx & 63;
    int ks   = (gidx >> 6) & 3;
    int cg   = gidx >> 8;                          // global col-tile 0..31
    int col  = cg * 16 + (lane & 15);
    #pragma unroll
    for (int j = 0; j < 8; ++j) {
        int k = ks * 32 + (lane >> 4) * 8 + j;
        int o = gidx * 8 + j;
        float vx = W_ih[col * DD + k];
        unsigned short xh = f2bf(vx);
        WxF_hi[o] = xh;
        WxF_lo[o] = f2bf(vx - bf2f(xh));
        float vh = W_hh[col * DD + k];
        unsigned short hh = f2bf(vh);
        WhF_hi[o] = hh;
        WhF_lo[o] = f2bf(vh - bf2f(hh));
    }
}

// ---------------------------------------------------------------------------
// K1: hx = x @ W_lin (bf16 out) + a_src/a_dst per-head reductions (batch-local)
// ---------------------------------------------------------------------------
__global__ __launch_bounds__(128) void hx_kernel(
    const float* __restrict__ xb, const float* __restrict__ W_lin,
    const float* __restrict__ att_src, const float* __restrict__ att_dst,
    unsigned short* __restrict__ hxb, float* __restrict__ a_srcT,
    float* __restrict__ a_dstT)
{
    const int rt = blockIdx.x;                 // n*T+t, 0..59999
    const int d  = threadIdx.x;
    const float* xr = xb + (size_t)rt * FF;
    float acc = 0.f;
    #pragma unroll
    for (int f = 0; f < FF; ++f) acc += xr[f] * W_lin[f * DD + d];
    hxb[(size_t)rt * DD + d] = f2bf(acc);
    float vs = acc * att_src[d];
    float vd = acc * att_dst[d];
    for (int off = 16; off; off >>= 1) {
        vs += __shfl_xor(vs, off, 32);
        vd += __shfl_xor(vd, off, 32);
    }
    if ((d & 31) == 0) {
        int h = d >> 5;
        a_srcT[(size_t)rt * HH + h] = vs;
        a_dstT[(size_t)rt * HH + h] = vd;
    }
}

// ---------------------------------------------------------------------------
// K2: CSR build (shared by both batches)
// ---------------------------------------------------------------------------
__global__ __launch_bounds__(256) void count_kernel(const int* __restrict__ dst,
                                                    int* __restrict__ counts)
{
    int e = blockIdx.x * 256 + threadIdx.x;
    if (e < EE) atomicAdd(&counts[dst[e]], 1);
}

__global__ __launch_bounds__(1024) void scan_kernel(const int* __restrict__ counts,
                                                    int* __restrict__ offs,
                                                    int* __restrict__ cur)
{
    __shared__ int part[1024];
    const int tid = threadIdx.x;
    const int CH = 5;
    int base = tid * CH;
    int pre[CH];
    int run = 0;
    #pragma unroll
    for (int i = 0; i < CH; ++i) {
        int idx = base + i;
        int v = (idx < NN) ? counts[idx] : 0;
        pre[i] = run;
        run += v;
    }
    part[tid] = run;
    __syncthreads();
    for (int off = 1; off < 1024; off <<= 1) {
        int v = (tid >= off) ? part[tid - off] : 0;
        __syncthreads();
        part[tid] += v;
        __syncthreads();
    }
    int prefix = (tid == 0) ? 0 : part[tid - 1];
    #pragma unroll
    for (int i = 0; i < CH; ++i) {
        int idx = base + i;
        if (idx < NN) {
            int o = prefix + pre[i];
            offs[idx] = o;
            cur[idx]  = o;
        }
    }
    if (tid == 1023) offs[NN] = part[1023];
}

__global__ __launch_bounds__(256) void fill_kernel(const int* __restrict__ dst,
                                                   int* __restrict__ cur,
                                                   int* __restrict__ elist)
{
    int e = blockIdx.x * 256 + threadIdx.x;
    if (e < EE) {
        int p = atomicAdd(&cur[dst[e]], 1);
        elist[p] = e;
    }
}

// ---------------------------------------------------------------------------
// K3: GAT scatter-softmax + aggregate + bias + ELU (batch-local, t-major out)
// ---------------------------------------------------------------------------
__global__ __launch_bounds__(128) void gat_kernel(
    const unsigned short* __restrict__ hxb, const float* __restrict__ a_srcT,
    const float* __restrict__ a_dstT, const int* __restrict__ src_arr,
    const float* __restrict__ ew, const float* __restrict__ s_h,
    const int* __restrict__ offs, const int* __restrict__ elist,
    const float* __restrict__ gat_bias, float* __restrict__ gnn)
{
    const int n = blockIdx.x;                  // dst node
    const int d = threadIdx.x;
    const int h = d >> 5;
    const int e0 = offs[n], e1 = offs[n + 1];
    const float sh = s_h[h];
    const float bias = gat_bias[d];

    const size_t base_dst = (size_t)n * TT;
    float ad[TT];
    #pragma unroll
    for (int t = 0; t < TT; ++t) ad[t] = a_dstT[(base_dst + t) * HH + h];

    float den[TT], acc[TT];
    #pragma unroll
    for (int t = 0; t < TT; ++t) { den[t] = 0.f; acc[t] = 0.f; }

    for (int ii = e0; ii < e1; ++ii) {
        int e = elist[ii];
        int s = src_arr[e];
        float aew = ew[e] * sh;
        const size_t base_src = (size_t)s * TT;
        #pragma unroll
        for (int t = 0; t < TT; ++t) {
            float al = a_srcT[(base_src + t) * HH + h] + ad[t] + aew;
            al = (al >= 0.f) ? al : 0.2f * al;
            float exv = expf(al);
            den[t] += exv;
            acc[t] += exv * bf2f(hxb[(base_src + t) * DD + d]);
        }
    }
    #pragma unroll
    for (int t = 0; t < TT; ++t) {
        float g = acc[t] / (den[t] + 1e-16f) + bias;
        float o = (g > 0.f) ? g : expm1f(g);
        gnn[((size_t)t * NN + n) * DD + d] = o;      // t-major
    }
}

// ---------------------------------------------------------------------------
// K4a: gx = bias + gnn @ W_ihT (split-bf16 MFMA), Wx frags resident in VGPRs.
// Output fragment order per 16-row tile, per gate col-tile cg:
//   i/f/o gates (cg 0..15, 24..31) -> gxS bf16, sidx = cg<16?cg:cg-8
//   g gate (cg 16..23)             -> gxG f32
//   element off within (tile,cg): l15*16 + q*4 + i  (q = data-row quad)
// ---------------------------------------------------------------------------
__global__ __launch_bounds__(512, 2) void gx_gemm(
    const float* __restrict__ gnn,             // [60000][128] t-major rows
    const unsigned short* __restrict__ WxF_hi,
    const unsigned short* __restrict__ WxF_lo,
    const float* __restrict__ bias_s,
    unsigned short* __restrict__ gxS, float* __restrict__ gxG)
{
    __shared__ unsigned short Ahi[64 * 128];   // 16 KB, XOR-swizzled
    __shared__ unsigned short Alo[64 * 128];

    const int tid  = threadIdx.x;
    const int wv   = tid >> 6;
    const int lane = tid & 63;
    const int l15  = lane & 15;
    const int g    = lane >> 4;
    const size_t fr0 = (size_t)blockIdx.x * 64;

    // stage A tile (64 rows x 128 k), split to bf16 hi/lo, swizzled
    #pragma unroll
    for (int c = 0; c < 2; ++c) {
        int linear = tid + c * 512;
        int row = linear >> 4;
        int k0  = (linear & 15) * 8;
        size_t r = fr0 + row;
        if (r > NRT - 1) r = NRT - 1;          // clamp (pad rows, unused)
        const float* src = gnn + r * DD + k0;
        float4 v0 = *(const float4*)src;
        float4 v1 = *(const float4*)(src + 4);
        float vv[8] = {v0.x, v0.y, v0.z, v0.w, v1.x, v1.y, v1.z, v1.w};
        bf16x8 h8, l8;
        #pragma unroll
        for (int e = 0; e < 8; ++e) {
            unsigned short hb = f2bf(vv[e]);
            h8[e] = (short)hb;
            l8[e] = (short)f2bf(vv[e] - bf2f(hb));
        }
        int byte = (row * 256 + k0 * 2) ^ ((row & 7) << 4);
        *(bf16x8*)((char*)Ahi + byte) = h8;
        *(bf16x8*)((char*)Alo + byte) = l8;
    }

    // resident Wx fragments
    bf16x8 wh[16], wl[16];
    #pragma unroll
    for (int ct = 0; ct < 4; ++ct)
        #pragma unroll
        for (int ks = 0; ks < 4; ++ks) {
            int fidx = (((wv * 4 + ct) * 4 + ks) * 64 + lane) * 8;
            wh[ct * 4 + ks] = *(const bf16x8*)&WxF_hi[fidx];
            wl[ct * 4 + ks] = *(const bf16x8*)&WxF_lo[fidx];
        }
    float bias[4];
    #pragma unroll
    for (int ct = 0; ct < 4; ++ct) bias[ct] = bias_s[(wv * 4 + ct) * 16 + l15];

    __syncthreads();

    #pragma unroll
    for (int ar = 0; ar < 4; ++ar) {
        size_t tile = (size_t)blockIdx.x * 4 + ar;
        if (tile >= NTILE) break;
        bf16x8 ah[4], al[4];
        int row = ar * 16 + l15;
        #pragma unroll
        for (int ks = 0; ks < 4; ++ks) {
            int byte = (row * 256 + (ks * 32 + g * 8) * 2) ^ ((row & 7) << 4);
            ah[ks] = *(const bf16x8*)((const char*)Ahi + byte);
            al[ks] = *(const bf16x8*)((const char*)Alo + byte);
        }
        #pragma unroll
        for (int ct = 0; ct < 4; ++ct) {
            int cg = wv * 4 + ct;
            f32x4 a;
            a[0] = bias[ct]; a[1] = bias[ct]; a[2] = bias[ct]; a[3] = bias[ct];
            #pragma unroll
            for (int ks = 0; ks < 4; ++ks) {
                a = __builtin_amdgcn_mfma_f32_16x16x32_bf16(ah[ks], wh[ct * 4 + ks], a, 0, 0, 0);
                a = __builtin_amdgcn_mfma_f32_16x16x32_bf16(ah[ks], wl[ct * 4 + ks], a, 0, 0, 0);
                a = __builtin_amdgcn_mfma_f32_16x16x32_bf16(al[ks], wh[ct * 4 + ks], a, 0, 0, 0);
            }
            int off = l15 * 16 + g * 4;        // lane holds data rows g*4+i, col l15
            if (cg >= 16 && cg < 24) {
                *(f32x4*)&gxG[(tile * 8 + (cg - 16)) * 256 + off] = a;
            } else {
                int sidx = (cg < 16) ? cg : cg - 8;
                uint2 p;
                p.x = (unsigned)f2bf(a[0]) | ((unsigned)f2bf(a[1]) << 16);
                p.y = (unsigned)f2bf(a[2]) | ((unsigned)f2bf(a[3]) << 16);
                *(uint2*)&gxS[(tile * 24 + sidx) * 256 + off] = p;
            }
        }
    }
}

// ---------------------------------------------------------------------------
// K4b: recurrent-only LSTM + head. W_hh resident in VGPRs; per step reads the
// gx fragment (C-init) with 1-step prefetch. Zero weight traffic in the loop.
// ---------------------------------------------------------------------------
__global__ __launch_bounds__(512, 2) void lstm_rec(
    const unsigned short* __restrict__ gxS, const float* __restrict__ gxG,
    const unsigned short* __restrict__ WhF_hi,
    const unsigned short* __restrict__ WhF_lo,
    const float* __restrict__ ln_g, const float* __restrict__ ln_b,
    const float* __restrict__ W1, const float* __restrict__ b1,
    const float* __restrict__ W2, const float* __restrict__ b2,
    float* __restrict__ outb)                  // out + b*NN*HORZ
{
    __shared__ float gb[16][520];
    __shared__ unsigned short h_hi[16 * 128];
    __shared__ unsigned short h_lo[16 * 128];

    const int tid  = threadIdx.x;
    const int wv   = tid >> 6;
    const int lane = tid & 63;
    const int l15  = lane & 15;
    const int g    = lane >> 4;
    const int r0   = blockIdx.x * 16;          // block 312: rows 4992..5007 (guard)

    for (int i = tid; i < 16 * 128; i += 512) { h_hi[i] = 0; h_lo[i] = 0; }

    bf16x8 wh[16], wl[16];
    #pragma unroll
    for (int ct = 0; ct < 4; ++ct)
        #pragma unroll
        for (int ks = 0; ks < 4; ++ks) {
            int fidx = (((wv * 4 + ct) * 4 + ks) * 64 + lane) * 8;
            wh[ct * 4 + ks] = *(const bf16x8*)&WhF_hi[fidx];
            wl[ct * 4 + ks] = *(const bf16x8*)&WhF_lo[fidx];
        }

    // clamped seq-quad (lane reads data rows seqq..seqq+3)
    int seqq = r0 + g * 4;
    if (seqq > NN - 4) seqq = NN - 4;

    float c4[4] = {0.f, 0.f, 0.f, 0.f};
    __syncthreads();

    f32x4 cin[4], nxt[4];
    #pragma unroll
    for (int ct = 0; ct < 4; ++ct) {           // load t=0 C-init
        int cg = wv * 4 + ct;
        size_t F = (size_t)seqq;               // t=0
        size_t tile = F >> 4;
        int q = ((int)F & 15) >> 2;
        if (cg >= 16 && cg < 24) {
            cin[ct] = *(const f32x4*)&gxG[(tile * 8 + (cg - 16)) * 256 + l15 * 16 + q * 4];
        } else {
            int sidx = (cg < 16) ? cg : cg - 8;
            uint2 p = *(const uint2*)&gxS[(tile * 24 + sidx) * 256 + l15 * 16 + q * 4];
            cin[ct][0] = bf2f((unsigned short)(p.x & 0xffff));
            cin[ct][1] = bf2f((unsigned short)(p.x >> 16));
            cin[ct][2] = bf2f((unsigned short)(p.y & 0xffff));
            cin[ct][3] = bf2f((unsigned short)(p.y >> 16));
        }
    }

    for (int t = 0; t < TT; ++t) {
        // prefetch next step's C-init (issues loads before the MFMA cluster)
        if (t < TT - 1) {
            #pragma unroll
            for (int ct = 0; ct < 4; ++ct) {
                int cg = wv * 4 + ct;
                size_t F = (size_t)(t + 1) * NN + seqq;
                size_t tile = F >> 4;
                int q = ((int)F & 15) >> 2;
                if (cg >= 16 && cg < 24) {
                    nxt[ct] = *(const f32x4*)&gxG[(tile * 8 + (cg - 16)) * 256 + l15 * 16 + q * 4];
                } else {
                    int sidx = (cg < 16) ? cg : cg - 8;
                    uint2 p = *(const uint2*)&gxS[(tile * 24 + sidx) * 256 + l15 * 16 + q * 4];
                    nxt[ct][0] = bf2f((unsigned short)(p.x & 0xffff));
                    nxt[ct][1] = bf2f((unsigned short)(p.x >> 16));
                    nxt[ct][2] = bf2f((unsigned short)(p.y & 0xffff));
                    nxt[ct][3] = bf2f((unsigned short)(p.y >> 16));
                }
            }
        }

        f32x4 acc[4];
        #pragma unroll
        for (int ct = 0; ct < 4; ++ct) acc[ct] = cin[ct];

        if (t > 0) {
            #pragma unroll
            for (int ks = 0; ks < 4; ++ks) {
                int byte = (l15 * 256 + (ks * 32 + g * 8) * 2) ^ ((l15 & 7) << 4);
                bf16x8 ah = *(const bf16x8*)((const char*)h_hi + byte);
                bf16x8 al = *(const bf16x8*)((const char*)h_lo + byte);
                #pragma unroll
                for (int ct = 0; ct < 4; ++ct) {
                    acc[ct] = __builtin_amdgcn_mfma_f32_16x16x32_bf16(ah, wh[ct * 4 + ks], acc[ct], 0, 0, 0);
                    acc[ct] = __builtin_amdgcn_mfma_f32_16x16x32_bf16(ah, wl[ct * 4 + ks], acc[ct], 0, 0, 0);
                    acc[ct] = __builtin_amdgcn_mfma_f32_16x16x32_bf16(al, wh[ct * 4 + ks], acc[ct], 0, 0, 0);
                }
            }
        }

        #pragma unroll
        for (int ct = 0; ct < 4; ++ct) {
            int col = (wv * 4 + ct) * 16 + l15;
            #pragma unroll
            for (int i = 0; i < 4; ++i) gb[g * 4 + i][col] = acc[ct][i];
        }
        __syncthreads();

        #pragma unroll
        for (int s = 0; s < 4; ++s) {
            int lin = tid + s * 512;
            int row = lin >> 7, d = lin & 127;
            float ig = gb[row][d];
            float fg = gb[row][128 + d];
            float gg = gb[row][256 + d];
            float og = gb[row][384 + d];
            float c = sigf(fg) * c4[s] + sigf(ig) * tanhf(gg);
            float hv = sigf(og) * tanhf(c);
            c4[s] = c;
            unsigned short hb = f2bf(hv);
            unsigned short lb = f2bf(hv - bf2f(hb));
            int byte = (row * 256 + d * 2) ^ ((row & 7) << 4);
            *(unsigned short*)((char*)h_hi + byte) = hb;
            *(unsigned short*)((char*)h_lo + byte) = lb;
        }
        __syncthreads();

        #pragma unroll
        for (int ct = 0; ct < 4; ++ct) cin[ct] = nxt[ct];
    }

    // ---- head: LayerNorm -> Linear(128,128)+ReLU -> Linear(128,12) ----
    float* lnbuf = &gb[0][0];
    float* zbuf  = lnbuf + 16 * 128;

    {
        const int row    = tid >> 5;
        const int lane32 = tid & 31;
        float v[4];
        #pragma unroll
        for (int s = 0; s < 4; ++s) {
            int d = lane32 + s * 32;
            int byte = (row * 256 + d * 2) ^ ((row & 7) << 4);
            v[s] = bf2f(*(const unsigned short*)((const char*)h_hi + byte)) +
                   bf2f(*(const unsigned short*)((const char*)h_lo + byte));
        }
        float sum = v[0] + v[1] + v[2] + v[3];
        for (int off = 16; off; off >>= 1) sum += __shfl_xor(sum, off, 32);
        float mu = sum * (1.f / 128.f);
        float var = 0.f;
        #pragma unroll
        for (int s = 0; s < 4; ++s) { float dv = v[s] - mu; var += dv * dv; }
        for (int off = 16; off; off >>= 1) var += __shfl_xor(var, off, 32);
        float rstd = rsqrtf(var * (1.f / 128.f) + 1e-5f);
        #pragma unroll
        for (int s = 0; s < 4; ++s) {
            int d = lane32 + s * 32;
            lnbuf[row * 128 + d] = (v[s] - mu) * rstd * ln_g[d] + ln_b[d];
        }
    }
    __syncthreads();

    {
        float zv[4];
        #pragma unroll
        for (int s = 0; s < 4; ++s) {
            int lin = tid + s * 512;
            int r2 = lin >> 7, j = lin & 127;
            float a = b1[j];
            #pragma unroll 4
            for (int k = 0; k < 128; ++k) a += lnbuf[r2 * 128 + k] * W1[k * 128 + j];
            zv[s] = fmaxf(a, 0.f);
        }
        #pragma unroll
        for (int s = 0; s < 4; ++s) zbuf[tid + s * 512] = zv[s];
    }
    __syncthreads();

    if (tid < 16 * HORZ) {
        int r2 = tid / HORZ, o = tid % HORZ;
        if (r0 + r2 < NN) {
            float a = b2[o];
            #pragma unroll 4
            for (int k = 0; k < 128; ++k) a += zbuf[r2 * 128 + k] * W2[k * HORZ + o];
            outb[(size_t)(r0 + r2) * HORZ + o] = a;
        }
    }
}

// ---------------------------------------------------------------------------
extern "C" void kernel_launch(void* const* d_in, const int* in_sizes, int n_in,
                              void* d_out, int out_size, void* d_ws, size_t ws_size,
                              hipStream_t stream)
{
    const float* x        = (const float*)d_in[0];
    const int*   eidx     = (const int*)d_in[1];
    const float* ew       = (const float*)d_in[2];
    const float* W_lin    = (const float*)d_in[3];
    const float* att_src  = (const float*)d_in[4];
    const float* att_dst  = (const float*)d_in[5];
    const float* W_edge   = (const float*)d_in[6];
    const float* att_edge = (const float*)d_in[7];
    const float* gat_bias = (const float*)d_in[8];
    const float* W_ih     = (const float*)d_in[9];
    const float* W_hh     = (const float*)d_in[10];
    const float* b_ih     = (const float*)d_in[11];
    const float* b_hh     = (const float*)d_in[12];
    const float* ln_g     = (const float*)d_in[13];
    const float* ln_b     = (const float*)d_in[14];
    const float* W1       = (const float*)d_in[15];
    const float* b1       = (const float*)d_in[16];
    const float* W2       = (const float*)d_in[17];
    const float* b2       = (const float*)d_in[18];
    float* out = (float*)d_out;

    // ---- workspace layout (per-phase region reused across batches) ----
    float* ws = (float*)d_ws;
    float* gnn = ws;                                  // 7,680,000 f32 (30.72 MB)
    float* gxG = gnn + 7680000;                       // 7,680,000 f32 (30.72 MB)
    unsigned short* hxb = (unsigned short*)gxG;       // ALIAS: dead before gx write
    unsigned short* gxS = (unsigned short*)(gxG + 7680000);  // 23,040,000 u16 (46.08 MB)
    float* a_srcT  = (float*)(gxS + 23040000);        // 240,000 f32
    float* a_dstT  = a_srcT + 240000;                 // 240,000 f32
    float* bias_s  = a_dstT + 240000;                 // 512
    float* s_h     = bias_s + 512;                    // 16
    unsigned short* WxF_hi = (unsigned short*)(s_h + 16);    // 65536 u16 x4
    unsigned short* WxF_lo = WxF_hi + 65536;
    unsigned short* WhF_hi = WxF_lo + 65536;
    unsigned short* WhF_lo = WhF_hi + 65536;
    int*   counts  = (int*)(WhF_lo + 65536);          // 5000
    int*   offs    = counts + NN;                     // 5001 (+pad)
    int*   cur     = offs + (NN + 8);                 // 5000
    int*   elist   = cur + NN;                        // 40000
    // total ≈ 110 MB (< proven 127.4 MB)

    const int* srcA = eidx;
    const int* dstA = eidx + EE;

    // shared prep
    hipMemsetAsync(counts, 0, NN * sizeof(int), stream);
    prep_small<<<1, 512, 0, stream>>>(W_edge, att_edge, b_ih, b_hh, s_h, bias_s);
    wfrag_kernel<<<32, 256, 0, stream>>>(W_ih, W_hh, WxF_hi, WxF_lo, WhF_hi, WhF_lo);
    count_kernel<<<(EE + 255) / 256, 256, 0, stream>>>(dstA, counts);
    scan_kernel<<<1, 1024, 0, stream>>>(counts, offs, cur);
    fill_kernel<<<(EE + 255) / 256, 256, 0, stream>>>(dstA, cur, elist);

    // per-batch phases (buffers reused; in-order stream makes this safe)
    for (int b = 0; b < BB; ++b) {
        const float* xb = x + (size_t)b * NN * TT * FF;
        float* outb = out + (size_t)b * NN * HORZ;
        hx_kernel<<<NRT, 128, 0, stream>>>(xb, W_lin, att_src, att_dst,
                                           hxb, a_srcT, a_dstT);
        gat_kernel<<<NN, 128, 0, stream>>>(hxb, a_srcT, a_dstT, srcA, ew, s_h,
                                           offs, elist, gat_bias, gnn);
        gx_gemm<<<(NRT + 63) / 64, 512, 0, stream>>>(gnn, WxF_hi, WxF_lo,
                                                     bias_s, gxS, gxG);
        lstm_rec<<<(NN + 15) / 16, 512, 0, stream>>>(gxS, gxG, WhF_hi, WhF_lo,
                                                     ln_g, ln_b, W1, b1, W2, b2,
                                                     outb);
    }
}

// Round 7
// 479.443 us; speedup vs baseline: 1.9468x; 1.2840x over previous
//
#include <hip/hip_runtime.h>
#include <math.h>

// Problem constants (fixed shapes)
#define BB  2
#define NN  5000
#define EE  40000
#define TT  12
#define FF  16
#define DD  128
#define HH  4
#define HORZ 12
#define NRT (NN * TT)           // 60000 rows per batch
#define NTILE (NRT / 16)        // 3750 16-row tiles per batch
#define BPB 313                 // lstm_rec blocks per batch = ceil(5000/16)

typedef short bf16x8 __attribute__((ext_vector_type(8)));
typedef float f32x4  __attribute__((ext_vector_type(4)));

__device__ __forceinline__ float sigfast(float x) {
    return __fdividef(1.f, 1.f + __expf(-x));
}
__device__ __forceinline__ float tanhfast(float x) {
    return __fdividef(2.f, 1.f + __expf(-2.f * x)) - 1.f;
}

__device__ __forceinline__ unsigned short f2bf(float f) {
    unsigned int u = __float_as_uint(f);
    unsigned int r = (u + 0x7fffu + ((u >> 16) & 1u)) >> 16;   // RNE
    return (unsigned short)r;
}
__device__ __forceinline__ float bf2f(unsigned short h) {
    return __uint_as_float(((unsigned int)h) << 16);
}

// ---------------------------------------------------------------------------
// K0a: tiny prep
// ---------------------------------------------------------------------------
__global__ __launch_bounds__(512) void prep_small(
    const float* __restrict__ W_edge, const float* __restrict__ att_edge,
    const float* __restrict__ b_ih, const float* __restrict__ b_hh,
    float* __restrict__ s_h, float* __restrict__ bias_sum)
{
    int tid = threadIdx.x;
    if (tid < 128) {
        float v = W_edge[tid] * att_edge[tid];
        for (int off = 16; off; off >>= 1) v += __shfl_xor(v, off, 32);
        if ((tid & 31) == 0) s_h[tid >> 5] = v;
    }
    bias_sum[tid] = b_ih[tid] + b_hh[tid];
}

// ---------------------------------------------------------------------------
// K0b: pack W_ih / W_hh into per-lane MFMA fragment order, split bf16 hi/lo.
// frag (cg,ks): lane L holds col=cg*16+(L&15), k=ks*32+(L>>4)*8+j.
// ---------------------------------------------------------------------------
__global__ __launch_bounds__(256) void wfrag_kernel(
    const float* __restrict__ W_ih, const float* __restrict__ W_hh,
    unsigned short* __restrict__ WxF_hi, unsigned short* __restrict__ WxF_lo,
    unsigned short* __restrict__ WhF_hi, unsigned short* __restrict__ WhF_lo)
{
    int gidx = blockIdx.x * 256 + threadIdx.x;    // 0..8191 : (cg,ks,lane)
    if (gidx >= 32 * 4 * 64) return;
    int lane = gidx & 63;
    int ks   = (gidx >> 6) & 3;
    int cg   = gidx >> 8;                          // global col-tile 0..31
    int col  = cg * 16 + (lane & 15);
    #pragma unroll
    for (int j = 0; j < 8; ++j) {
        int k = ks * 32 + (lane >> 4) * 8 + j;
        int o = gidx * 8 + j;
        float vx = W_ih[col * DD + k];
        unsigned short xh = f2bf(vx);
        WxF_hi[o] = xh;
        WxF_lo[o] = f2bf(vx - bf2f(xh));
        float vh = W_hh[col * DD + k];
        unsigned short hh = f2bf(vh);
        WhF_hi[o] = hh;
        WhF_lo[o] = f2bf(vh - bf2f(hh));
    }
}

// ---------------------------------------------------------------------------
// K1: hx = x @ W_lin (bf16 out) + a_src/a_dst per-head reductions (batch-local)
// ---------------------------------------------------------------------------
__global__ __launch_bounds__(128) void hx_kernel(
    const float* __restrict__ xb, const float* __restrict__ W_lin,
    const float* __restrict__ att_src, const float* __restrict__ att_dst,
    unsigned short* __restrict__ hxb, float* __restrict__ a_srcT,
    float* __restrict__ a_dstT)
{
    const int rt = blockIdx.x;                 // n*T+t, 0..59999
    const int d  = threadIdx.x;
    const float* xr = xb + (size_t)rt * FF;
    float acc = 0.f;
    #pragma unroll
    for (int f = 0; f < FF; ++f) acc += xr[f] * W_lin[f * DD + d];
    hxb[(size_t)rt * DD + d] = f2bf(acc);
    float vs = acc * att_src[d];
    float vd = acc * att_dst[d];
    for (int off = 16; off; off >>= 1) {
        vs += __shfl_xor(vs, off, 32);
        vd += __shfl_xor(vd, off, 32);
    }
    if ((d & 31) == 0) {
        int h = d >> 5;
        a_srcT[(size_t)rt * HH + h] = vs;
        a_dstT[(size_t)rt * HH + h] = vd;
    }
}

// ---------------------------------------------------------------------------
// K2: CSR build (shared by both batches)
// ---------------------------------------------------------------------------
__global__ __launch_bounds__(256) void count_kernel(const int* __restrict__ dst,
                                                    int* __restrict__ counts)
{
    int e = blockIdx.x * 256 + threadIdx.x;
    if (e < EE) atomicAdd(&counts[dst[e]], 1);
}

__global__ __launch_bounds__(1024) void scan_kernel(const int* __restrict__ counts,
                                                    int* __restrict__ offs,
                                                    int* __restrict__ cur)
{
    __shared__ int part[1024];
    const int tid = threadIdx.x;
    const int CH = 5;
    int base = tid * CH;
    int pre[CH];
    int run = 0;
    #pragma unroll
    for (int i = 0; i < CH; ++i) {
        int idx = base + i;
        int v = (idx < NN) ? counts[idx] : 0;
        pre[i] = run;
        run += v;
    }
    part[tid] = run;
    __syncthreads();
    for (int off = 1; off < 1024; off <<= 1) {
        int v = (tid >= off) ? part[tid - off] : 0;
        __syncthreads();
        part[tid] += v;
        __syncthreads();
    }
    int prefix = (tid == 0) ? 0 : part[tid - 1];
    #pragma unroll
    for (int i = 0; i < CH; ++i) {
        int idx = base + i;
        if (idx < NN) {
            int o = prefix + pre[i];
            offs[idx] = o;
            cur[idx]  = o;
        }
    }
    if (tid == 1023) offs[NN] = part[1023];
}

__global__ __launch_bounds__(256) void fill_kernel(const int* __restrict__ dst,
                                                   int* __restrict__ cur,
                                                   int* __restrict__ elist)
{
    int e = blockIdx.x * 256 + threadIdx.x;
    if (e < EE) {
        int p = atomicAdd(&cur[dst[e]], 1);
        elist[p] = e;
    }
}

// ---------------------------------------------------------------------------
// K3: GAT scatter-softmax + aggregate + bias + ELU (batch-local, t-major out)
// ---------------------------------------------------------------------------
__global__ __launch_bounds__(128) void gat_kernel(
    const unsigned short* __restrict__ hxb, const float* __restrict__ a_srcT,
    const float* __restrict__ a_dstT, const int* __restrict__ src_arr,
    const float* __restrict__ ew, const float* __restrict__ s_h,
    const int* __restrict__ offs, const int* __restrict__ elist,
    const float* __restrict__ gat_bias, float* __restrict__ gnn)
{
    const int n = blockIdx.x;                  // dst node
    const int d = threadIdx.x;
    const int h = d >> 5;
    const int e0 = offs[n], e1 = offs[n + 1];
    const float sh = s_h[h];
    const float bias = gat_bias[d];

    const size_t base_dst = (size_t)n * TT;
    float ad[TT];
    #pragma unroll
    for (int t = 0; t < TT; ++t) ad[t] = a_dstT[(base_dst + t) * HH + h];

    float den[TT], acc[TT];
    #pragma unroll
    for (int t = 0; t < TT; ++t) { den[t] = 0.f; acc[t] = 0.f; }

    for (int ii = e0; ii < e1; ++ii) {
        int e = elist[ii];
        int s = src_arr[e];
        float aew = ew[e] * sh;
        const size_t base_src = (size_t)s * TT;
        #pragma unroll
        for (int t = 0; t < TT; ++t) {
            float al = a_srcT[(base_src + t) * HH + h] + ad[t] + aew;
            al = (al >= 0.f) ? al : 0.2f * al;
            float exv = __expf(al);
            den[t] += exv;
            acc[t] += exv * bf2f(hxb[(base_src + t) * DD + d]);
        }
    }
    #pragma unroll
    for (int t = 0; t < TT; ++t) {
        float g = acc[t] / (den[t] + 1e-16f) + bias;
        float o = (g > 0.f) ? g : expm1f(g);
        gnn[((size_t)t * NN + n) * DD + d] = o;      // t-major
    }
}

// ---------------------------------------------------------------------------
// K4a: gx = bias + gnn @ W_ihT (split-bf16 MFMA), Wx frags resident in VGPRs.
//   i/f/o gates (cg 0..15, 24..31) -> gxS bf16, sidx = cg<16?cg:cg-8
//   g gate (cg 16..23)             -> gxG f32
//   element off within (tile,cg): l15*16 + q*4 + i  (q = data-row quad)
// ---------------------------------------------------------------------------
__global__ __launch_bounds__(512, 2) void gx_gemm(
    const float* __restrict__ gnn,             // [60000][128] t-major rows
    const unsigned short* __restrict__ WxF_hi,
    const unsigned short* __restrict__ WxF_lo,
    const float* __restrict__ bias_s,
    unsigned short* __restrict__ gxS, float* __restrict__ gxG)
{
    __shared__ unsigned short Ahi[64 * 128];   // 16 KB, XOR-swizzled
    __shared__ unsigned short Alo[64 * 128];

    const int tid  = threadIdx.x;
    const int wv   = tid >> 6;
    const int lane = tid & 63;
    const int l15  = lane & 15;
    const int g    = lane >> 4;
    const size_t fr0 = (size_t)blockIdx.x * 64;

    // stage A tile (64 rows x 128 k), split to bf16 hi/lo, swizzled
    #pragma unroll
    for (int c = 0; c < 2; ++c) {
        int linear = tid + c * 512;
        int row = linear >> 4;
        int k0  = (linear & 15) * 8;
        size_t r = fr0 + row;
        if (r > NRT - 1) r = NRT - 1;          // clamp (pad rows, unused)
        const float* src = gnn + r * DD + k0;
        float4 v0 = *(const float4*)src;
        float4 v1 = *(const float4*)(src + 4);
        float vv[8] = {v0.x, v0.y, v0.z, v0.w, v1.x, v1.y, v1.z, v1.w};
        bf16x8 h8, l8;
        #pragma unroll
        for (int e = 0; e < 8; ++e) {
            unsigned short hb = f2bf(vv[e]);
            h8[e] = (short)hb;
            l8[e] = (short)f2bf(vv[e] - bf2f(hb));
        }
        int byte = (row * 256 + k0 * 2) ^ ((row & 7) << 4);
        *(bf16x8*)((char*)Ahi + byte) = h8;
        *(bf16x8*)((char*)Alo + byte) = l8;
    }

    // resident Wx fragments (wave -> 4 consecutive col-tiles)
    bf16x8 wh[16], wl[16];
    #pragma unroll
    for (int ct = 0; ct < 4; ++ct)
        #pragma unroll
        for (int ks = 0; ks < 4; ++ks) {
            int fidx = (((wv * 4 + ct) * 4 + ks) * 64 + lane) * 8;
            wh[ct * 4 + ks] = *(const bf16x8*)&WxF_hi[fidx];
            wl[ct * 4 + ks] = *(const bf16x8*)&WxF_lo[fidx];
        }
    float bias[4];
    #pragma unroll
    for (int ct = 0; ct < 4; ++ct) bias[ct] = bias_s[(wv * 4 + ct) * 16 + l15];

    __syncthreads();

    #pragma unroll
    for (int ar = 0; ar < 4; ++ar) {
        size_t tile = (size_t)blockIdx.x * 4 + ar;
        if (tile >= NTILE) break;
        bf16x8 ah[4], al[4];
        int row = ar * 16 + l15;
        #pragma unroll
        for (int ks = 0; ks < 4; ++ks) {
            int byte = (row * 256 + (ks * 32 + g * 8) * 2) ^ ((row & 7) << 4);
            ah[ks] = *(const bf16x8*)((const char*)Ahi + byte);
            al[ks] = *(const bf16x8*)((const char*)Alo + byte);
        }
        #pragma unroll
        for (int ct = 0; ct < 4; ++ct) {
            int cg = wv * 4 + ct;
            f32x4 a;
            a[0] = bias[ct]; a[1] = bias[ct]; a[2] = bias[ct]; a[3] = bias[ct];
            #pragma unroll
            for (int ks = 0; ks < 4; ++ks) {
                a = __builtin_amdgcn_mfma_f32_16x16x32_bf16(ah[ks], wh[ct * 4 + ks], a, 0, 0, 0);
                a = __builtin_amdgcn_mfma_f32_16x16x32_bf16(ah[ks], wl[ct * 4 + ks], a, 0, 0, 0);
                a = __builtin_amdgcn_mfma_f32_16x16x32_bf16(al[ks], wh[ct * 4 + ks], a, 0, 0, 0);
            }
            int off = l15 * 16 + g * 4;        // lane holds data rows g*4+i, col l15
            if (cg >= 16 && cg < 24) {
                *(f32x4*)&gxG[(tile * 8 + (cg - 16)) * 256 + off] = a;
            } else {
                int sidx = (cg < 16) ? cg : cg - 8;
                uint2 p;
                p.x = (unsigned)f2bf(a[0]) | ((unsigned)f2bf(a[1]) << 16);
                p.y = (unsigned)f2bf(a[2]) | ((unsigned)f2bf(a[3]) << 16);
                *(uint2*)&gxS[(tile * 24 + sidx) * 256 + off] = p;
            }
        }
    }
}

// ---------------------------------------------------------------------------
// K4b: recurrent-only LSTM + head, IN-REGISTER gates.
// Wave wv owns dims wv*16..+15 of ALL FOUR gates (cg = gate*8 + wv): after the
// MFMAs each lane holds i,f,g,o for its 4 (row,dim) pairs; gate math pure VALU.
// sS/sG: per-batch strides in ELEMENTS (u16 / f32) = full 76.8MB chunk.
// ---------------------------------------------------------------------------
__global__ __launch_bounds__(512, 2) void lstm_rec(
    const unsigned short* __restrict__ gxS, const float* __restrict__ gxG,
    long sS, long sG,
    const unsigned short* __restrict__ WhF_hi,
    const unsigned short* __restrict__ WhF_lo,
    const float* __restrict__ ln_g, const float* __restrict__ ln_b,
    const float* __restrict__ W1, const float* __restrict__ b1,
    const float* __restrict__ W2, const float* __restrict__ b2,
    float* __restrict__ out)                   // full out base
{
    __shared__ unsigned short h_hi[16 * 128];
    __shared__ unsigned short h_lo[16 * 128];
    __shared__ float lnbuf[16 * 128];
    __shared__ float zbuf[16 * 128];

    const int tid  = threadIdx.x;
    const int wv   = tid >> 6;
    const int lane = tid & 63;
    const int l15  = lane & 15;
    const int g    = lane >> 4;
    const int bat  = blockIdx.x / BPB;
    const int bk   = blockIdx.x - bat * BPB;
    const int r0   = bk * 16;

    gxS += (size_t)bat * sS;
    gxG += (size_t)bat * sG;
    float* outb = out + (size_t)bat * NN * HORZ;

    // resident W_hh fragments: gate gt -> cg = gt*8 + wv
    bf16x8 wh[4][4], wl[4][4];
    #pragma unroll
    for (int gt = 0; gt < 4; ++gt)
        #pragma unroll
        for (int ks = 0; ks < 4; ++ks) {
            int cg = gt * 8 + wv;
            int fidx = ((cg * 4 + ks) * 64 + lane) * 8;
            wh[gt][ks] = *(const bf16x8*)&WhF_hi[fidx];
            wl[gt][ks] = *(const bf16x8*)&WhF_lo[fidx];
        }

    int seqq = r0 + g * 4;                     // lane reads data rows seqq..+3
    if (seqq > NN - 4) seqq = NN - 4;

    float c4[4] = {0.f, 0.f, 0.f, 0.f};
    f32x4 cin[4], nxt[4];

    // t = 0 C-init
    {
        size_t F = (size_t)seqq;
        size_t tile = F >> 4;
        int q = ((int)F & 15) >> 2;
        int off = l15 * 16 + q * 4;
        #pragma unroll
        for (int gt = 0; gt < 4; ++gt) {
            if (gt == 2) {
                cin[gt] = *(const f32x4*)&gxG[(tile * 8 + wv) * 256 + off];
            } else {
                int sidx = (gt == 0) ? wv : (gt == 1) ? 8 + wv : 16 + wv;
                uint2 p = *(const uint2*)&gxS[(tile * 24 + sidx) * 256 + off];
                cin[gt][0] = bf2f((unsigned short)(p.x & 0xffff));
                cin[gt][1] = bf2f((unsigned short)(p.x >> 16));
                cin[gt][2] = bf2f((unsigned short)(p.y & 0xffff));
                cin[gt][3] = bf2f((unsigned short)(p.y >> 16));
            }
        }
    }

    for (int t = 0; t < TT; ++t) {
        // prefetch next step's C-init (hides HBM latency under MFMA+gates)
        if (t < TT - 1) {
            size_t F = (size_t)(t + 1) * NN + seqq;
            size_t tile = F >> 4;
            int q = ((int)F & 15) >> 2;
            int off = l15 * 16 + q * 4;
            #pragma unroll
            for (int gt = 0; gt < 4; ++gt) {
                if (gt == 2) {
                    nxt[gt] = *(const f32x4*)&gxG[(tile * 8 + wv) * 256 + off];
                } else {
                    int sidx = (gt == 0) ? wv : (gt == 1) ? 8 + wv : 16 + wv;
                    uint2 p = *(const uint2*)&gxS[(tile * 24 + sidx) * 256 + off];
                    nxt[gt][0] = bf2f((unsigned short)(p.x & 0xffff));
                    nxt[gt][1] = bf2f((unsigned short)(p.x >> 16));
                    nxt[gt][2] = bf2f((unsigned short)(p.y & 0xffff));
                    nxt[gt][3] = bf2f((unsigned short)(p.y >> 16));
                }
            }
        }

        f32x4 acc[4];
        #pragma unroll
        for (int gt = 0; gt < 4; ++gt) acc[gt] = cin[gt];

        if (t > 0) {
            #pragma unroll
            for (int ks = 0; ks < 4; ++ks) {
                int byte = (l15 * 256 + (ks * 32 + g * 8) * 2) ^ ((l15 & 7) << 4);
                bf16x8 ah = *(const bf16x8*)((const char*)h_hi + byte);
                bf16x8 al = *(const bf16x8*)((const char*)h_lo + byte);
                #pragma unroll
                for (int gt = 0; gt < 4; ++gt) {
                    acc[gt] = __builtin_amdgcn_mfma_f32_16x16x32_bf16(ah, wh[gt][ks], acc[gt], 0, 0, 0);
                    acc[gt] = __builtin_amdgcn_mfma_f32_16x16x32_bf16(ah, wl[gt][ks], acc[gt], 0, 0, 0);
                    acc[gt] = __builtin_amdgcn_mfma_f32_16x16x32_bf16(al, wh[gt][ks], acc[gt], 0, 0, 0);
                }
            }
        }

        // gates fully in-register: lane owns (rows g*4+i, dim wv*16+l15)
        float hv4[4];
        #pragma unroll
        for (int i = 0; i < 4; ++i) {
            float ig = acc[0][i];
            float fg = acc[1][i];
            float gg = acc[2][i];
            float og = acc[3][i];
            float c = sigfast(fg) * c4[i] + sigfast(ig) * tanhfast(gg);
            c4[i] = c;
            hv4[i] = sigfast(og) * tanhfast(c);
        }

        __syncthreads();                       // all reads of h(t) done
        #pragma unroll
        for (int i = 0; i < 4; ++i) {
            int row = g * 4 + i;
            int d   = wv * 16 + l15;
            unsigned short hb = f2bf(hv4[i]);
            unsigned short lb = f2bf(hv4[i] - bf2f(hb));
            int byte = (row * 256 + d * 2) ^ ((row & 7) << 4);
            *(unsigned short*)((char*)h_hi + byte) = hb;
            *(unsigned short*)((char*)h_lo + byte) = lb;
        }
        __syncthreads();                       // h(t+1) visible

        if (t < TT - 1) {
            #pragma unroll
            for (int gt = 0; gt < 4; ++gt) cin[gt] = nxt[gt];
        }
    }

    // ---- head: LayerNorm -> Linear(128,128)+ReLU -> Linear(128,12) ----
    {
        const int row    = tid >> 5;
        const int lane32 = tid & 31;
        float v[4];
        #pragma unroll
        for (int s = 0; s < 4; ++s) {
            int d = lane32 + s * 32;
            int byte = (row * 256 + d * 2) ^ ((row & 7) << 4);
            v[s] = bf2f(*(const unsigned short*)((const char*)h_hi + byte)) +
                   bf2f(*(const unsigned short*)((const char*)h_lo + byte));
        }
        float sum = v[0] + v[1] + v[2] + v[3];
        for (int off = 16; off; off >>= 1) sum += __shfl_xor(sum, off, 32);
        float mu = sum * (1.f / 128.f);
        float var = 0.f;
        #pragma unroll
        for (int s = 0; s < 4; ++s) { float dv = v[s] - mu; var += dv * dv; }
        for (int off = 16; off; off >>= 1) var += __shfl_xor(var, off, 32);
        float rstd = rsqrtf(var * (1.f / 128.f) + 1e-5f);
        #pragma unroll
        for (int s = 0; s < 4; ++s) {
            int d = lane32 + s * 32;
            lnbuf[row * 128 + d] = (v[s] - mu) * rstd * ln_g[d] + ln_b[d];
        }
    }
    __syncthreads();

    {
        float zv[4];
        #pragma unroll
        for (int s = 0; s < 4; ++s) {
            int lin = tid + s * 512;
            int r2 = lin >> 7, j = lin & 127;
            float a = b1[j];
            #pragma unroll 4
            for (int k = 0; k < 128; ++k) a += lnbuf[r2 * 128 + k] * W1[k * 128 + j];
            zv[s] = fmaxf(a, 0.f);
        }
        #pragma unroll
        for (int s = 0; s < 4; ++s) zbuf[tid + s * 512] = zv[s];
    }
    __syncthreads();

    if (tid < 16 * HORZ) {
        int r2 = tid / HORZ, o = tid % HORZ;
        if (r0 + r2 < NN) {
            float a = b2[o];
            #pragma unroll 4
            for (int k = 0; k < 128; ++k) a += zbuf[r2 * 128 + k] * W2[k * HORZ + o];
            outb[(size_t)(r0 + r2) * HORZ + o] = a;
        }
    }
}

// ---------------------------------------------------------------------------
extern "C" void kernel_launch(void* const* d_in, const int* in_sizes, int n_in,
                              void* d_out, int out_size, void* d_ws, size_t ws_size,
                              hipStream_t stream)
{
    const float* x        = (const float*)d_in[0];
    const int*   eidx     = (const int*)d_in[1];
    const float* ew       = (const float*)d_in[2];
    const float* W_lin    = (const float*)d_in[3];
    const float* att_src  = (const float*)d_in[4];
    const float* att_dst  = (const float*)d_in[5];
    const float* W_edge   = (const float*)d_in[6];
    const float* att_edge = (const float*)d_in[7];
    const float* gat_bias = (const float*)d_in[8];
    const float* W_ih     = (const float*)d_in[9];
    const float* W_hh     = (const float*)d_in[10];
    const float* b_ih     = (const float*)d_in[11];
    const float* b_hh     = (const float*)d_in[12];
    const float* ln_g     = (const float*)d_in[13];
    const float* ln_b     = (const float*)d_in[14];
    const float* W1       = (const float*)d_in[15];
    const float* b1       = (const float*)d_in[16];
    const float* W2       = (const float*)d_in[17];
    const float* b2       = (const float*)d_in[18];
    float* out = (float*)d_out;

    // ---- dual-batch layout: gnn | chunk0{gxS,gxG} | chunk1{gxS,gxG} | tail ----
    // chunk = 46,080,000 B (gxS) + 30,720,000 B (gxG) = 76,800,000 B
    char* base = (char*)d_ws;
    float* gnn2            = (float*)base;                        // 30.72 MB
    char*  gxb             = base + 30720000;
    unsigned short* gx0S   = (unsigned short*)gxb;
    float*          gx0G   = (float*)(gxb + 46080000);
    unsigned short* gx1S   = (unsigned short*)(gxb + 76800000);
    float*          gx1G   = (float*)(gxb + 76800000 + 46080000);
    char*  tail2           = gxb + 2 * 76800000;                  // byte 184.32M
    const long SSTRIDE = 76800000 / 2;   // u16 elems between gx0S and gx1S
    const long GSTRIDE = 76800000 / 4;   // f32 elems between gx0G and gx1G

    // ---- serial layout (110 MB, proven): gnn | gxG | gxS | tail ----
    float* gnn1            = (float*)base;                        // 30.72 MB
    float* gxG1            = gnn1 + 7680000;                      // 30.72 MB
    unsigned short* gxS1   = (unsigned short*)(gxG1 + 7680000);   // 46.08 MB
    char*  tail1           = (char*)(gxS1 + 23040000);            // byte 107.52M

    // shared tail (a_src.., weights, CSR)
    size_t tail_bytes = (240000 + 240000 + 512 + 16) * 4 + 4 * 65536 * 2 +
                        (NN + (NN + 8) + NN + EE + 8) * 4;
    size_t need_dual = (size_t)(tail2 - base) + tail_bytes;
    const int dual = (ws_size >= need_dual) ? 1 : 0;

    float* a_srcT  = (float*)(dual ? tail2 : tail1);
    float* a_dstT  = a_srcT + 240000;
    float* bias_s  = a_dstT + 240000;
    float* s_h     = bias_s + 512;
    unsigned short* WxF_hi = (unsigned short*)(s_h + 16);
    unsigned short* WxF_lo = WxF_hi + 65536;
    unsigned short* WhF_hi = WxF_lo + 65536;
    unsigned short* WhF_lo = WhF_hi + 65536;
    int*   counts  = (int*)(WhF_lo + 65536);
    int*   offs    = counts + NN;
    int*   cur     = offs + (NN + 8);
    int*   elist   = cur + NN;

    float* gnn = dual ? gnn2 : gnn1;
    // hxb (15.36MB): alias a region written only AFTER gat consumes hxb
    unsigned short* hxb = dual ? gx1S : (unsigned short*)gxG1;

    const int* srcA = eidx;
    const int* dstA = eidx + EE;

    // shared prep
    hipMemsetAsync(counts, 0, NN * sizeof(int), stream);
    prep_small<<<1, 512, 0, stream>>>(W_edge, att_edge, b_ih, b_hh, s_h, bias_s);
    wfrag_kernel<<<32, 256, 0, stream>>>(W_ih, W_hh, WxF_hi, WxF_lo, WhF_hi, WhF_lo);
    count_kernel<<<(EE + 255) / 256, 256, 0, stream>>>(dstA, counts);
    scan_kernel<<<1, 1024, 0, stream>>>(counts, offs, cur);
    fill_kernel<<<(EE + 255) / 256, 256, 0, stream>>>(dstA, cur, elist);

    if (dual) {
        for (int b = 0; b < BB; ++b) {
            const float* xb = x + (size_t)b * NN * TT * FF;
            unsigned short* gxSb = b ? gx1S : gx0S;
            float*          gxGb = b ? gx1G : gx0G;
            hx_kernel<<<NRT, 128, 0, stream>>>(xb, W_lin, att_src, att_dst,
                                               hxb, a_srcT, a_dstT);
            gat_kernel<<<NN, 128, 0, stream>>>(hxb, a_srcT, a_dstT, srcA, ew, s_h,
                                               offs, elist, gat_bias, gnn);
            gx_gemm<<<(NRT + 63) / 64, 512, 0, stream>>>(gnn, WxF_hi, WxF_lo,
                                                         bias_s, gxSb, gxGb);
        }
        lstm_rec<<<2 * BPB, 512, 0, stream>>>(gx0S, gx0G, SSTRIDE, GSTRIDE,
                                              WhF_hi, WhF_lo,
                                              ln_g, ln_b, W1, b1, W2, b2, out);
    } else {
        for (int b = 0; b < BB; ++b) {
            const float* xb = x + (size_t)b * NN * TT * FF;
            float* outb = out + (size_t)b * NN * HORZ;
            hx_kernel<<<NRT, 128, 0, stream>>>(xb, W_lin, att_src, att_dst,
                                               hxb, a_srcT, a_dstT);
            gat_kernel<<<NN, 128, 0, stream>>>(hxb, a_srcT, a_dstT, srcA, ew, s_h,
                                               offs, elist, gat_bias, gnn);
            gx_gemm<<<(NRT + 63) / 64, 512, 0, stream>>>(gnn, WxF_hi, WxF_lo,
                                                         bias_s, gxS1, gxG1);
            lstm_rec<<<BPB, 512, 0, stream>>>(gxS1, gxG1, 0, 0,
                                              WhF_hi, WhF_lo,
                                              ln_g, ln_b, W1, b1, W2, b2, outb);
        }
    }
}

// Round 8
// 463.811 us; speedup vs baseline: 2.0124x; 1.0337x over previous
//
#include <hip/hip_runtime.h>
#include <math.h>

// Problem constants (fixed shapes)
#define BB  2
#define NN  5000
#define EE  40000
#define TT  12
#define FF  16
#define DD  128
#define HH  4
#define HORZ 12
#define NRT (NN * TT)           // 60000 rows per batch
#define NTILE (NRT / 16)        // 3750 16-row tiles per batch
#define BPB 313                 // lstm_rec blocks per batch = ceil(5000/16)

typedef short bf16x8 __attribute__((ext_vector_type(8)));
typedef float f32x4  __attribute__((ext_vector_type(4)));

__device__ __forceinline__ float sigfast(float x) {
    return __fdividef(1.f, 1.f + __expf(-x));
}
__device__ __forceinline__ float tanhfast(float x) {
    return __fdividef(2.f, 1.f + __expf(-2.f * x)) - 1.f;
}

__device__ __forceinline__ unsigned short f2bf(float f) {
    unsigned int u = __float_as_uint(f);
    unsigned int r = (u + 0x7fffu + ((u >> 16) & 1u)) >> 16;   // RNE
    return (unsigned short)r;
}
__device__ __forceinline__ float bf2f(unsigned short h) {
    return __uint_as_float(((unsigned int)h) << 16);
}

// ---------------------------------------------------------------------------
// K0a: tiny prep
// ---------------------------------------------------------------------------
__global__ __launch_bounds__(512) void prep_small(
    const float* __restrict__ W_edge, const float* __restrict__ att_edge,
    const float* __restrict__ b_ih, const float* __restrict__ b_hh,
    float* __restrict__ s_h, float* __restrict__ bias_sum)
{
    int tid = threadIdx.x;
    if (tid < 128) {
        float v = W_edge[tid] * att_edge[tid];
        for (int off = 16; off; off >>= 1) v += __shfl_xor(v, off, 32);
        if ((tid & 31) == 0) s_h[tid >> 5] = v;
    }
    bias_sum[tid] = b_ih[tid] + b_hh[tid];
}

// ---------------------------------------------------------------------------
// K0b: pack W_ih / W_hh into per-lane MFMA fragment order, split bf16 hi/lo.
// frag (cg,ks): lane L holds col=cg*16+(L&15), k=ks*32+(L>>4)*8+j.
// ---------------------------------------------------------------------------
__global__ __launch_bounds__(256) void wfrag_kernel(
    const float* __restrict__ W_ih, const float* __restrict__ W_hh,
    unsigned short* __restrict__ WxF_hi, unsigned short* __restrict__ WxF_lo,
    unsigned short* __restrict__ WhF_hi, unsigned short* __restrict__ WhF_lo)
{
    int gidx = blockIdx.x * 256 + threadIdx.x;    // 0..8191 : (cg,ks,lane)
    if (gidx >= 32 * 4 * 64) return;
    int lane = gidx & 63;
    int ks   = (gidx >> 6) & 3;
    int cg   = gidx >> 8;                          // global col-tile 0..31
    int col  = cg * 16 + (lane & 15);
    #pragma unroll
    for (int j = 0; j < 8; ++j) {
        int k = ks * 32 + (lane >> 4) * 8 + j;
        int o = gidx * 8 + j;
        float vx = W_ih[col * DD + k];
        unsigned short xh = f2bf(vx);
        WxF_hi[o] = xh;
        WxF_lo[o] = f2bf(vx - bf2f(xh));
        float vh = W_hh[col * DD + k];
        unsigned short hh = f2bf(vh);
        WhF_hi[o] = hh;
        WhF_lo[o] = f2bf(vh - bf2f(hh));
    }
}

// ---------------------------------------------------------------------------
// K1: hx = x @ W_lin (bf16 out) + a_src/a_dst per-head reductions (batch-local)
// ---------------------------------------------------------------------------
__global__ __launch_bounds__(128) void hx_kernel(
    const float* __restrict__ xb, const float* __restrict__ W_lin,
    const float* __restrict__ att_src, const float* __restrict__ att_dst,
    unsigned short* __restrict__ hxb, float* __restrict__ a_srcT,
    float* __restrict__ a_dstT)
{
    const int rt = blockIdx.x;                 // n*T+t, 0..59999
    const int d  = threadIdx.x;
    const float* xr = xb + (size_t)rt * FF;
    float acc = 0.f;
    #pragma unroll
    for (int f = 0; f < FF; ++f) acc += xr[f] * W_lin[f * DD + d];
    hxb[(size_t)rt * DD + d] = f2bf(acc);
    float vs = acc * att_src[d];
    float vd = acc * att_dst[d];
    for (int off = 16; off; off >>= 1) {
        vs += __shfl_xor(vs, off, 32);
        vd += __shfl_xor(vd, off, 32);
    }
    if ((d & 31) == 0) {
        int h = d >> 5;
        a_srcT[(size_t)rt * HH + h] = vs;
        a_dstT[(size_t)rt * HH + h] = vd;
    }
}

// ---------------------------------------------------------------------------
// K2: CSR build (shared by both batches)
// ---------------------------------------------------------------------------
__global__ __launch_bounds__(256) void count_kernel(const int* __restrict__ dst,
                                                    int* __restrict__ counts)
{
    int e = blockIdx.x * 256 + threadIdx.x;
    if (e < EE) atomicAdd(&counts[dst[e]], 1);
}

__global__ __launch_bounds__(1024) void scan_kernel(const int* __restrict__ counts,
                                                    int* __restrict__ offs,
                                                    int* __restrict__ cur)
{
    __shared__ int part[1024];
    const int tid = threadIdx.x;
    const int CH = 5;
    int base = tid * CH;
    int pre[CH];
    int run = 0;
    #pragma unroll
    for (int i = 0; i < CH; ++i) {
        int idx = base + i;
        int v = (idx < NN) ? counts[idx] : 0;
        pre[i] = run;
        run += v;
    }
    part[tid] = run;
    __syncthreads();
    for (int off = 1; off < 1024; off <<= 1) {
        int v = (tid >= off) ? part[tid - off] : 0;
        __syncthreads();
        part[tid] += v;
        __syncthreads();
    }
    int prefix = (tid == 0) ? 0 : part[tid - 1];
    #pragma unroll
    for (int i = 0; i < CH; ++i) {
        int idx = base + i;
        if (idx < NN) {
            int o = prefix + pre[i];
            offs[idx] = o;
            cur[idx]  = o;
        }
    }
    if (tid == 1023) offs[NN] = part[1023];
}

__global__ __launch_bounds__(256) void fill_kernel(const int* __restrict__ dst,
                                                   int* __restrict__ cur,
                                                   int* __restrict__ elist)
{
    int e = blockIdx.x * 256 + threadIdx.x;
    if (e < EE) {
        int p = atomicAdd(&cur[dst[e]], 1);
        elist[p] = e;
    }
}

// ---------------------------------------------------------------------------
// K3: GAT scatter-softmax + aggregate + bias + ELU (batch-local, t-major out)
// ---------------------------------------------------------------------------
__global__ __launch_bounds__(128) void gat_kernel(
    const unsigned short* __restrict__ hxb, const float* __restrict__ a_srcT,
    const float* __restrict__ a_dstT, const int* __restrict__ src_arr,
    const float* __restrict__ ew, const float* __restrict__ s_h,
    const int* __restrict__ offs, const int* __restrict__ elist,
    const float* __restrict__ gat_bias, float* __restrict__ gnn)
{
    const int n = blockIdx.x;                  // dst node
    const int d = threadIdx.x;
    const int h = d >> 5;
    const int e0 = offs[n], e1 = offs[n + 1];
    const float sh = s_h[h];
    const float bias = gat_bias[d];

    const size_t base_dst = (size_t)n * TT;
    float ad[TT];
    #pragma unroll
    for (int t = 0; t < TT; ++t) ad[t] = a_dstT[(base_dst + t) * HH + h];

    float den[TT], acc[TT];
    #pragma unroll
    for (int t = 0; t < TT; ++t) { den[t] = 0.f; acc[t] = 0.f; }

    for (int ii = e0; ii < e1; ++ii) {
        int e = elist[ii];
        int s = src_arr[e];
        float aew = ew[e] * sh;
        const size_t base_src = (size_t)s * TT;
        #pragma unroll
        for (int t = 0; t < TT; ++t) {
            float al = a_srcT[(base_src + t) * HH + h] + ad[t] + aew;
            al = (al >= 0.f) ? al : 0.2f * al;
            float exv = __expf(al);
            den[t] += exv;
            acc[t] += exv * bf2f(hxb[(base_src + t) * DD + d]);
        }
    }
    #pragma unroll
    for (int t = 0; t < TT; ++t) {
        float g = acc[t] / (den[t] + 1e-16f) + bias;
        float o = (g > 0.f) ? g : expm1f(g);
        gnn[((size_t)t * NN + n) * DD + d] = o;      // t-major
    }
}

// ---------------------------------------------------------------------------
// K4a: gx = bias + gnn @ W_ihT (split-bf16 MFMA), Wx frags PINNED in VGPRs.
//   i/f/o gates (cg 0..15, 24..31) -> gxS bf16, sidx = cg<16?cg:cg-8
//   g gate (cg 16..23)             -> gxG f32
//   element off within (tile,cg): l15*16 + q*4 + i  (q = data-row quad)
// ---------------------------------------------------------------------------
__global__ __launch_bounds__(512, 2) void gx_gemm(
    const float* __restrict__ gnn,             // [60000][128] t-major rows
    const unsigned short* __restrict__ WxF_hi,
    const unsigned short* __restrict__ WxF_lo,
    const float* __restrict__ bias_s,
    unsigned short* __restrict__ gxS, float* __restrict__ gxG)
{
    __shared__ unsigned short Ahi[64 * 128];   // 16 KB, XOR-swizzled
    __shared__ unsigned short Alo[64 * 128];

    const int tid  = threadIdx.x;
    const int wv   = tid >> 6;
    const int lane = tid & 63;
    const int l15  = lane & 15;
    const int g    = lane >> 4;
    const size_t fr0 = (size_t)blockIdx.x * 64;

    // stage A tile (64 rows x 128 k), split to bf16 hi/lo, swizzled
    #pragma unroll
    for (int c = 0; c < 2; ++c) {
        int linear = tid + c * 512;
        int row = linear >> 4;
        int k0  = (linear & 15) * 8;
        size_t r = fr0 + row;
        if (r > NRT - 1) r = NRT - 1;          // clamp (pad rows, unused)
        const float* src = gnn + r * DD + k0;
        float4 v0 = *(const float4*)src;
        float4 v1 = *(const float4*)(src + 4);
        float vv[8] = {v0.x, v0.y, v0.z, v0.w, v1.x, v1.y, v1.z, v1.w};
        bf16x8 h8, l8;
        #pragma unroll
        for (int e = 0; e < 8; ++e) {
            unsigned short hb = f2bf(vv[e]);
            h8[e] = (short)hb;
            l8[e] = (short)f2bf(vv[e] - bf2f(hb));
        }
        int byte = (row * 256 + k0 * 2) ^ ((row & 7) << 4);
        *(bf16x8*)((char*)Ahi + byte) = h8;
        *(bf16x8*)((char*)Alo + byte) = l8;
    }

    // resident Wx fragments, PINNED so the allocator can't rematerialize
    bf16x8 wh[16], wl[16];
    #pragma unroll
    for (int ct = 0; ct < 4; ++ct)
        #pragma unroll
        for (int ks = 0; ks < 4; ++ks) {
            int fidx = (((wv * 4 + ct) * 4 + ks) * 64 + lane) * 8;
            wh[ct * 4 + ks] = *(const bf16x8*)&WxF_hi[fidx];
            wl[ct * 4 + ks] = *(const bf16x8*)&WxF_lo[fidx];
        }
    #pragma unroll
    for (int i = 0; i < 16; ++i) {
        asm volatile("" : "+v"(wh[i]));
        asm volatile("" : "+v"(wl[i]));
    }
    float bias[4];
    #pragma unroll
    for (int ct = 0; ct < 4; ++ct) bias[ct] = bias_s[(wv * 4 + ct) * 16 + l15];

    __syncthreads();

    #pragma unroll
    for (int ar = 0; ar < 4; ++ar) {
        size_t tile = (size_t)blockIdx.x * 4 + ar;
        if (tile >= NTILE) break;
        bf16x8 ah[4], al[4];
        int row = ar * 16 + l15;
        #pragma unroll
        for (int ks = 0; ks < 4; ++ks) {
            int byte = (row * 256 + (ks * 32 + g * 8) * 2) ^ ((row & 7) << 4);
            ah[ks] = *(const bf16x8*)((const char*)Ahi + byte);
            al[ks] = *(const bf16x8*)((const char*)Alo + byte);
        }
        #pragma unroll
        for (int ct = 0; ct < 4; ++ct) {
            int cg = wv * 4 + ct;
            f32x4 a;
            a[0] = bias[ct]; a[1] = bias[ct]; a[2] = bias[ct]; a[3] = bias[ct];
            #pragma unroll
            for (int ks = 0; ks < 4; ++ks) {
                a = __builtin_amdgcn_mfma_f32_16x16x32_bf16(ah[ks], wh[ct * 4 + ks], a, 0, 0, 0);
                a = __builtin_amdgcn_mfma_f32_16x16x32_bf16(ah[ks], wl[ct * 4 + ks], a, 0, 0, 0);
                a = __builtin_amdgcn_mfma_f32_16x16x32_bf16(al[ks], wh[ct * 4 + ks], a, 0, 0, 0);
            }
            int off = l15 * 16 + g * 4;        // lane holds data rows g*4+i, col l15
            if (cg >= 16 && cg < 24) {
                *(f32x4*)&gxG[(tile * 8 + (cg - 16)) * 256 + off] = a;
            } else {
                int sidx = (cg < 16) ? cg : cg - 8;
                uint2 p;
                p.x = (unsigned)f2bf(a[0]) | ((unsigned)f2bf(a[1]) << 16);
                p.y = (unsigned)f2bf(a[2]) | ((unsigned)f2bf(a[3]) << 16);
                *(uint2*)&gxS[(tile * 24 + sidx) * 256 + off] = p;
            }
        }
    }
}

// ---------------------------------------------------------------------------
// K4b: recurrent-only LSTM + head. In-register gates; W_hh frags PINNED in
// VGPRs (the whole point: zero weight traffic in the t-loop). h double-buffered
// in LDS -> ONE barrier per step. sS/sG: per-batch strides in elements.
// ---------------------------------------------------------------------------
__global__ __launch_bounds__(512, 2) void lstm_rec(
    const unsigned short* __restrict__ gxS, const float* __restrict__ gxG,
    long sS, long sG,
    const unsigned short* __restrict__ WhF_hi,
    const unsigned short* __restrict__ WhF_lo,
    const float* __restrict__ ln_g, const float* __restrict__ ln_b,
    const float* __restrict__ W1, const float* __restrict__ b1,
    const float* __restrict__ W2, const float* __restrict__ b2,
    float* __restrict__ out)                   // full out base
{
    __shared__ unsigned short hb_hi[2][16 * 128];   // double-buffered h (hi)
    __shared__ unsigned short hb_lo[2][16 * 128];   // double-buffered h (lo)
    __shared__ float lnbuf[16 * 128];
    __shared__ float zbuf[16 * 128];

    const int tid  = threadIdx.x;
    const int wv   = tid >> 6;
    const int lane = tid & 63;
    const int l15  = lane & 15;
    const int g    = lane >> 4;
    const int bat  = blockIdx.x / BPB;
    const int bk   = blockIdx.x - bat * BPB;
    const int r0   = bk * 16;

    gxS += (size_t)bat * sS;
    gxG += (size_t)bat * sG;
    float* outb = out + (size_t)bat * NN * HORZ;

    // resident W_hh fragments: gate gt -> cg = gt*8 + wv; PINNED
    bf16x8 wh[4][4], wl[4][4];
    #pragma unroll
    for (int gt = 0; gt < 4; ++gt)
        #pragma unroll
        for (int ks = 0; ks < 4; ++ks) {
            int cg = gt * 8 + wv;
            int fidx = ((cg * 4 + ks) * 64 + lane) * 8;
            wh[gt][ks] = *(const bf16x8*)&WhF_hi[fidx];
            wl[gt][ks] = *(const bf16x8*)&WhF_lo[fidx];
        }
    #pragma unroll
    for (int gt = 0; gt < 4; ++gt)
        #pragma unroll
        for (int ks = 0; ks < 4; ++ks) {
            asm volatile("" : "+v"(wh[gt][ks]));
            asm volatile("" : "+v"(wl[gt][ks]));
        }

    int seqq = r0 + g * 4;                     // lane reads data rows seqq..+3
    if (seqq > NN - 4) seqq = NN - 4;

    float c4[4] = {0.f, 0.f, 0.f, 0.f};
    f32x4 cin[4], nxt[4];

    // t = 0 C-init
    {
        size_t F = (size_t)seqq;
        size_t tile = F >> 4;
        int q = ((int)F & 15) >> 2;
        int off = l15 * 16 + q * 4;
        #pragma unroll
        for (int gt = 0; gt < 4; ++gt) {
            if (gt == 2) {
                cin[gt] = *(const f32x4*)&gxG[(tile * 8 + wv) * 256 + off];
            } else {
                int sidx = (gt == 0) ? wv : (gt == 1) ? 8 + wv : 16 + wv;
                uint2 p = *(const uint2*)&gxS[(tile * 24 + sidx) * 256 + off];
                cin[gt][0] = bf2f((unsigned short)(p.x & 0xffff));
                cin[gt][1] = bf2f((unsigned short)(p.x >> 16));
                cin[gt][2] = bf2f((unsigned short)(p.y & 0xffff));
                cin[gt][3] = bf2f((unsigned short)(p.y >> 16));
            }
        }
    }

    for (int t = 0; t < TT; ++t) {
        // prefetch next step's C-init (stays in flight through the MFMAs)
        if (t < TT - 1) {
            size_t F = (size_t)(t + 1) * NN + seqq;
            size_t tile = F >> 4;
            int q = ((int)F & 15) >> 2;
            int off = l15 * 16 + q * 4;
            #pragma unroll
            for (int gt = 0; gt < 4; ++gt) {
                if (gt == 2) {
                    nxt[gt] = *(const f32x4*)&gxG[(tile * 8 + wv) * 256 + off];
                } else {
                    int sidx = (gt == 0) ? wv : (gt == 1) ? 8 + wv : 16 + wv;
                    uint2 p = *(const uint2*)&gxS[(tile * 24 + sidx) * 256 + off];
                    nxt[gt][0] = bf2f((unsigned short)(p.x & 0xffff));
                    nxt[gt][1] = bf2f((unsigned short)(p.x >> 16));
                    nxt[gt][2] = bf2f((unsigned short)(p.y & 0xffff));
                    nxt[gt][3] = bf2f((unsigned short)(p.y >> 16));
                }
            }
        }

        f32x4 acc[4];
        #pragma unroll
        for (int gt = 0; gt < 4; ++gt) acc[gt] = cin[gt];

        if (t > 0) {
            const char* rh = (const char*)hb_hi[t & 1];
            const char* rl = (const char*)hb_lo[t & 1];
            #pragma unroll
            for (int ks = 0; ks < 4; ++ks) {
                int byte = (l15 * 256 + (ks * 32 + g * 8) * 2) ^ ((l15 & 7) << 4);
                bf16x8 ah = *(const bf16x8*)(rh + byte);
                bf16x8 al = *(const bf16x8*)(rl + byte);
                #pragma unroll
                for (int gt = 0; gt < 4; ++gt) {
                    acc[gt] = __builtin_amdgcn_mfma_f32_16x16x32_bf16(ah, wh[gt][ks], acc[gt], 0, 0, 0);
                    acc[gt] = __builtin_amdgcn_mfma_f32_16x16x32_bf16(ah, wl[gt][ks], acc[gt], 0, 0, 0);
                    acc[gt] = __builtin_amdgcn_mfma_f32_16x16x32_bf16(al, wh[gt][ks], acc[gt], 0, 0, 0);
                }
            }
        }

        // gates fully in-register: lane owns (rows g*4+i, dim wv*16+l15)
        float hv4[4];
        #pragma unroll
        for (int i = 0; i < 4; ++i) {
            float ig = acc[0][i];
            float fg = acc[1][i];
            float gg = acc[2][i];
            float og = acc[3][i];
            float c = sigfast(fg) * c4[i] + sigfast(ig) * tanhfast(gg);
            c4[i] = c;
            hv4[i] = sigfast(og) * tanhfast(c);
        }

        // write h(t+1) into the OTHER buffer (no read/write conflict)
        {
            char* whp = (char*)hb_hi[(t + 1) & 1];
            char* wlp = (char*)hb_lo[(t + 1) & 1];
            #pragma unroll
            for (int i = 0; i < 4; ++i) {
                int row = g * 4 + i;
                int d   = wv * 16 + l15;
                unsigned short hb = f2bf(hv4[i]);
                unsigned short lb = f2bf(hv4[i] - bf2f(hb));
                int byte = (row * 256 + d * 2) ^ ((row & 7) << 4);
                *(unsigned short*)(whp + byte) = hb;
                *(unsigned short*)(wlp + byte) = lb;
            }
        }
        __syncthreads();                       // h(t+1) visible for next step

        if (t < TT - 1) {
            #pragma unroll
            for (int gt = 0; gt < 4; ++gt) cin[gt] = nxt[gt];
        }
    }

    // ---- head: final h is in buffer [TT & 1] == [0] ----
    {
        const int row    = tid >> 5;
        const int lane32 = tid & 31;
        const char* rh = (const char*)hb_hi[0];
        const char* rl = (const char*)hb_lo[0];
        float v[4];
        #pragma unroll
        for (int s = 0; s < 4; ++s) {
            int d = lane32 + s * 32;
            int byte = (row * 256 + d * 2) ^ ((row & 7) << 4);
            v[s] = bf2f(*(const unsigned short*)(rh + byte)) +
                   bf2f(*(const unsigned short*)(rl + byte));
        }
        float sum = v[0] + v[1] + v[2] + v[3];
        for (int off = 16; off; off >>= 1) sum += __shfl_xor(sum, off, 32);
        float mu = sum * (1.f / 128.f);
        float var = 0.f;
        #pragma unroll
        for (int s = 0; s < 4; ++s) { float dv = v[s] - mu; var += dv * dv; }
        for (int off = 16; off; off >>= 1) var += __shfl_xor(var, off, 32);
        float rstd = rsqrtf(var * (1.f / 128.f) + 1e-5f);
        #pragma unroll
        for (int s = 0; s < 4; ++s) {
            int d = lane32 + s * 32;
            lnbuf[row * 128 + d] = (v[s] - mu) * rstd * ln_g[d] + ln_b[d];
        }
    }
    __syncthreads();

    {
        float zv[4];
        #pragma unroll
        for (int s = 0; s < 4; ++s) {
            int lin = tid + s * 512;
            int r2 = lin >> 7, j = lin & 127;
            float a = b1[j];
            #pragma unroll 4
            for (int k = 0; k < 128; ++k) a += lnbuf[r2 * 128 + k] * W1[k * 128 + j];
            zv[s] = fmaxf(a, 0.f);
        }
        #pragma unroll
        for (int s = 0; s < 4; ++s) zbuf[tid + s * 512] = zv[s];
    }
    __syncthreads();

    if (tid < 16 * HORZ) {
        int r2 = tid / HORZ, o = tid % HORZ;
        if (r0 + r2 < NN) {
            float a = b2[o];
            #pragma unroll 4
            for (int k = 0; k < 128; ++k) a += zbuf[r2 * 128 + k] * W2[k * HORZ + o];
            outb[(size_t)(r0 + r2) * HORZ + o] = a;
        }
    }
}

// ---------------------------------------------------------------------------
extern "C" void kernel_launch(void* const* d_in, const int* in_sizes, int n_in,
                              void* d_out, int out_size, void* d_ws, size_t ws_size,
                              hipStream_t stream)
{
    const float* x        = (const float*)d_in[0];
    const int*   eidx     = (const int*)d_in[1];
    const float* ew       = (const float*)d_in[2];
    const float* W_lin    = (const float*)d_in[3];
    const float* att_src  = (const float*)d_in[4];
    const float* att_dst  = (const float*)d_in[5];
    const float* W_edge   = (const float*)d_in[6];
    const float* att_edge = (const float*)d_in[7];
    const float* gat_bias = (const float*)d_in[8];
    const float* W_ih     = (const float*)d_in[9];
    const float* W_hh     = (const float*)d_in[10];
    const float* b_ih     = (const float*)d_in[11];
    const float* b_hh     = (const float*)d_in[12];
    const float* ln_g     = (const float*)d_in[13];
    const float* ln_b     = (const float*)d_in[14];
    const float* W1       = (const float*)d_in[15];
    const float* b1       = (const float*)d_in[16];
    const float* W2       = (const float*)d_in[17];
    const float* b2       = (const float*)d_in[18];
    float* out = (float*)d_out;

    // ---- dual-batch layout: gnn | chunk0{gxS,gxG} | chunk1{gxS,gxG} | tail ----
    // chunk = 46,080,000 B (gxS) + 30,720,000 B (gxG) = 76,800,000 B
    char* base = (char*)d_ws;
    float* gnn2            = (float*)base;                        // 30.72 MB
    char*  gxb             = base + 30720000;
    unsigned short* gx0S   = (unsigned short*)gxb;
    float*          gx0G   = (float*)(gxb + 46080000);
    unsigned short* gx1S   = (unsigned short*)(gxb + 76800000);
    float*          gx1G   = (float*)(gxb + 76800000 + 46080000);
    char*  tail2           = gxb + 2 * 76800000;                  // byte 184.32M
    const long SSTRIDE = 76800000 / 2;   // u16 elems between gx0S and gx1S
    const long GSTRIDE = 76800000 / 4;   // f32 elems between gx0G and gx1G

    // ---- serial layout (110 MB, proven): gnn | gxG | gxS | tail ----
    float* gnn1            = (float*)base;                        // 30.72 MB
    float* gxG1            = gnn1 + 7680000;                      // 30.72 MB
    unsigned short* gxS1   = (unsigned short*)(gxG1 + 7680000);   // 46.08 MB
    char*  tail1           = (char*)(gxS1 + 23040000);            // byte 107.52M

    // shared tail (a_src.., weights, CSR)
    size_t tail_bytes = (240000 + 240000 + 512 + 16) * 4 + 4 * 65536 * 2 +
                        (NN + (NN + 8) + NN + EE + 8) * 4;
    size_t need_dual = (size_t)(tail2 - base) + tail_bytes;
    const int dual = (ws_size >= need_dual) ? 1 : 0;

    float* a_srcT  = (float*)(dual ? tail2 : tail1);
    float* a_dstT  = a_srcT + 240000;
    float* bias_s  = a_dstT + 240000;
    float* s_h     = bias_s + 512;
    unsigned short* WxF_hi = (unsigned short*)(s_h + 16);
    unsigned short* WxF_lo = WxF_hi + 65536;
    unsigned short* WhF_hi = WxF_lo + 65536;
    unsigned short* WhF_lo = WhF_hi + 65536;
    int*   counts  = (int*)(WhF_lo + 65536);
    int*   offs    = counts + NN;
    int*   cur     = offs + (NN + 8);
    int*   elist   = cur + NN;

    float* gnn = dual ? gnn2 : gnn1;
    // hxb (15.36MB): alias a region written only AFTER gat consumes hxb
    unsigned short* hxb = dual ? gx1S : (unsigned short*)gxG1;

    const int* srcA = eidx;
    const int* dstA = eidx + EE;

    // shared prep
    hipMemsetAsync(counts, 0, NN * sizeof(int), stream);
    prep_small<<<1, 512, 0, stream>>>(W_edge, att_edge, b_ih, b_hh, s_h, bias_s);
    wfrag_kernel<<<32, 256, 0, stream>>>(W_ih, W_hh, WxF_hi, WxF_lo, WhF_hi, WhF_lo);
    count_kernel<<<(EE + 255) / 256, 256, 0, stream>>>(dstA, counts);
    scan_kernel<<<1, 1024, 0, stream>>>(counts, offs, cur);
    fill_kernel<<<(EE + 255) / 256, 256, 0, stream>>>(dstA, cur, elist);

    if (dual) {
        for (int b = 0; b < BB; ++b) {
            const float* xb = x + (size_t)b * NN * TT * FF;
            unsigned short* gxSb = b ? gx1S : gx0S;
            float*          gxGb = b ? gx1G : gx0G;
            hx_kernel<<<NRT, 128, 0, stream>>>(xb, W_lin, att_src, att_dst,
                                               hxb, a_srcT, a_dstT);
            gat_kernel<<<NN, 128, 0, stream>>>(hxb, a_srcT, a_dstT, srcA, ew, s_h,
                                               offs, elist, gat_bias, gnn);
            gx_gemm<<<(NRT + 63) / 64, 512, 0, stream>>>(gnn, WxF_hi, WxF_lo,
                                                         bias_s, gxSb, gxGb);
        }
        lstm_rec<<<2 * BPB, 512, 0, stream>>>(gx0S, gx0G, SSTRIDE, GSTRIDE,
                                              WhF_hi, WhF_lo,
                                              ln_g, ln_b, W1, b1, W2, b2, out);
    } else {
        for (int b = 0; b < BB; ++b) {
            const float* xb = x + (size_t)b * NN * TT * FF;
            float* outb = out + (size_t)b * NN * HORZ;
            hx_kernel<<<NRT, 128, 0, stream>>>(xb, W_lin, att_src, att_dst,
                                               hxb, a_srcT, a_dstT);
            gat_kernel<<<NN, 128, 0, stream>>>(hxb, a_srcT, a_dstT, srcA, ew, s_h,
                                               offs, elist, gat_bias, gnn);
            gx_gemm<<<(NRT + 63) / 64, 512, 0, stream>>>(gnn, WxF_hi, WxF_lo,
                                                         bias_s, gxS1, gxG1);
            lstm_rec<<<BPB, 512, 0, stream>>>(gxS1, gxG1, 0, 0,
                                              WhF_hi, WhF_lo,
                                              ln_g, ln_b, W1, b1, W2, b2, outb);
        }
    }
}

// Round 9
// 427.256 us; speedup vs baseline: 2.1846x; 1.0856x over previous
//
#include <hip/hip_runtime.h>
#include <math.h>

// Problem constants (fixed shapes)
#define BB  2
#define NN  5000
#define EE  40000
#define TT  12
#define FF  16
#define DD  128
#define HH  4
#define HORZ 12
#define NRT (NN * TT)           // 60000 rows per batch
#define NTILE (NRT / 16)        // 3750 16-row tiles per batch
#define BPB2 157                // lstm_loop blocks per batch = ceil(5000/32)

typedef short bf16x8 __attribute__((ext_vector_type(8)));
typedef float f32x4  __attribute__((ext_vector_type(4)));

__device__ __forceinline__ float sigfast(float x) {
    return __fdividef(1.f, 1.f + __expf(-x));
}
__device__ __forceinline__ float tanhfast(float x) {
    return __fdividef(2.f, 1.f + __expf(-2.f * x)) - 1.f;
}

__device__ __forceinline__ unsigned short f2bf(float f) {
    unsigned int u = __float_as_uint(f);
    unsigned int r = (u + 0x7fffu + ((u >> 16) & 1u)) >> 16;   // RNE
    return (unsigned short)r;
}
__device__ __forceinline__ float bf2f(unsigned short h) {
    return __uint_as_float(((unsigned int)h) << 16);
}

// ---------------------------------------------------------------------------
// K0a: tiny prep
// ---------------------------------------------------------------------------
__global__ __launch_bounds__(512) void prep_small(
    const float* __restrict__ W_edge, const float* __restrict__ att_edge,
    const float* __restrict__ b_ih, const float* __restrict__ b_hh,
    float* __restrict__ s_h, float* __restrict__ bias_sum)
{
    int tid = threadIdx.x;
    if (tid < 128) {
        float v = W_edge[tid] * att_edge[tid];
        for (int off = 16; off; off >>= 1) v += __shfl_xor(v, off, 32);
        if ((tid & 31) == 0) s_h[tid >> 5] = v;
    }
    bias_sum[tid] = b_ih[tid] + b_hh[tid];
}

// ---------------------------------------------------------------------------
// K0b: pack W_ih / W_hh into per-lane MFMA fragment order (bf16, RNE).
// frag (cg,ks): lane L holds col=cg*16+(L&15), k=ks*32+(L>>4)*8+j.
// ---------------------------------------------------------------------------
__global__ __launch_bounds__(256) void wfrag_kernel(
    const float* __restrict__ W_ih, const float* __restrict__ W_hh,
    unsigned short* __restrict__ WxF, unsigned short* __restrict__ WhF)
{
    int gidx = blockIdx.x * 256 + threadIdx.x;    // 0..8191 : (cg,ks,lane)
    if (gidx >= 32 * 4 * 64) return;
    int lane = gidx & 63;
    int ks   = (gidx >> 6) & 3;
    int cg   = gidx >> 8;                          // global col-tile 0..31
    int col  = cg * 16 + (lane & 15);
    #pragma unroll
    for (int j = 0; j < 8; ++j) {
        int k = ks * 32 + (lane >> 4) * 8 + j;
        int o = gidx * 8 + j;
        WxF[o] = f2bf(W_ih[col * DD + k]);
        WhF[o] = f2bf(W_hh[col * DD + k]);
    }
}

// ---------------------------------------------------------------------------
// K1: hx = x @ W_lin (bf16 out) + a_src/a_dst per-head reductions (batch-local)
// ---------------------------------------------------------------------------
__global__ __launch_bounds__(128) void hx_kernel(
    const float* __restrict__ xb, const float* __restrict__ W_lin,
    const float* __restrict__ att_src, const float* __restrict__ att_dst,
    unsigned short* __restrict__ hxb, float* __restrict__ a_srcT,
    float* __restrict__ a_dstT)
{
    const int rt = blockIdx.x;                 // n*T+t, 0..59999
    const int d  = threadIdx.x;
    const float* xr = xb + (size_t)rt * FF;
    float acc = 0.f;
    #pragma unroll
    for (int f = 0; f < FF; ++f) acc += xr[f] * W_lin[f * DD + d];
    hxb[(size_t)rt * DD + d] = f2bf(acc);
    float vs = acc * att_src[d];
    float vd = acc * att_dst[d];
    for (int off = 16; off; off >>= 1) {
        vs += __shfl_xor(vs, off, 32);
        vd += __shfl_xor(vd, off, 32);
    }
    if ((d & 31) == 0) {
        int h = d >> 5;
        a_srcT[(size_t)rt * HH + h] = vs;
        a_dstT[(size_t)rt * HH + h] = vd;
    }
}

// ---------------------------------------------------------------------------
// K2: CSR build (shared by both batches)
// ---------------------------------------------------------------------------
__global__ __launch_bounds__(256) void count_kernel(const int* __restrict__ dst,
                                                    int* __restrict__ counts)
{
    int e = blockIdx.x * 256 + threadIdx.x;
    if (e < EE) atomicAdd(&counts[dst[e]], 1);
}

__global__ __launch_bounds__(1024) void scan_kernel(const int* __restrict__ counts,
                                                    int* __restrict__ offs,
                                                    int* __restrict__ cur)
{
    __shared__ int part[1024];
    const int tid = threadIdx.x;
    const int CH = 5;
    int base = tid * CH;
    int pre[CH];
    int run = 0;
    #pragma unroll
    for (int i = 0; i < CH; ++i) {
        int idx = base + i;
        int v = (idx < NN) ? counts[idx] : 0;
        pre[i] = run;
        run += v;
    }
    part[tid] = run;
    __syncthreads();
    for (int off = 1; off < 1024; off <<= 1) {
        int v = (tid >= off) ? part[tid - off] : 0;
        __syncthreads();
        part[tid] += v;
        __syncthreads();
    }
    int prefix = (tid == 0) ? 0 : part[tid - 1];
    #pragma unroll
    for (int i = 0; i < CH; ++i) {
        int idx = base + i;
        if (idx < NN) {
            int o = prefix + pre[i];
            offs[idx] = o;
            cur[idx]  = o;
        }
    }
    if (tid == 1023) offs[NN] = part[1023];
}

__global__ __launch_bounds__(256) void fill_kernel(const int* __restrict__ dst,
                                                   int* __restrict__ cur,
                                                   int* __restrict__ elist)
{
    int e = blockIdx.x * 256 + threadIdx.x;
    if (e < EE) {
        int p = atomicAdd(&cur[dst[e]], 1);
        elist[p] = e;
    }
}

// ---------------------------------------------------------------------------
// K3: GAT scatter-softmax + aggregate + bias + ELU (batch-local, t-major out)
// ---------------------------------------------------------------------------
__global__ __launch_bounds__(128) void gat_kernel(
    const unsigned short* __restrict__ hxb, const float* __restrict__ a_srcT,
    const float* __restrict__ a_dstT, const int* __restrict__ src_arr,
    const float* __restrict__ ew, const float* __restrict__ s_h,
    const int* __restrict__ offs, const int* __restrict__ elist,
    const float* __restrict__ gat_bias, float* __restrict__ gnn)
{
    const int n = blockIdx.x;                  // dst node
    const int d = threadIdx.x;
    const int h = d >> 5;
    const int e0 = offs[n], e1 = offs[n + 1];
    const float sh = s_h[h];
    const float bias = gat_bias[d];

    const size_t base_dst = (size_t)n * TT;
    float ad[TT];
    #pragma unroll
    for (int t = 0; t < TT; ++t) ad[t] = a_dstT[(base_dst + t) * HH + h];

    float den[TT], acc[TT];
    #pragma unroll
    for (int t = 0; t < TT; ++t) { den[t] = 0.f; acc[t] = 0.f; }

    for (int ii = e0; ii < e1; ++ii) {
        int e = elist[ii];
        int s = src_arr[e];
        float aew = ew[e] * sh;
        const size_t base_src = (size_t)s * TT;
        #pragma unroll
        for (int t = 0; t < TT; ++t) {
            float al = a_srcT[(base_src + t) * HH + h] + ad[t] + aew;
            al = (al >= 0.f) ? al : 0.2f * al;
            float exv = __expf(al);
            den[t] += exv;
            acc[t] += exv * bf2f(hxb[(base_src + t) * DD + d]);
        }
    }
    #pragma unroll
    for (int t = 0; t < TT; ++t) {
        float g = acc[t] / (den[t] + 1e-16f) + bias;
        float o = (g > 0.f) ? g : expm1f(g);
        gnn[((size_t)t * NN + n) * DD + d] = o;      // t-major
    }
}

// ---------------------------------------------------------------------------
// K4a: gx = bias + gnn @ W_ihT. 2-term: (A_hi + A_lo) x W_bf16.
// Wx frags = 16 (64 VGPRs), pinned. Output fragment order per 16-row tile:
//   i/f/o gates -> gxS bf16 (sidx = cg<16?cg:cg-8); g gate -> gxG f32
// ---------------------------------------------------------------------------
__global__ __launch_bounds__(512, 2) void gx_gemm(
    const float* __restrict__ gnn,             // [60000][128] t-major rows
    const unsigned short* __restrict__ WxF,
    const float* __restrict__ bias_s,
    unsigned short* __restrict__ gxS, float* __restrict__ gxG)
{
    __shared__ unsigned short Ahi[64 * 128];   // 16 KB, XOR-swizzled
    __shared__ unsigned short Alo[64 * 128];

    const int tid  = threadIdx.x;
    const int wv   = tid >> 6;
    const int lane = tid & 63;
    const int l15  = lane & 15;
    const int g    = lane >> 4;
    const size_t fr0 = (size_t)blockIdx.x * 64;

    // stage A tile (64 rows x 128 k), split to bf16 hi/lo, swizzled
    #pragma unroll
    for (int c = 0; c < 2; ++c) {
        int linear = tid + c * 512;
        int row = linear >> 4;
        int k0  = (linear & 15) * 8;
        size_t r = fr0 + row;
        if (r > NRT - 1) r = NRT - 1;          // clamp (pad rows, unused)
        const float* src = gnn + r * DD + k0;
        float4 v0 = *(const float4*)src;
        float4 v1 = *(const float4*)(src + 4);
        float vv[8] = {v0.x, v0.y, v0.z, v0.w, v1.x, v1.y, v1.z, v1.w};
        bf16x8 h8, l8;
        #pragma unroll
        for (int e = 0; e < 8; ++e) {
            unsigned short hb = f2bf(vv[e]);
            h8[e] = (short)hb;
            l8[e] = (short)f2bf(vv[e] - bf2f(hb));
        }
        int byte = (row * 256 + k0 * 2) ^ ((row & 7) << 4);
        *(bf16x8*)((char*)Ahi + byte) = h8;
        *(bf16x8*)((char*)Alo + byte) = l8;
    }

    // resident Wx fragments (bf16, 64 VGPRs), pinned
    bf16x8 wh[16];
    #pragma unroll
    for (int ct = 0; ct < 4; ++ct)
        #pragma unroll
        for (int ks = 0; ks < 4; ++ks) {
            int fidx = (((wv * 4 + ct) * 4 + ks) * 64 + lane) * 8;
            wh[ct * 4 + ks] = *(const bf16x8*)&WxF[fidx];
        }
    #pragma unroll
    for (int i = 0; i < 16; ++i) asm volatile("" : "+v"(wh[i]));
    float bias[4];
    #pragma unroll
    for (int ct = 0; ct < 4; ++ct) bias[ct] = bias_s[(wv * 4 + ct) * 16 + l15];

    __syncthreads();

    #pragma unroll
    for (int ar = 0; ar < 4; ++ar) {
        size_t tile = (size_t)blockIdx.x * 4 + ar;
        if (tile >= NTILE) break;
        bf16x8 ah[4], al[4];
        int row = ar * 16 + l15;
        #pragma unroll
        for (int ks = 0; ks < 4; ++ks) {
            int byte = (row * 256 + (ks * 32 + g * 8) * 2) ^ ((row & 7) << 4);
            ah[ks] = *(const bf16x8*)((const char*)Ahi + byte);
            al[ks] = *(const bf16x8*)((const char*)Alo + byte);
        }
        #pragma unroll
        for (int ct = 0; ct < 4; ++ct) {
            int cg = wv * 4 + ct;
            f32x4 a;
            a[0] = bias[ct]; a[1] = bias[ct]; a[2] = bias[ct]; a[3] = bias[ct];
            #pragma unroll
            for (int ks = 0; ks < 4; ++ks) {
                a = __builtin_amdgcn_mfma_f32_16x16x32_bf16(ah[ks], wh[ct * 4 + ks], a, 0, 0, 0);
                a = __builtin_amdgcn_mfma_f32_16x16x32_bf16(al[ks], wh[ct * 4 + ks], a, 0, 0, 0);
            }
            int off = l15 * 16 + g * 4;        // lane holds data rows g*4+i, col l15
            if (cg >= 16 && cg < 24) {
                *(f32x4*)&gxG[(tile * 8 + (cg - 16)) * 256 + off] = a;
            } else {
                int sidx = (cg < 16) ? cg : cg - 8;
                uint2 p;
                p.x = (unsigned)f2bf(a[0]) | ((unsigned)f2bf(a[1]) << 16);
                p.y = (unsigned)f2bf(a[2]) | ((unsigned)f2bf(a[3]) << 16);
                *(uint2*)&gxS[(tile * 24 + sidx) * 256 + off] = p;
            }
        }
    }
}

// ---------------------------------------------------------------------------
// K4b: recurrence ONLY (no head). 32 rows/block (2 row-tiles/wave).
// W_hh bf16 frags = 16 = 64 VGPRs, pinned -> truly resident.
// 2-term MFMA: (h_hi + h_lo) x W. In-register gates. h dbuf in LDS, 1 barrier.
// Writes final hT (f32) to global. nbat batches in one launch.
// ---------------------------------------------------------------------------
__global__ __launch_bounds__(512, 2) void lstm_loop(
    const unsigned short* __restrict__ gxS, const float* __restrict__ gxG,
    long sS, long sG,
    const unsigned short* __restrict__ WhF,
    float* __restrict__ hT)                    // [nbat*NN][128]
{
    __shared__ unsigned short hb_hi[2][32 * 128];   // 8 KB each
    __shared__ unsigned short hb_lo[2][32 * 128];

    const int tid  = threadIdx.x;
    const int wv   = tid >> 6;
    const int lane = tid & 63;
    const int l15  = lane & 15;
    const int g    = lane >> 4;
    const int bat  = blockIdx.x / BPB2;
    const int bk   = blockIdx.x - bat * BPB2;
    const int r0   = bk * 32;

    gxS += (size_t)bat * sS;
    gxG += (size_t)bat * sG;

    // resident W_hh fragments (bf16): gate gt -> cg = gt*8 + wv; PINNED
    bf16x8 wh[4][4];
    #pragma unroll
    for (int gt = 0; gt < 4; ++gt)
        #pragma unroll
        for (int ks = 0; ks < 4; ++ks) {
            int cg = gt * 8 + wv;
            wh[gt][ks] = *(const bf16x8*)&WhF[((cg * 4 + ks) * 64 + lane) * 8];
        }
    #pragma unroll
    for (int gt = 0; gt < 4; ++gt)
        #pragma unroll
        for (int ks = 0; ks < 4; ++ks) asm volatile("" : "+v"(wh[gt][ks]));

    int seqq[2];
    #pragma unroll
    for (int rt = 0; rt < 2; ++rt) {
        int s = r0 + rt * 16 + g * 4;
        seqq[rt] = (s > NN - 4) ? (NN - 4) : s;
    }

    float c8[2][4] = {{0.f,0.f,0.f,0.f},{0.f,0.f,0.f,0.f}};
    uint2  cS[2][3];  f32x4 cG[2];             // packed C-init (i,f,o | g)
    uint2  nS[2][3];  f32x4 nG[2];

    // t = 0 C-init
    #pragma unroll
    for (int rt = 0; rt < 2; ++rt) {
        size_t F = (size_t)seqq[rt];
        size_t tile = F >> 4;
        int off = l15 * 16 + (((int)F & 15) >> 2) * 4;
        cS[rt][0] = *(const uint2*)&gxS[(tile * 24 + wv) * 256 + off];
        cS[rt][1] = *(const uint2*)&gxS[(tile * 24 + 8 + wv) * 256 + off];
        cS[rt][2] = *(const uint2*)&gxS[(tile * 24 + 16 + wv) * 256 + off];
        cG[rt]    = *(const f32x4*)&gxG[(tile * 8 + wv) * 256 + off];
    }

    for (int t = 0; t < TT; ++t) {
        if (t < TT - 1) {                      // prefetch next C-init
            #pragma unroll
            for (int rt = 0; rt < 2; ++rt) {
                size_t F = (size_t)(t + 1) * NN + seqq[rt];
                size_t tile = F >> 4;
                int off = l15 * 16 + (((int)F & 15) >> 2) * 4;
                nS[rt][0] = *(const uint2*)&gxS[(tile * 24 + wv) * 256 + off];
                nS[rt][1] = *(const uint2*)&gxS[(tile * 24 + 8 + wv) * 256 + off];
                nS[rt][2] = *(const uint2*)&gxS[(tile * 24 + 16 + wv) * 256 + off];
                nG[rt]    = *(const f32x4*)&gxG[(tile * 8 + wv) * 256 + off];
            }
        }

        #pragma unroll
        for (int rt = 0; rt < 2; ++rt) {
            // unpack C-init into acc
            f32x4 acc[4];
            #pragma unroll
            for (int s = 0; s < 3; ++s) {      // i, f, o (packed bf16)
                int gt = (s == 2) ? 3 : s;
                acc[gt][0] = bf2f((unsigned short)(cS[rt][s].x & 0xffff));
                acc[gt][1] = bf2f((unsigned short)(cS[rt][s].x >> 16));
                acc[gt][2] = bf2f((unsigned short)(cS[rt][s].y & 0xffff));
                acc[gt][3] = bf2f((unsigned short)(cS[rt][s].y >> 16));
            }
            acc[2] = cG[rt];

            if (t > 0) {
                const char* rh = (const char*)hb_hi[t & 1];
                const char* rl = (const char*)hb_lo[t & 1];
                #pragma unroll
                for (int ks = 0; ks < 4; ++ks) {
                    int row = rt * 16 + l15;
                    int byte = (row * 256 + (ks * 32 + g * 8) * 2) ^ ((row & 7) << 4);
                    bf16x8 ah = *(const bf16x8*)(rh + byte);
                    bf16x8 al = *(const bf16x8*)(rl + byte);
                    #pragma unroll
                    for (int gt = 0; gt < 4; ++gt) {
                        acc[gt] = __builtin_amdgcn_mfma_f32_16x16x32_bf16(ah, wh[gt][ks], acc[gt], 0, 0, 0);
                        acc[gt] = __builtin_amdgcn_mfma_f32_16x16x32_bf16(al, wh[gt][ks], acc[gt], 0, 0, 0);
                    }
                }
            }

            // gates in-register: lane owns rows rt*16+g*4+i, dim wv*16+l15
            #pragma unroll
            for (int i = 0; i < 4; ++i) {
                float c = sigfast(acc[1][i]) * c8[rt][i] +
                          sigfast(acc[0][i]) * tanhfast(acc[2][i]);
                c8[rt][i] = c;
                float hv = sigfast(acc[3][i]) * tanhfast(c);
                if (t < TT - 1) {
                    char* whp = (char*)hb_hi[(t + 1) & 1];
                    char* wlp = (char*)hb_lo[(t + 1) & 1];
                    int row = rt * 16 + g * 4 + i;
                    int d   = wv * 16 + l15;
                    unsigned short hb = f2bf(hv);
                    int byte = (row * 256 + d * 2) ^ ((row & 7) << 4);
                    *(unsigned short*)(whp + byte) = hb;
                    *(unsigned short*)(wlp + byte) = f2bf(hv - bf2f(hb));
                } else {
                    int row = r0 + rt * 16 + g * 4 + i;
                    if (row < NN)
                        hT[((size_t)bat * NN + row) * DD + wv * 16 + l15] = hv;
                }
            }
        }

        if (t < TT - 1) {
            __syncthreads();                   // h(t+1) visible
            #pragma unroll
            for (int rt = 0; rt < 2; ++rt) {
                cS[rt][0] = nS[rt][0]; cS[rt][1] = nS[rt][1]; cS[rt][2] = nS[rt][2];
                cG[rt] = nG[rt];
            }
        }
    }
}

// ---------------------------------------------------------------------------
// K5: head over all rows: LayerNorm -> Linear(128,128)+ReLU -> Linear(128,12)
// ---------------------------------------------------------------------------
__global__ __launch_bounds__(512, 4) void head_kernel(
    const float* __restrict__ hT,              // [nrows][128]
    const float* __restrict__ ln_g, const float* __restrict__ ln_b,
    const float* __restrict__ W1, const float* __restrict__ b1,
    const float* __restrict__ W2, const float* __restrict__ b2,
    float* __restrict__ out, int nrows)
{
    __shared__ float lnbuf[16 * 128];
    __shared__ float zbuf[16 * 128];

    const int tid = threadIdx.x;
    const int r0  = blockIdx.x * 16;

    {
        const int row    = tid >> 5;
        const int lane32 = tid & 31;
        int gr = r0 + row; if (gr > nrows - 1) gr = nrows - 1;
        float v[4];
        #pragma unroll
        for (int s = 0; s < 4; ++s) v[s] = hT[(size_t)gr * DD + lane32 + s * 32];
        float sum = v[0] + v[1] + v[2] + v[3];
        for (int off = 16; off; off >>= 1) sum += __shfl_xor(sum, off, 32);
        float mu = sum * (1.f / 128.f);
        float var = 0.f;
        #pragma unroll
        for (int s = 0; s < 4; ++s) { float dv = v[s] - mu; var += dv * dv; }
        for (int off = 16; off; off >>= 1) var += __shfl_xor(var, off, 32);
        float rstd = rsqrtf(var * (1.f / 128.f) + 1e-5f);
        #pragma unroll
        for (int s = 0; s < 4; ++s) {
            int d = lane32 + s * 32;
            lnbuf[row * 128 + d] = (v[s] - mu) * rstd * ln_g[d] + ln_b[d];
        }
    }
    __syncthreads();

    {
        float zv[4];
        #pragma unroll
        for (int s = 0; s < 4; ++s) {
            int lin = tid + s * 512;
            int r2 = lin >> 7, j = lin & 127;
            float a = b1[j];
            #pragma unroll 4
            for (int k = 0; k < 128; ++k) a += lnbuf[r2 * 128 + k] * W1[k * 128 + j];
            zv[s] = fmaxf(a, 0.f);
        }
        #pragma unroll
        for (int s = 0; s < 4; ++s) zbuf[tid + s * 512] = zv[s];
    }
    __syncthreads();

    if (tid < 16 * HORZ) {
        int r2 = tid / HORZ, o = tid % HORZ;
        if (r0 + r2 < nrows) {
            float a = b2[o];
            #pragma unroll 4
            for (int k = 0; k < 128; ++k) a += zbuf[r2 * 128 + k] * W2[k * HORZ + o];
            out[(size_t)(r0 + r2) * HORZ + o] = a;
        }
    }
}

// ---------------------------------------------------------------------------
extern "C" void kernel_launch(void* const* d_in, const int* in_sizes, int n_in,
                              void* d_out, int out_size, void* d_ws, size_t ws_size,
                              hipStream_t stream)
{
    const float* x        = (const float*)d_in[0];
    const int*   eidx     = (const int*)d_in[1];
    const float* ew       = (const float*)d_in[2];
    const float* W_lin    = (const float*)d_in[3];
    const float* att_src  = (const float*)d_in[4];
    const float* att_dst  = (const float*)d_in[5];
    const float* W_edge   = (const float*)d_in[6];
    const float* att_edge = (const float*)d_in[7];
    const float* gat_bias = (const float*)d_in[8];
    const float* W_ih     = (const float*)d_in[9];
    const float* W_hh     = (const float*)d_in[10];
    const float* b_ih     = (const float*)d_in[11];
    const float* b_hh     = (const float*)d_in[12];
    const float* ln_g     = (const float*)d_in[13];
    const float* ln_b     = (const float*)d_in[14];
    const float* W1       = (const float*)d_in[15];
    const float* b1       = (const float*)d_in[16];
    const float* W2       = (const float*)d_in[17];
    const float* b2       = (const float*)d_in[18];
    float* out = (float*)d_out;

    // ---- dual layout: gnn(+hT alias) | chunk0{gxS,gxG} | chunk1 | tail ----
    char* base = (char*)d_ws;
    float* gnn2            = (float*)base;                        // 30.72 MB
    char*  gxb             = base + 30720000;
    unsigned short* gx0S   = (unsigned short*)gxb;
    float*          gx0G   = (float*)(gxb + 46080000);
    unsigned short* gx1S   = (unsigned short*)(gxb + 76800000);
    float*          gx1G   = (float*)(gxb + 76800000 + 46080000);
    char*  tail2           = gxb + 2 * 76800000;                  // byte 184.32M
    const long SSTRIDE = 76800000 / 2;
    const long GSTRIDE = 76800000 / 4;

    // ---- serial layout (proven): gnn(+hT alias) | gxG | gxS | tail ----
    float* gnn1            = (float*)base;
    float* gxG1            = gnn1 + 7680000;
    unsigned short* gxS1   = (unsigned short*)(gxG1 + 7680000);
    char*  tail1           = (char*)(gxS1 + 23040000);            // byte 107.52M

    size_t tail_bytes = (240000 + 240000 + 512 + 16) * 4 + 2 * 65536 * 2 +
                        (NN + (NN + 8) + NN + EE + 8) * 4;
    size_t need_dual = (size_t)(tail2 - base) + tail_bytes;
    const int dual = (ws_size >= need_dual) ? 1 : 0;

    float* a_srcT  = (float*)(dual ? tail2 : tail1);
    float* a_dstT  = a_srcT + 240000;
    float* bias_s  = a_dstT + 240000;
    float* s_h     = bias_s + 512;
    unsigned short* WxF = (unsigned short*)(s_h + 16);
    unsigned short* WhF = WxF + 65536;
    int*   counts  = (int*)(WhF + 65536);
    int*   offs    = counts + NN;
    int*   cur     = offs + (NN + 8);
    int*   elist   = cur + NN;

    float* gnn = dual ? gnn2 : gnn1;
    float* hT  = gnn;                          // alias: gnn dead after gx_gemm
    unsigned short* hxb = dual ? gx1S : (unsigned short*)gxG1;

    const int* srcA = eidx;
    const int* dstA = eidx + EE;

    hipMemsetAsync(counts, 0, NN * sizeof(int), stream);
    prep_small<<<1, 512, 0, stream>>>(W_edge, att_edge, b_ih, b_hh, s_h, bias_s);
    wfrag_kernel<<<32, 256, 0, stream>>>(W_ih, W_hh, WxF, WhF);
    count_kernel<<<(EE + 255) / 256, 256, 0, stream>>>(dstA, counts);
    scan_kernel<<<1, 1024, 0, stream>>>(counts, offs, cur);
    fill_kernel<<<(EE + 255) / 256, 256, 0, stream>>>(dstA, cur, elist);

    if (dual) {
        for (int b = 0; b < BB; ++b) {
            const float* xb = x + (size_t)b * NN * TT * FF;
            unsigned short* gxSb = b ? gx1S : gx0S;
            float*          gxGb = b ? gx1G : gx0G;
            hx_kernel<<<NRT, 128, 0, stream>>>(xb, W_lin, att_src, att_dst,
                                               hxb, a_srcT, a_dstT);
            gat_kernel<<<NN, 128, 0, stream>>>(hxb, a_srcT, a_dstT, srcA, ew, s_h,
                                               offs, elist, gat_bias, gnn);
            gx_gemm<<<(NRT + 63) / 64, 512, 0, stream>>>(gnn, WxF, bias_s,
                                                         gxSb, gxGb);
        }
        lstm_loop<<<BB * BPB2, 512, 0, stream>>>(gx0S, gx0G, SSTRIDE, GSTRIDE,
                                                 WhF, hT);
        head_kernel<<<(BB * NN) / 16, 512, 0, stream>>>(hT, ln_g, ln_b,
                                                        W1, b1, W2, b2,
                                                        out, BB * NN);
    } else {
        for (int b = 0; b < BB; ++b) {
            const float* xb = x + (size_t)b * NN * TT * FF;
            float* outb = out + (size_t)b * NN * HORZ;
            hx_kernel<<<NRT, 128, 0, stream>>>(xb, W_lin, att_src, att_dst,
                                               hxb, a_srcT, a_dstT);
            gat_kernel<<<NN, 128, 0, stream>>>(hxb, a_srcT, a_dstT, srcA, ew, s_h,
                                               offs, elist, gat_bias, gnn);
            gx_gemm<<<(NRT + 63) / 64, 512, 0, stream>>>(gnn, WxF, bias_s,
                                                         gxS1, gxG1);
            lstm_loop<<<BPB2, 512, 0, stream>>>(gxS1, gxG1, 0, 0, WhF, hT);
            head_kernel<<<(NN + 15) / 16, 512, 0, stream>>>(hT, ln_g, ln_b,
                                                            W1, b1, W2, b2,
                                                            outb, NN);
        }
    }
}

// Round 10
// 412.145 us; speedup vs baseline: 2.2647x; 1.0367x over previous
//
#include <hip/hip_runtime.h>
#include <math.h>

// Problem constants (fixed shapes)
#define BB  2
#define NN  5000
#define EE  40000
#define TT  12
#define FF  16
#define DD  128
#define HH  4
#define HORZ 12
#define NRT (NN * TT)           // 60000 rows per batch
#define NTILE (NRT / 16)        // 3750 16-row tiles per batch
#define LROWS 48
#define BPB3 105                // ceil(5000/48)
#define THALF 6

typedef short bf16x8 __attribute__((ext_vector_type(8)));
typedef float f32x4  __attribute__((ext_vector_type(4)));
typedef __attribute__((address_space(3))) unsigned int lds_u32;
typedef const __attribute__((address_space(1))) unsigned int glb_u32;

__device__ __forceinline__ float sigfast(float x) {
    return __fdividef(1.f, 1.f + __expf(-x));
}
__device__ __forceinline__ float tanhfast(float x) {
    return __fdividef(2.f, 1.f + __expf(-2.f * x)) - 1.f;
}

__device__ __forceinline__ unsigned short f2bf(float f) {
    unsigned int u = __float_as_uint(f);
    unsigned int r = (u + 0x7fffu + ((u >> 16) & 1u)) >> 16;   // RNE
    return (unsigned short)r;
}
__device__ __forceinline__ float bf2f(unsigned short h) {
    return __uint_as_float(((unsigned int)h) << 16);
}

// ---------------------------------------------------------------------------
// K0a: tiny prep
// ---------------------------------------------------------------------------
__global__ __launch_bounds__(512) void prep_small(
    const float* __restrict__ W_edge, const float* __restrict__ att_edge,
    const float* __restrict__ b_ih, const float* __restrict__ b_hh,
    float* __restrict__ s_h, float* __restrict__ bias_sum)
{
    int tid = threadIdx.x;
    if (tid < 128) {
        float v = W_edge[tid] * att_edge[tid];
        for (int off = 16; off; off >>= 1) v += __shfl_xor(v, off, 32);
        if ((tid & 31) == 0) s_h[tid >> 5] = v;
    }
    bias_sum[tid] = b_ih[tid] + b_hh[tid];
}

// ---------------------------------------------------------------------------
// K0b: pack W_ih / W_hh into per-lane MFMA fragment order (bf16, RNE).
// frag (cg,ks): lane L holds col=cg*16+(L&15), k=ks*32+(L>>4)*8+j.
// ---------------------------------------------------------------------------
__global__ __launch_bounds__(256) void wfrag_kernel(
    const float* __restrict__ W_ih, const float* __restrict__ W_hh,
    unsigned short* __restrict__ WxF, unsigned short* __restrict__ WhF)
{
    int gidx = blockIdx.x * 256 + threadIdx.x;    // 0..8191 : (cg,ks,lane)
    if (gidx >= 32 * 4 * 64) return;
    int lane = gidx & 63;
    int ks   = (gidx >> 6) & 3;
    int cg   = gidx >> 8;                          // global col-tile 0..31
    int col  = cg * 16 + (lane & 15);
    #pragma unroll
    for (int j = 0; j < 8; ++j) {
        int k = ks * 32 + (lane >> 4) * 8 + j;
        int o = gidx * 8 + j;
        WxF[o] = f2bf(W_ih[col * DD + k]);
        WhF[o] = f2bf(W_hh[col * DD + k]);
    }
}

// ---------------------------------------------------------------------------
// K1: hx = x @ W_lin (bf16 out) + a_src/a_dst per-head reductions (batch-local)
// ---------------------------------------------------------------------------
__global__ __launch_bounds__(128) void hx_kernel(
    const float* __restrict__ xb, const float* __restrict__ W_lin,
    const float* __restrict__ att_src, const float* __restrict__ att_dst,
    unsigned short* __restrict__ hxb, float* __restrict__ a_srcT,
    float* __restrict__ a_dstT)
{
    const int rt = blockIdx.x;                 // n*T+t, 0..59999
    const int d  = threadIdx.x;
    const float* xr = xb + (size_t)rt * FF;
    float acc = 0.f;
    #pragma unroll
    for (int f = 0; f < FF; ++f) acc += xr[f] * W_lin[f * DD + d];
    hxb[(size_t)rt * DD + d] = f2bf(acc);
    float vs = acc * att_src[d];
    float vd = acc * att_dst[d];
    for (int off = 16; off; off >>= 1) {
        vs += __shfl_xor(vs, off, 32);
        vd += __shfl_xor(vd, off, 32);
    }
    if ((d & 31) == 0) {
        int h = d >> 5;
        a_srcT[(size_t)rt * HH + h] = vs;
        a_dstT[(size_t)rt * HH + h] = vd;
    }
}

// ---------------------------------------------------------------------------
// K2: CSR build (shared by both batches)
// ---------------------------------------------------------------------------
__global__ __launch_bounds__(256) void count_kernel(const int* __restrict__ dst,
                                                    int* __restrict__ counts)
{
    int e = blockIdx.x * 256 + threadIdx.x;
    if (e < EE) atomicAdd(&counts[dst[e]], 1);
}

__global__ __launch_bounds__(1024) void scan_kernel(const int* __restrict__ counts,
                                                    int* __restrict__ offs,
                                                    int* __restrict__ cur)
{
    __shared__ int part[1024];
    const int tid = threadIdx.x;
    const int CH = 5;
    int base = tid * CH;
    int pre[CH];
    int run = 0;
    #pragma unroll
    for (int i = 0; i < CH; ++i) {
        int idx = base + i;
        int v = (idx < NN) ? counts[idx] : 0;
        pre[i] = run;
        run += v;
    }
    part[tid] = run;
    __syncthreads();
    for (int off = 1; off < 1024; off <<= 1) {
        int v = (tid >= off) ? part[tid - off] : 0;
        __syncthreads();
        part[tid] += v;
        __syncthreads();
    }
    int prefix = (tid == 0) ? 0 : part[tid - 1];
    #pragma unroll
    for (int i = 0; i < CH; ++i) {
        int idx = base + i;
        if (idx < NN) {
            int o = prefix + pre[i];
            offs[idx] = o;
            cur[idx]  = o;
        }
    }
    if (tid == 1023) offs[NN] = part[1023];
}

__global__ __launch_bounds__(256) void fill_kernel(const int* __restrict__ dst,
                                                   int* __restrict__ cur,
                                                   int* __restrict__ elist)
{
    int e = blockIdx.x * 256 + threadIdx.x;
    if (e < EE) {
        int p = atomicAdd(&cur[dst[e]], 1);
        elist[p] = e;
    }
}

// ---------------------------------------------------------------------------
// K3: GAT scatter-softmax + aggregate + bias + ELU. t-split: block = (n, half),
// each handles THALF=6 timesteps -> 2x block-level parallelism.
// ---------------------------------------------------------------------------
__global__ __launch_bounds__(128) void gat_kernel(
    const unsigned short* __restrict__ hxb, const float* __restrict__ a_srcT,
    const float* __restrict__ a_dstT, const int* __restrict__ src_arr,
    const float* __restrict__ ew, const float* __restrict__ s_h,
    const int* __restrict__ offs, const int* __restrict__ elist,
    const float* __restrict__ gat_bias, float* __restrict__ gnn)
{
    const int bid = blockIdx.x;
    const int n  = bid >> 1;                   // dst node
    const int t0 = (bid & 1) * THALF;          // timestep half
    const int d = threadIdx.x;
    const int h = d >> 5;
    const int e0 = offs[n], e1 = offs[n + 1];
    const float sh = s_h[h];
    const float bias = gat_bias[d];

    const size_t base_dst = (size_t)n * TT;
    float ad[THALF];
    #pragma unroll
    for (int tt = 0; tt < THALF; ++tt)
        ad[tt] = a_dstT[(base_dst + t0 + tt) * HH + h];

    float den[THALF], acc[THALF];
    #pragma unroll
    for (int tt = 0; tt < THALF; ++tt) { den[tt] = 0.f; acc[tt] = 0.f; }

    for (int ii = e0; ii < e1; ++ii) {
        int e = elist[ii];
        int s = src_arr[e];
        float aew = ew[e] * sh;
        const size_t base_src = (size_t)s * TT + t0;
        #pragma unroll
        for (int tt = 0; tt < THALF; ++tt) {
            float al = a_srcT[(base_src + tt) * HH + h] + ad[tt] + aew;
            al = (al >= 0.f) ? al : 0.2f * al;
            float exv = __expf(al);
            den[tt] += exv;
            acc[tt] += exv * bf2f(hxb[(base_src + tt) * DD + d]);
        }
    }
    #pragma unroll
    for (int tt = 0; tt < THALF; ++tt) {
        float g = acc[tt] / (den[tt] + 1e-16f) + bias;
        float o = (g > 0.f) ? g : expm1f(g);
        gnn[((size_t)(t0 + tt) * NN + n) * DD + d] = o;      // t-major
    }
}

// ---------------------------------------------------------------------------
// K4a: gx = bias + gnn @ W_ihT. 2-term A (hi/lo) x W_bf16. All gates bf16.
// Output per 16-row tile, col-tile cg: uint2/lane at (tile*32+cg)*256 +
// l15*16 + g*4 (elems). Wx frags = 16 (64 VGPRs), pinned.
// ---------------------------------------------------------------------------
__global__ __launch_bounds__(512, 2) void gx_gemm(
    const float* __restrict__ gnn,             // [60000][128] t-major rows
    const unsigned short* __restrict__ WxF,
    const float* __restrict__ bias_s,
    unsigned short* __restrict__ gxS)
{
    __shared__ unsigned short Ahi[64 * 128];   // 16 KB, XOR-swizzled
    __shared__ unsigned short Alo[64 * 128];

    const int tid  = threadIdx.x;
    const int wv   = tid >> 6;
    const int lane = tid & 63;
    const int l15  = lane & 15;
    const int g    = lane >> 4;
    const size_t fr0 = (size_t)blockIdx.x * 64;

    // stage A tile (64 rows x 128 k), split to bf16 hi/lo, swizzled
    #pragma unroll
    for (int c = 0; c < 2; ++c) {
        int linear = tid + c * 512;
        int row = linear >> 4;
        int k0  = (linear & 15) * 8;
        size_t r = fr0 + row;
        if (r > NRT - 1) r = NRT - 1;          // clamp (pad rows, unused)
        const float* src = gnn + r * DD + k0;
        float4 v0 = *(const float4*)src;
        float4 v1 = *(const float4*)(src + 4);
        float vv[8] = {v0.x, v0.y, v0.z, v0.w, v1.x, v1.y, v1.z, v1.w};
        bf16x8 h8, l8;
        #pragma unroll
        for (int e = 0; e < 8; ++e) {
            unsigned short hb = f2bf(vv[e]);
            h8[e] = (short)hb;
            l8[e] = (short)f2bf(vv[e] - bf2f(hb));
        }
        int byte = (row * 256 + k0 * 2) ^ ((row & 7) << 4);
        *(bf16x8*)((char*)Ahi + byte) = h8;
        *(bf16x8*)((char*)Alo + byte) = l8;
    }

    // resident Wx fragments (bf16, 64 VGPRs), pinned
    bf16x8 wh[16];
    #pragma unroll
    for (int ct = 0; ct < 4; ++ct)
        #pragma unroll
        for (int ks = 0; ks < 4; ++ks) {
            int fidx = (((wv * 4 + ct) * 4 + ks) * 64 + lane) * 8;
            wh[ct * 4 + ks] = *(const bf16x8*)&WxF[fidx];
        }
    #pragma unroll
    for (int i = 0; i < 16; ++i) asm volatile("" : "+v"(wh[i]));
    float bias[4];
    #pragma unroll
    for (int ct = 0; ct < 4; ++ct) bias[ct] = bias_s[(wv * 4 + ct) * 16 + l15];

    __syncthreads();

    #pragma unroll
    for (int ar = 0; ar < 4; ++ar) {
        size_t tile = (size_t)blockIdx.x * 4 + ar;
        if (tile >= NTILE) break;
        bf16x8 ah[4], al[4];
        int row = ar * 16 + l15;
        #pragma unroll
        for (int ks = 0; ks < 4; ++ks) {
            int byte = (row * 256 + (ks * 32 + g * 8) * 2) ^ ((row & 7) << 4);
            ah[ks] = *(const bf16x8*)((const char*)Ahi + byte);
            al[ks] = *(const bf16x8*)((const char*)Alo + byte);
        }
        #pragma unroll
        for (int ct = 0; ct < 4; ++ct) {
            int cg = wv * 4 + ct;
            f32x4 a;
            a[0] = bias[ct]; a[1] = bias[ct]; a[2] = bias[ct]; a[3] = bias[ct];
            #pragma unroll
            for (int ks = 0; ks < 4; ++ks) {
                a = __builtin_amdgcn_mfma_f32_16x16x32_bf16(ah[ks], wh[ct * 4 + ks], a, 0, 0, 0);
                a = __builtin_amdgcn_mfma_f32_16x16x32_bf16(al[ks], wh[ct * 4 + ks], a, 0, 0, 0);
            }
            int off = l15 * 16 + g * 4;        // lane holds data rows g*4+i, col l15
            uint2 p;
            p.x = (unsigned)f2bf(a[0]) | ((unsigned)f2bf(a[1]) << 16);
            p.y = (unsigned)f2bf(a[2]) | ((unsigned)f2bf(a[3]) << 16);
            *(uint2*)&gxS[(tile * 32 + cg) * 256 + off] = p;
        }
    }
}

// ---------------------------------------------------------------------------
// K4b: recurrence ONLY. 48 rows/block -> 105 blocks/batch (210 dual <= 256 CUs,
// perfectly balanced). gx staged via global_load_lds into LDS (zero staging
// VGPRs); W_hh bf16 frags (64 VGPRs) pinned-resident. In-register gates.
// h hi/lo double-buffered in LDS, one barrier/step. Writes hT f32.
// ---------------------------------------------------------------------------
__global__ __launch_bounds__(512, 2) void lstm_loop(
    const unsigned short* __restrict__ gxS, long sS,
    const unsigned short* __restrict__ WhF,
    float* __restrict__ hT)                    // [nbat*NN][128]
{
    __shared__ unsigned short hb_hi[2][LROWS * 128];   // 24.6 KB
    __shared__ unsigned short hb_lo[2][LROWS * 128];   // 24.6 KB
    __shared__ unsigned int gstage[3][4][2][512];      // 49.2 KB

    const int tid  = threadIdx.x;
    const int wv   = tid >> 6;
    const int lane = tid & 63;
    const int l15  = lane & 15;
    const int g    = lane >> 4;
    const int bat  = blockIdx.x / BPB3;
    const int bk   = blockIdx.x - bat * BPB3;
    const int r0   = bk * LROWS;

    gxS += (size_t)bat * sS;

    // resident W_hh fragments (bf16): gate gt -> cg = gt*8 + wv; PINNED
    bf16x8 wh[4][4];
    #pragma unroll
    for (int gt = 0; gt < 4; ++gt)
        #pragma unroll
        for (int ks = 0; ks < 4; ++ks) {
            int cg = gt * 8 + wv;
            wh[gt][ks] = *(const bf16x8*)&WhF[((cg * 4 + ks) * 64 + lane) * 8];
        }
    #pragma unroll
    for (int gt = 0; gt < 4; ++gt)
        #pragma unroll
        for (int ks = 0; ks < 4; ++ks) asm volatile("" : "+v"(wh[gt][ks]));

    int seqq[3];
    #pragma unroll
    for (int rt = 0; rt < 3; ++rt) {
        int s = r0 + rt * 16 + g * 4;
        seqq[rt] = (s > NN - 4) ? (NN - 4) : s;
    }

    // async-stage gx(t) into LDS: per (rt,gt) two 4B words; lane slot = tid*4
    auto issue_stage = [&](int t) {
        #pragma unroll
        for (int rt = 0; rt < 3; ++rt) {
            size_t F = (size_t)t * NN + seqq[rt];
            size_t tile = F >> 4;
            int off = l15 * 16 + ((((int)F) & 15) >> 2) * 4;
            #pragma unroll
            for (int gt = 0; gt < 4; ++gt) {
                const unsigned short* gp = gxS + (tile * 32 + gt * 8 + wv) * 256 + off;
                __builtin_amdgcn_global_load_lds(
                    (glb_u32*)(const void*)gp,
                    (lds_u32*)(void*)&gstage[rt][gt][0][wv * 64], 4, 0, 0);
                __builtin_amdgcn_global_load_lds(
                    (glb_u32*)(const void*)(gp + 2),
                    (lds_u32*)(void*)&gstage[rt][gt][1][wv * 64], 4, 0, 0);
            }
        }
    };

    issue_stage(0);
    float c12[3][4];
    #pragma unroll
    for (int rt = 0; rt < 3; ++rt)
        #pragma unroll
        for (int i = 0; i < 4; ++i) c12[rt][i] = 0.f;
    __syncthreads();                           // drains vmcnt -> gx(0) in LDS

    for (int t = 0; t < TT; ++t) {
        // read this step's gx from LDS (own slots), fence, then prefetch t+1
        unsigned int gv[3][4][2];
        #pragma unroll
        for (int rt = 0; rt < 3; ++rt)
            #pragma unroll
            for (int gt = 0; gt < 4; ++gt) {
                gv[rt][gt][0] = gstage[rt][gt][0][tid];
                gv[rt][gt][1] = gstage[rt][gt][1][tid];
            }
        __builtin_amdgcn_sched_barrier(0);
        asm volatile("s_waitcnt lgkmcnt(0)" ::: "memory");
        __builtin_amdgcn_sched_barrier(0);
        if (t < TT - 1) issue_stage(t + 1);

        #pragma unroll
        for (int rt = 0; rt < 3; ++rt) {
            f32x4 acc[4];
            #pragma unroll
            for (int gt = 0; gt < 4; ++gt) {
                acc[gt][0] = bf2f((unsigned short)(gv[rt][gt][0] & 0xffff));
                acc[gt][1] = bf2f((unsigned short)(gv[rt][gt][0] >> 16));
                acc[gt][2] = bf2f((unsigned short)(gv[rt][gt][1] & 0xffff));
                acc[gt][3] = bf2f((unsigned short)(gv[rt][gt][1] >> 16));
            }

            if (t > 0) {
                const char* rh = (const char*)hb_hi[t & 1];
                const char* rl = (const char*)hb_lo[t & 1];
                #pragma unroll
                for (int ks = 0; ks < 4; ++ks) {
                    int row = rt * 16 + l15;
                    int byte = (row * 256 + (ks * 32 + g * 8) * 2) ^ ((row & 7) << 4);
                    bf16x8 ah = *(const bf16x8*)(rh + byte);
                    bf16x8 al = *(const bf16x8*)(rl + byte);
                    #pragma unroll
                    for (int gt = 0; gt < 4; ++gt) {
                        acc[gt] = __builtin_amdgcn_mfma_f32_16x16x32_bf16(ah, wh[gt][ks], acc[gt], 0, 0, 0);
                        acc[gt] = __builtin_amdgcn_mfma_f32_16x16x32_bf16(al, wh[gt][ks], acc[gt], 0, 0, 0);
                    }
                }
            }

            // gates in-register: lane owns rows rt*16+g*4+i, dim wv*16+l15
            #pragma unroll
            for (int i = 0; i < 4; ++i) {
                float c = sigfast(acc[1][i]) * c12[rt][i] +
                          sigfast(acc[0][i]) * tanhfast(acc[2][i]);
                c12[rt][i] = c;
                float hv = sigfast(acc[3][i]) * tanhfast(c);
                if (t < TT - 1) {
                    int row = rt * 16 + g * 4 + i;
                    int d   = wv * 16 + l15;
                    unsigned short hb = f2bf(hv);
                    int byte = (row * 256 + d * 2) ^ ((row & 7) << 4);
                    *(unsigned short*)((char*)hb_hi[(t + 1) & 1] + byte) = hb;
                    *(unsigned short*)((char*)hb_lo[(t + 1) & 1] + byte) = f2bf(hv - bf2f(hb));
                } else {
                    int row = r0 + rt * 16 + g * 4 + i;
                    if (row < NN)
                        hT[((size_t)bat * NN + row) * DD + wv * 16 + l15] = hv;
                }
            }
        }

        if (t < TT - 1) __syncthreads();       // h(t+1) + staged gx visible
    }
}

// ---------------------------------------------------------------------------
// K5: head over all rows: LayerNorm -> Linear(128,128)+ReLU -> Linear(128,12)
// ---------------------------------------------------------------------------
__global__ __launch_bounds__(512, 4) void head_kernel(
    const float* __restrict__ hT,              // [nrows][128]
    const float* __restrict__ ln_g, const float* __restrict__ ln_b,
    const float* __restrict__ W1, const float* __restrict__ b1,
    const float* __restrict__ W2, const float* __restrict__ b2,
    float* __restrict__ out, int nrows)
{
    __shared__ float lnbuf[16 * 128];
    __shared__ float zbuf[16 * 128];

    const int tid = threadIdx.x;
    const int r0  = blockIdx.x * 16;

    {
        const int row    = tid >> 5;
        const int lane32 = tid & 31;
        int gr = r0 + row; if (gr > nrows - 1) gr = nrows - 1;
        float v[4];
        #pragma unroll
        for (int s = 0; s < 4; ++s) v[s] = hT[(size_t)gr * DD + lane32 + s * 32];
        float sum = v[0] + v[1] + v[2] + v[3];
        for (int off = 16; off; off >>= 1) sum += __shfl_xor(sum, off, 32);
        float mu = sum * (1.f / 128.f);
        float var = 0.f;
        #pragma unroll
        for (int s = 0; s < 4; ++s) { float dv = v[s] - mu; var += dv * dv; }
        for (int off = 16; off; off >>= 1) var += __shfl_xor(var, off, 32);
        float rstd = rsqrtf(var * (1.f / 128.f) + 1e-5f);
        #pragma unroll
        for (int s = 0; s < 4; ++s) {
            int d = lane32 + s * 32;
            lnbuf[row * 128 + d] = (v[s] - mu) * rstd * ln_g[d] + ln_b[d];
        }
    }
    __syncthreads();

    {
        float zv[4];
        #pragma unroll
        for (int s = 0; s < 4; ++s) {
            int lin = tid + s * 512;
            int r2 = lin >> 7, j = lin & 127;
            float a = b1[j];
            #pragma unroll 4
            for (int k = 0; k < 128; ++k) a += lnbuf[r2 * 128 + k] * W1[k * 128 + j];
            zv[s] = fmaxf(a, 0.f);
        }
        #pragma unroll
        for (int s = 0; s < 4; ++s) zbuf[tid + s * 512] = zv[s];
    }
    __syncthreads();

    if (tid < 16 * HORZ) {
        int r2 = tid / HORZ, o = tid % HORZ;
        if (r0 + r2 < nrows) {
            float a = b2[o];
            #pragma unroll 4
            for (int k = 0; k < 128; ++k) a += zbuf[r2 * 128 + k] * W2[k * HORZ + o];
            out[(size_t)(r0 + r2) * HORZ + o] = a;
        }
    }
}

// ---------------------------------------------------------------------------
extern "C" void kernel_launch(void* const* d_in, const int* in_sizes, int n_in,
                              void* d_out, int out_size, void* d_ws, size_t ws_size,
                              hipStream_t stream)
{
    const float* x        = (const float*)d_in[0];
    const int*   eidx     = (const int*)d_in[1];
    const float* ew       = (const float*)d_in[2];
    const float* W_lin    = (const float*)d_in[3];
    const float* att_src  = (const float*)d_in[4];
    const float* att_dst  = (const float*)d_in[5];
    const float* W_edge   = (const float*)d_in[6];
    const float* att_edge = (const float*)d_in[7];
    const float* gat_bias = (const float*)d_in[8];
    const float* W_ih     = (const float*)d_in[9];
    const float* W_hh     = (const float*)d_in[10];
    const float* b_ih     = (const float*)d_in[11];
    const float* b_hh     = (const float*)d_in[12];
    const float* ln_g     = (const float*)d_in[13];
    const float* ln_b     = (const float*)d_in[14];
    const float* W1       = (const float*)d_in[15];
    const float* b1       = (const float*)d_in[16];
    const float* W2       = (const float*)d_in[17];
    const float* b2       = (const float*)d_in[18];
    float* out = (float*)d_out;

    const size_t GXB = 61440000;               // gx bytes per batch (all-bf16)
    char* base = (char*)d_ws;

    // ---- dual layout: gnn(+hT alias) | gx0S | gx1S | tail (~156 MB) ----
    float* gnn2          = (float*)base;                      // 30.72 MB
    unsigned short* gx0S = (unsigned short*)(base + 30720000);
    unsigned short* gx1S = (unsigned short*)(base + 30720000 + GXB);
    char* tail2          = base + 30720000 + 2 * GXB;
    const long SSTRIDE   = (long)(GXB / 2);    // u16 elems between gx0S, gx1S

    // ---- serial layout (~94 MB): gnn(+hT alias) | gxS | tail ----
    float* gnn1          = (float*)base;
    unsigned short* gxS1 = (unsigned short*)(base + 30720000);
    char* tail1          = base + 30720000 + GXB;

    size_t tail_bytes = (240000 + 240000 + 512 + 16) * 4 + 2 * 65536 * 2 +
                        (NN + (NN + 8) + NN + EE + 8) * 4;
    size_t need_dual = (size_t)(tail2 - base) + tail_bytes;
    const int dual = (ws_size >= need_dual) ? 1 : 0;

    float* a_srcT  = (float*)(dual ? tail2 : tail1);
    float* a_dstT  = a_srcT + 240000;
    float* bias_s  = a_dstT + 240000;
    float* s_h     = bias_s + 512;
    unsigned short* WxF = (unsigned short*)(s_h + 16);
    unsigned short* WhF = WxF + 65536;
    int*   counts  = (int*)(WhF + 65536);
    int*   offs    = counts + NN;
    int*   cur     = offs + (NN + 8);
    int*   elist   = cur + NN;

    float* gnn = dual ? gnn2 : gnn1;
    float* hT  = gnn;                          // alias: gnn dead after gx_gemm
    // hxb (15.36MB): alias a region written only AFTER gat consumes hxb
    unsigned short* hxb = dual ? gx1S : gxS1;

    const int* srcA = eidx;
    const int* dstA = eidx + EE;

    hipMemsetAsync(counts, 0, NN * sizeof(int), stream);
    prep_small<<<1, 512, 0, stream>>>(W_edge, att_edge, b_ih, b_hh, s_h, bias_s);
    wfrag_kernel<<<32, 256, 0, stream>>>(W_ih, W_hh, WxF, WhF);
    count_kernel<<<(EE + 255) / 256, 256, 0, stream>>>(dstA, counts);
    scan_kernel<<<1, 1024, 0, stream>>>(counts, offs, cur);
    fill_kernel<<<(EE + 255) / 256, 256, 0, stream>>>(dstA, cur, elist);

    if (dual) {
        for (int b = 0; b < BB; ++b) {
            const float* xb = x + (size_t)b * NN * TT * FF;
            unsigned short* gxSb = b ? gx1S : gx0S;
            hx_kernel<<<NRT, 128, 0, stream>>>(xb, W_lin, att_src, att_dst,
                                               hxb, a_srcT, a_dstT);
            gat_kernel<<<NN * 2, 128, 0, stream>>>(hxb, a_srcT, a_dstT, srcA, ew,
                                                   s_h, offs, elist, gat_bias, gnn);
            gx_gemm<<<(NRT + 63) / 64, 512, 0, stream>>>(gnn, WxF, bias_s, gxSb);
        }
        lstm_loop<<<BB * BPB3, 512, 0, stream>>>(gx0S, SSTRIDE, WhF, hT);
        head_kernel<<<(BB * NN + 15) / 16, 512, 0, stream>>>(hT, ln_g, ln_b,
                                                             W1, b1, W2, b2,
                                                             out, BB * NN);
    } else {
        for (int b = 0; b < BB; ++b) {
            const float* xb = x + (size_t)b * NN * TT * FF;
            float* outb = out + (size_t)b * NN * HORZ;
            hx_kernel<<<NRT, 128, 0, stream>>>(xb, W_lin, att_src, att_dst,
                                               hxb, a_srcT, a_dstT);
            gat_kernel<<<NN * 2, 128, 0, stream>>>(hxb, a_srcT, a_dstT, srcA, ew,
                                                   s_h, offs, elist, gat_bias, gnn);
            gx_gemm<<<(NRT + 63) / 64, 512, 0, stream>>>(gnn, WxF, bias_s, gxS1);
            lstm_loop<<<BPB3, 512, 0, stream>>>(gxS1, 0, WhF, hT);
            head_kernel<<<(NN + 15) / 16, 512, 0, stream>>>(hT, ln_g, ln_b,
                                                            W1, b1, W2, b2,
                                                            outb, NN);
        }
    }
}